// Round 3
// baseline (4207.893 us; speedup 1.0000x reference)
//
#include <hip/hip_runtime.h>
#include <hip/hip_bf16.h>

#define PP 4096          // H*W = 64*64
#define HH 64
#define WW 64

// ---------------------------------------------------------------------------
// Kernel 1: txc = concat([t_hx, upsample2x_align_corners(tx)], C) -> [8,512,4096] bf16
// ---------------------------------------------------------------------------
__global__ void k_txc(const float* __restrict__ t_hx, const float* __restrict__ tx,
                      __hip_bfloat16* __restrict__ txc) {
    int tid = threadIdx.x;
    int pt = blockIdx.x;        // 16 pixel tiles of 256
    int c  = blockIdx.y;        // 512
    int n  = blockIdx.z;        // 8
    int p = pt * 256 + tid;
    float v;
    if (c < 256) {
        v = t_hx[((size_t)(n * 256 + c)) * PP + p];
    } else {
        int y = p >> 6, x = p & 63;
        const float s = 31.0f / 63.0f;   // align_corners scale for 32->64
        float fy = y * s, fx = x * s;
        int y0 = (int)fy, x0 = (int)fx;
        int y1 = min(y0 + 1, 31), x1 = min(x0 + 1, 31);
        float wy = fy - (float)y0, wx = fx - (float)x0;
        const float* t = tx + ((size_t)(n * 256 + (c - 256))) * 1024;
        float v00 = t[y0 * 32 + x0], v01 = t[y0 * 32 + x1];
        float v10 = t[y1 * 32 + x0], v11 = t[y1 * 32 + x1];
        v = (v00 * (1.0f - wy) + v10 * wy) * (1.0f - wx)
          + (v01 * (1.0f - wy) + v11 * wy) * wx;
    }
    txc[((size_t)(n * 512 + c)) * PP + p] = __float2bfloat16(v);
}

// ---------------------------------------------------------------------------
// Kernel 2: per-pixel relu(W_t1 @ [sx1; txc] + b_t1), partial sum over pixel tile
// part: [8][256][16] f32
// ---------------------------------------------------------------------------
__global__ void k_gap(const float* __restrict__ sx1, const __hip_bfloat16* __restrict__ txc,
                      const float* __restrict__ Wt1, const float* __restrict__ bt1,
                      float* __restrict__ part) {
    int tid = threadIdx.x;
    int ot = blockIdx.x;   // 32 tiles of 8 output channels
    int pt = blockIdx.y;   // 16 pixel tiles
    int n  = blockIdx.z;
    int p = pt * 256 + tid;
    int o0 = ot * 8;
    float acc[8] = {0, 0, 0, 0, 0, 0, 0, 0};
    const float* xs = sx1 + ((size_t)n * 256) * PP + p;
    for (int c = 0; c < 256; ++c) {
        float v = xs[(size_t)c * PP];
        #pragma unroll
        for (int j = 0; j < 8; ++j)
            acc[j] = fmaf(Wt1[(o0 + j) * 768 + c], v, acc[j]);
    }
    const __hip_bfloat16* xt = txc + ((size_t)n * 512) * PP + p;
    for (int c = 0; c < 512; ++c) {
        float v = __bfloat162float(xt[(size_t)c * PP]);
        #pragma unroll
        for (int j = 0; j < 8; ++j)
            acc[j] = fmaf(Wt1[(o0 + j) * 768 + 256 + c], v, acc[j]);
    }
    __shared__ float red[8 * 4];
    int lane = tid & 63, wv = tid >> 6;
    #pragma unroll
    for (int j = 0; j < 8; ++j) {
        float v = acc[j] + bt1[o0 + j];
        v = v > 0.0f ? v : 0.0f;           // relu BEFORE spatial mean
        #pragma unroll
        for (int off = 32; off > 0; off >>= 1) v += __shfl_down(v, off);
        if (lane == 0) red[j * 4 + wv] = v;
    }
    __syncthreads();
    if (tid < 8) {
        float s = red[tid * 4] + red[tid * 4 + 1] + red[tid * 4 + 2] + red[tid * 4 + 3];
        part[(size_t)(n * 256 + o0 + tid) * 16 + pt] = s;
    }
}

// ---------------------------------------------------------------------------
// Kernel 3: finish GAP mean, w2=relu(Wt2 w1), w3=Wt3 w2, L2-normalize.
// out_w is FLOAT32 (reference output dtype).
// ---------------------------------------------------------------------------
__global__ void k_wvec(const float* __restrict__ part, const float* __restrict__ Wt2,
                       const float* __restrict__ Wt3, float* __restrict__ wvec,
                       float* __restrict__ out_w) {
    int n = blockIdx.x, tid = threadIdx.x;
    __shared__ float sm1[256];
    __shared__ float sm2[64];
    __shared__ float smr[4];
    float s = 0.0f;
    #pragma unroll
    for (int t = 0; t < 16; ++t) s += part[(size_t)(n * 256 + tid) * 16 + t];
    sm1[tid] = s * (1.0f / 4096.0f);
    __syncthreads();
    if (tid < 64) {
        float a = 0.0f;
        for (int c = 0; c < 256; ++c) a = fmaf(Wt2[tid * 256 + c], sm1[c], a);
        sm2[tid] = a > 0.0f ? a : 0.0f;
    }
    __syncthreads();
    float w3 = 0.0f;
    for (int e = 0; e < 64; ++e) w3 = fmaf(Wt3[tid * 64 + e], sm2[e], w3);
    float q = w3 * w3;
    int lane = tid & 63, wv = tid >> 6;
    #pragma unroll
    for (int off = 32; off > 0; off >>= 1) q += __shfl_down(q, off);
    if (lane == 0) smr[wv] = q;
    __syncthreads();
    float nrm = sqrtf(smr[0] + smr[1] + smr[2] + smr[3]);
    nrm = fmaxf(nrm, 1e-12f);
    float w = w3 / nrm;
    wvec[n * 256 + tid] = w;
    out_w[n * 256 + tid] = w;
}

// ---------------------------------------------------------------------------
// Kernel 4: bU = relu(W_U @ sx2 + b_U) * wvec   -> [8,256,4096] bf16
// ---------------------------------------------------------------------------
__global__ void k_bU(const float* __restrict__ sx2, const float* __restrict__ WU,
                     const float* __restrict__ bUbias, const float* __restrict__ wvec,
                     __hip_bfloat16* __restrict__ bUout) {
    int tid = threadIdx.x;
    int ot = blockIdx.x, pt = blockIdx.y, n = blockIdx.z;
    int p = pt * 256 + tid, o0 = ot * 8;
    float acc[8] = {0, 0, 0, 0, 0, 0, 0, 0};
    const float* xs = sx2 + ((size_t)n * 256) * PP + p;
    for (int c = 0; c < 256; ++c) {
        float v = xs[(size_t)c * PP];
        #pragma unroll
        for (int j = 0; j < 8; ++j)
            acc[j] = fmaf(WU[(o0 + j) * 256 + c], v, acc[j]);
    }
    #pragma unroll
    for (int j = 0; j < 8; ++j) {
        float v = acc[j] + bUbias[o0 + j];
        v = v > 0.0f ? v : 0.0f;
        v *= wvec[n * 256 + o0 + j];
        bUout[(size_t)(n * 256 + o0 + j) * PP + p] = __float2bfloat16(v);
    }
}

// ---------------------------------------------------------------------------
// Kernel 5: bV = relu(W_V @ bU + b_V)   -> [8,128,4096] bf16
// ---------------------------------------------------------------------------
__global__ void k_bV(const __hip_bfloat16* __restrict__ bUin, const float* __restrict__ WV,
                     const float* __restrict__ bVbias, __hip_bfloat16* __restrict__ bVout) {
    int tid = threadIdx.x;
    int ot = blockIdx.x, pt = blockIdx.y, n = blockIdx.z;
    int p = pt * 256 + tid, o0 = ot * 8;
    float acc[8] = {0, 0, 0, 0, 0, 0, 0, 0};
    const __hip_bfloat16* xs = bUin + ((size_t)n * 256) * PP + p;
    for (int c = 0; c < 256; ++c) {
        float v = __bfloat162float(xs[(size_t)c * PP]);
        #pragma unroll
        for (int j = 0; j < 8; ++j)
            acc[j] = fmaf(WV[(o0 + j) * 256 + c], v, acc[j]);
    }
    #pragma unroll
    for (int j = 0; j < 8; ++j) {
        float v = acc[j] + bVbias[o0 + j];
        v = v > 0.0f ? v : 0.0f;
        bVout[(size_t)(n * 128 + o0 + j) * PP + p] = __float2bfloat16(v);
    }
}

// ---------------------------------------------------------------------------
// Kernel 6: a1 = relu(W_a1 @ [bV; txc] + b_a1)   -> [8,128,4096] bf16
// ---------------------------------------------------------------------------
__global__ void k_a1(const __hip_bfloat16* __restrict__ bVin, const __hip_bfloat16* __restrict__ txc,
                     const float* __restrict__ Wa1, const float* __restrict__ ba1,
                     __hip_bfloat16* __restrict__ a1out) {
    int tid = threadIdx.x;
    int ot = blockIdx.x, pt = blockIdx.y, n = blockIdx.z;
    int p = pt * 256 + tid, o0 = ot * 8;
    float acc[8] = {0, 0, 0, 0, 0, 0, 0, 0};
    const __hip_bfloat16* xb = bVin + ((size_t)n * 128) * PP + p;
    for (int c = 0; c < 128; ++c) {
        float v = __bfloat162float(xb[(size_t)c * PP]);
        #pragma unroll
        for (int j = 0; j < 8; ++j)
            acc[j] = fmaf(Wa1[(o0 + j) * 640 + c], v, acc[j]);
    }
    const __hip_bfloat16* xt = txc + ((size_t)n * 512) * PP + p;
    for (int c = 0; c < 512; ++c) {
        float v = __bfloat162float(xt[(size_t)c * PP]);
        #pragma unroll
        for (int j = 0; j < 8; ++j)
            acc[j] = fmaf(Wa1[(o0 + j) * 640 + 128 + c], v, acc[j]);
    }
    #pragma unroll
    for (int j = 0; j < 8; ++j) {
        float v = acc[j] + ba1[o0 + j];
        v = v > 0.0f ? v : 0.0f;
        a1out[(size_t)(n * 128 + o0 + j) * PP + p] = __float2bfloat16(v);
    }
}

// ---------------------------------------------------------------------------
// Kernel 7: gate = sigmoid(W_a2 @ a1 + b_a2); channels 0..127 -> amulA = gate*bV,
// channels 128..639 -> txc *= gate (IN PLACE; each element read+written by the
// same thread exactly once; txc is rebuilt by k_txc every launch).
// ---------------------------------------------------------------------------
__global__ void k_amul(const __hip_bfloat16* __restrict__ a1in, const __hip_bfloat16* __restrict__ bVin,
                       __hip_bfloat16* __restrict__ txc, const float* __restrict__ Wa2,
                       const float* __restrict__ ba2, __hip_bfloat16* __restrict__ amulA) {
    int tid = threadIdx.x;
    int ot = blockIdx.x;   // 80 tiles of 8 (O = 640)
    int pt = blockIdx.y, n = blockIdx.z;
    int p = pt * 256 + tid, o0 = ot * 8;
    float acc[8] = {0, 0, 0, 0, 0, 0, 0, 0};
    const __hip_bfloat16* xs = a1in + ((size_t)n * 128) * PP + p;
    for (int c = 0; c < 128; ++c) {
        float v = __bfloat162float(xs[(size_t)c * PP]);
        #pragma unroll
        for (int j = 0; j < 8; ++j)
            acc[j] = fmaf(Wa2[(o0 + j) * 128 + c], v, acc[j]);
    }
    #pragma unroll
    for (int j = 0; j < 8; ++j) {
        int o = o0 + j;
        float x = acc[j] + ba2[o];
        float sg = 1.0f / (1.0f + expf(-x));
        if (o < 128) {
            float bval = __bfloat162float(bVin[(size_t)(n * 128 + o) * PP + p]);
            amulA[(size_t)(n * 128 + o) * PP + p] = __float2bfloat16(sg * bval);
        } else {
            size_t idx = ((size_t)(n * 512 + (o - 128))) * PP + p;
            float bval = __bfloat162float(txc[idx]);
            txc[idx] = __float2bfloat16(sg * bval);
        }
    }
}

// ---------------------------------------------------------------------------
// Kernel 8: out_a = relu(conv3x3([amulA; txc_gated], W_ot) + b_ot) -> FLOAT32
// ---------------------------------------------------------------------------
__global__ void k_conv3(const __hip_bfloat16* __restrict__ amulA, const __hip_bfloat16* __restrict__ txc,
                        const float* __restrict__ Wot, const float* __restrict__ bot,
                        float* __restrict__ out_a) {
    int tid = threadIdx.x;
    int ot = blockIdx.x;   // 32 tiles of 8 output channels
    int pt = blockIdx.y;   // 16 tiles of 4 rows
    int n  = blockIdx.z;
    int r = tid >> 6, x = tid & 63;
    int y = pt * 4 + r;
    int o0 = ot * 8;
    float acc[8] = {0, 0, 0, 0, 0, 0, 0, 0};
    for (int c = 0; c < 640; ++c) {
        const __hip_bfloat16* base = (c < 128)
            ? amulA + ((size_t)(n * 128 + c)) * PP
            : txc   + ((size_t)(n * 512 + (c - 128))) * PP;
        float v[3][3];
        #pragma unroll
        for (int dy = 0; dy < 3; ++dy) {
            int yy = y + dy - 1;
            #pragma unroll
            for (int dx = 0; dx < 3; ++dx) {
                int xx = x + dx - 1;
                bool ok = (yy >= 0) && (yy < HH) && (xx >= 0) && (xx < WW);
                v[dy][dx] = ok ? __bfloat162float(base[yy * WW + xx]) : 0.0f;
            }
        }
        #pragma unroll
        for (int j = 0; j < 8; ++j) {
            const float* w = Wot + ((size_t)((o0 + j) * 640 + c)) * 9;
            #pragma unroll
            for (int dy = 0; dy < 3; ++dy)
                #pragma unroll
                for (int dx = 0; dx < 3; ++dx)
                    acc[j] = fmaf(w[dy * 3 + dx], v[dy][dx], acc[j]);
        }
    }
    int p = y * WW + x;
    #pragma unroll
    for (int j = 0; j < 8; ++j) {
        float v = acc[j] + bot[o0 + j];
        v = v > 0.0f ? v : 0.0f;
        out_a[(size_t)(n * 256 + o0 + j) * PP + p] = v;
    }
}

// ---------------------------------------------------------------------------
extern "C" void kernel_launch(void* const* d_in, const int* in_sizes, int n_in,
                              void* d_out, int out_size, void* d_ws, size_t ws_size,
                              hipStream_t stream) {
    // Resolve inputs by element count (robust to dict vs key-sorted ordering;
    // proved equivalent to raw order in R1/R2 — kept as cheap insurance).
    static const int want[18] = {
        8388608,  // 0 sx1   [8,256,64,64]
        8388608,  // 1 sx2
        8388608,  // 2 t_hx
        2097152,  // 3 tx    [8,256,32,32]
        196608,   // 4 W_t1  [256,768]
        256,      // 5 b_t1  (zeros)
        16384,    // 6 W_t2  [64,256]
        16384,    // 7 W_t3  [256,64]
        65536,    // 8 W_U   [256,256]
        256,      // 9 b_U   (zeros)
        32768,    // 10 W_V  [128,256]
        128,      // 11 b_V  (zeros)
        81920,    // 12 W_a1 [128,640]
        128,      // 13 b_a1 (zeros)
        81920,    // 14 W_a2 [640,128]
        640,      // 15 b_a2 (zeros)
        1474560,  // 16 W_ot [256,640,3,3]
        256       // 17 b_ot (zeros)
    };
    const void* ptr[18];
    bool used[64];
    for (int i = 0; i < 64; ++i) used[i] = false;
    bool ok = (n_in >= 18 && n_in <= 64);
    for (int k = 0; k < 18 && ok; ++k) {
        ptr[k] = nullptr;
        for (int i = 0; i < n_in; ++i) {
            if (!used[i] && in_sizes[i] == want[k]) { ptr[k] = d_in[i]; used[i] = true; break; }
        }
        if (!ptr[k]) ok = false;
    }
    if (!ok) { for (int k = 0; k < 18; ++k) ptr[k] = d_in[k]; }

    const float* sx1  = (const float*)ptr[0];
    const float* sx2  = (const float*)ptr[1];
    const float* t_hx = (const float*)ptr[2];
    const float* tx   = (const float*)ptr[3];
    const float* Wt1  = (const float*)ptr[4];
    const float* bt1  = (const float*)ptr[5];
    const float* Wt2  = (const float*)ptr[6];
    const float* Wt3  = (const float*)ptr[7];
    const float* WU   = (const float*)ptr[8];
    const float* bU   = (const float*)ptr[9];
    const float* WV   = (const float*)ptr[10];
    const float* bV   = (const float*)ptr[11];
    const float* Wa1  = (const float*)ptr[12];
    const float* ba1  = (const float*)ptr[13];
    const float* Wa2  = (const float*)ptr[14];
    const float* ba2  = (const float*)ptr[15];
    const float* Wot  = (const float*)ptr[16];
    const float* bot  = (const float*)ptr[17];

    // Workspace layout (peak 58.9 MB; regions reused when dead):
    char* base = (char*)d_ws;
    __hip_bfloat16* txc  = (__hip_bfloat16*)base;                      // 33,554,432 B
    char* regB           = base + (size_t)33554432;                    // 16,777,216 B (bU)
    __hip_bfloat16* bUb  = (__hip_bfloat16*)regB;
    __hip_bfloat16* a1b  = (__hip_bfloat16*)regB;                      // reuses bU half 1 (bU dead)
    __hip_bfloat16* amulA= (__hip_bfloat16*)(regB + (size_t)8388608);  // reuses bU half 2
    __hip_bfloat16* bVb  = (__hip_bfloat16*)(base + (size_t)50331648); // 8,388,608 B
    float* part = (float*)(base + (size_t)58720256);                   // 131,072 B
    float* wvec = (float*)(base + (size_t)58851328);                   // 8,192 B

    float* out_a = (float*)d_out;                   // FLOAT32 output
    float* out_w = out_a + (size_t)8 * 256 * PP;    // second tuple element

    k_txc <<<dim3(16, 512, 8), 256, 0, stream>>>(t_hx, tx, txc);
    k_gap <<<dim3(32, 16, 8),  256, 0, stream>>>(sx1, txc, Wt1, bt1, part);
    k_wvec<<<dim3(8),          256, 0, stream>>>(part, Wt2, Wt3, wvec, out_w);
    k_bU  <<<dim3(32, 16, 8),  256, 0, stream>>>(sx2, WU, bU, wvec, bUb);
    k_bV  <<<dim3(16, 16, 8),  256, 0, stream>>>(bUb, WV, bV, bVb);
    k_a1  <<<dim3(16, 16, 8),  256, 0, stream>>>(bVb, txc, Wa1, ba1, a1b);
    k_amul<<<dim3(80, 16, 8),  256, 0, stream>>>(a1b, bVb, txc, Wa2, ba2, amulA);
    k_conv3<<<dim3(32, 16, 8), 256, 0, stream>>>(amulA, txc, Wot, bot, out_a);
}

// Round 4
// 1344.303 us; speedup vs baseline: 3.1302x; 3.1302x over previous
//
#include <hip/hip_runtime.h>
#include <hip/hip_bf16.h>

#define PP 4096          // H*W = 64*64
#define HH 64
#define WW 64

typedef __attribute__((ext_vector_type(8))) short short8b;   // 8 bf16 in 4 VGPRs
typedef __attribute__((ext_vector_type(4))) float f32x4;

// ---------------------------------------------------------------------------
// Kernel 1: txc = concat([t_hx, upsample2x_align_corners(tx)], C) -> [8,512,4096] bf16
// ---------------------------------------------------------------------------
__global__ void k_txc(const float* __restrict__ t_hx, const float* __restrict__ tx,
                      __hip_bfloat16* __restrict__ txc) {
    int tid = threadIdx.x;
    int pt = blockIdx.x;        // 16 pixel tiles of 256
    int c  = blockIdx.y;        // 512
    int n  = blockIdx.z;        // 8
    int p = pt * 256 + tid;
    float v;
    if (c < 256) {
        v = t_hx[((size_t)(n * 256 + c)) * PP + p];
    } else {
        int y = p >> 6, x = p & 63;
        const float s = 31.0f / 63.0f;   // align_corners scale for 32->64
        float fy = y * s, fx = x * s;
        int y0 = (int)fy, x0 = (int)fx;
        int y1 = min(y0 + 1, 31), x1 = min(x0 + 1, 31);
        float wy = fy - (float)y0, wx = fx - (float)x0;
        const float* t = tx + ((size_t)(n * 256 + (c - 256))) * 1024;
        float v00 = t[y0 * 32 + x0], v01 = t[y0 * 32 + x1];
        float v10 = t[y1 * 32 + x0], v11 = t[y1 * 32 + x1];
        v = (v00 * (1.0f - wy) + v10 * wy) * (1.0f - wx)
          + (v01 * (1.0f - wy) + v11 * wy) * wx;
    }
    txc[((size_t)(n * 512 + c)) * PP + p] = __float2bfloat16(v);
}

// ---------------------------------------------------------------------------
// Kernel 2: per-pixel relu(W_t1 @ [sx1; txc] + b_t1), partial sum over pixel tile
// ---------------------------------------------------------------------------
__global__ void k_gap(const float* __restrict__ sx1, const __hip_bfloat16* __restrict__ txc,
                      const float* __restrict__ Wt1, const float* __restrict__ bt1,
                      float* __restrict__ part) {
    int tid = threadIdx.x;
    int ot = blockIdx.x;   // 32 tiles of 8 output channels
    int pt = blockIdx.y;   // 16 pixel tiles
    int n  = blockIdx.z;
    int p = pt * 256 + tid;
    int o0 = ot * 8;
    float acc[8] = {0, 0, 0, 0, 0, 0, 0, 0};
    const float* xs = sx1 + ((size_t)n * 256) * PP + p;
    for (int c = 0; c < 256; ++c) {
        float v = xs[(size_t)c * PP];
        #pragma unroll
        for (int j = 0; j < 8; ++j)
            acc[j] = fmaf(Wt1[(o0 + j) * 768 + c], v, acc[j]);
    }
    const __hip_bfloat16* xt = txc + ((size_t)n * 512) * PP + p;
    for (int c = 0; c < 512; ++c) {
        float v = __bfloat162float(xt[(size_t)c * PP]);
        #pragma unroll
        for (int j = 0; j < 8; ++j)
            acc[j] = fmaf(Wt1[(o0 + j) * 768 + 256 + c], v, acc[j]);
    }
    __shared__ float red[8 * 4];
    int lane = tid & 63, wv = tid >> 6;
    #pragma unroll
    for (int j = 0; j < 8; ++j) {
        float v = acc[j] + bt1[o0 + j];
        v = v > 0.0f ? v : 0.0f;           // relu BEFORE spatial mean
        #pragma unroll
        for (int off = 32; off > 0; off >>= 1) v += __shfl_down(v, off);
        if (lane == 0) red[j * 4 + wv] = v;
    }
    __syncthreads();
    if (tid < 8) {
        float s = red[tid * 4] + red[tid * 4 + 1] + red[tid * 4 + 2] + red[tid * 4 + 3];
        part[(size_t)(n * 256 + o0 + tid) * 16 + pt] = s;
    }
}

// ---------------------------------------------------------------------------
// Kernel 3: finish GAP mean, w2=relu(Wt2 w1), w3=Wt3 w2, L2-normalize. out_w f32.
// ---------------------------------------------------------------------------
__global__ void k_wvec(const float* __restrict__ part, const float* __restrict__ Wt2,
                       const float* __restrict__ Wt3, float* __restrict__ wvec,
                       float* __restrict__ out_w) {
    int n = blockIdx.x, tid = threadIdx.x;
    __shared__ float sm1[256];
    __shared__ float sm2[64];
    __shared__ float smr[4];
    float s = 0.0f;
    #pragma unroll
    for (int t = 0; t < 16; ++t) s += part[(size_t)(n * 256 + tid) * 16 + t];
    sm1[tid] = s * (1.0f / 4096.0f);
    __syncthreads();
    if (tid < 64) {
        float a = 0.0f;
        for (int c = 0; c < 256; ++c) a = fmaf(Wt2[tid * 256 + c], sm1[c], a);
        sm2[tid] = a > 0.0f ? a : 0.0f;
    }
    __syncthreads();
    float w3 = 0.0f;
    for (int e = 0; e < 64; ++e) w3 = fmaf(Wt3[tid * 64 + e], sm2[e], w3);
    float q = w3 * w3;
    int lane = tid & 63, wv = tid >> 6;
    #pragma unroll
    for (int off = 32; off > 0; off >>= 1) q += __shfl_down(q, off);
    if (lane == 0) smr[wv] = q;
    __syncthreads();
    float nrm = sqrtf(smr[0] + smr[1] + smr[2] + smr[3]);
    nrm = fmaxf(nrm, 1e-12f);
    float w = w3 / nrm;
    wvec[n * 256 + tid] = w;
    out_w[n * 256 + tid] = w;
}

// ---------------------------------------------------------------------------
// Kernel 4: bU = relu(W_U @ sx2 + b_U) * wvec   -> [8,256,4096] bf16
// ---------------------------------------------------------------------------
__global__ void k_bU(const float* __restrict__ sx2, const float* __restrict__ WU,
                     const float* __restrict__ bUbias, const float* __restrict__ wvec,
                     __hip_bfloat16* __restrict__ bUout) {
    int tid = threadIdx.x;
    int ot = blockIdx.x, pt = blockIdx.y, n = blockIdx.z;
    int p = pt * 256 + tid, o0 = ot * 8;
    float acc[8] = {0, 0, 0, 0, 0, 0, 0, 0};
    const float* xs = sx2 + ((size_t)n * 256) * PP + p;
    for (int c = 0; c < 256; ++c) {
        float v = xs[(size_t)c * PP];
        #pragma unroll
        for (int j = 0; j < 8; ++j)
            acc[j] = fmaf(WU[(o0 + j) * 256 + c], v, acc[j]);
    }
    #pragma unroll
    for (int j = 0; j < 8; ++j) {
        float v = acc[j] + bUbias[o0 + j];
        v = v > 0.0f ? v : 0.0f;
        v *= wvec[n * 256 + o0 + j];
        bUout[(size_t)(n * 256 + o0 + j) * PP + p] = __float2bfloat16(v);
    }
}

// ---------------------------------------------------------------------------
// Kernel 5: bV = relu(W_V @ bU + b_V)   -> [8,128,4096] bf16
// ---------------------------------------------------------------------------
__global__ void k_bV(const __hip_bfloat16* __restrict__ bUin, const float* __restrict__ WV,
                     const float* __restrict__ bVbias, __hip_bfloat16* __restrict__ bVout) {
    int tid = threadIdx.x;
    int ot = blockIdx.x, pt = blockIdx.y, n = blockIdx.z;
    int p = pt * 256 + tid, o0 = ot * 8;
    float acc[8] = {0, 0, 0, 0, 0, 0, 0, 0};
    const __hip_bfloat16* xs = bUin + ((size_t)n * 256) * PP + p;
    for (int c = 0; c < 256; ++c) {
        float v = __bfloat162float(xs[(size_t)c * PP]);
        #pragma unroll
        for (int j = 0; j < 8; ++j)
            acc[j] = fmaf(WV[(o0 + j) * 256 + c], v, acc[j]);
    }
    #pragma unroll
    for (int j = 0; j < 8; ++j) {
        float v = acc[j] + bVbias[o0 + j];
        v = v > 0.0f ? v : 0.0f;
        bVout[(size_t)(n * 128 + o0 + j) * PP + p] = __float2bfloat16(v);
    }
}

// ---------------------------------------------------------------------------
// Kernel 6: a1 = relu(W_a1 @ [bV; txc] + b_a1)   -> [8,128,4096] bf16
// ---------------------------------------------------------------------------
__global__ void k_a1(const __hip_bfloat16* __restrict__ bVin, const __hip_bfloat16* __restrict__ txc,
                     const float* __restrict__ Wa1, const float* __restrict__ ba1,
                     __hip_bfloat16* __restrict__ a1out) {
    int tid = threadIdx.x;
    int ot = blockIdx.x, pt = blockIdx.y, n = blockIdx.z;
    int p = pt * 256 + tid, o0 = ot * 8;
    float acc[8] = {0, 0, 0, 0, 0, 0, 0, 0};
    const __hip_bfloat16* xb = bVin + ((size_t)n * 128) * PP + p;
    for (int c = 0; c < 128; ++c) {
        float v = __bfloat162float(xb[(size_t)c * PP]);
        #pragma unroll
        for (int j = 0; j < 8; ++j)
            acc[j] = fmaf(Wa1[(o0 + j) * 640 + c], v, acc[j]);
    }
    const __hip_bfloat16* xt = txc + ((size_t)n * 512) * PP + p;
    for (int c = 0; c < 512; ++c) {
        float v = __bfloat162float(xt[(size_t)c * PP]);
        #pragma unroll
        for (int j = 0; j < 8; ++j)
            acc[j] = fmaf(Wa1[(o0 + j) * 640 + 128 + c], v, acc[j]);
    }
    #pragma unroll
    for (int j = 0; j < 8; ++j) {
        float v = acc[j] + ba1[o0 + j];
        v = v > 0.0f ? v : 0.0f;
        a1out[(size_t)(n * 128 + o0 + j) * PP + p] = __float2bfloat16(v);
    }
}

// ---------------------------------------------------------------------------
// Kernel 7: gate = sigmoid(W_a2 @ a1 + b_a2); ch<128 -> amulA = gate*bV (NCHW);
// ch>=128 -> txc *= gate in place.
// ---------------------------------------------------------------------------
__global__ void k_amul(const __hip_bfloat16* __restrict__ a1in, const __hip_bfloat16* __restrict__ bVin,
                       __hip_bfloat16* __restrict__ txc, const float* __restrict__ Wa2,
                       const float* __restrict__ ba2, __hip_bfloat16* __restrict__ amulA) {
    int tid = threadIdx.x;
    int ot = blockIdx.x;   // 80 tiles of 8 (O = 640)
    int pt = blockIdx.y, n = blockIdx.z;
    int p = pt * 256 + tid, o0 = ot * 8;
    float acc[8] = {0, 0, 0, 0, 0, 0, 0, 0};
    const __hip_bfloat16* xs = a1in + ((size_t)n * 128) * PP + p;
    for (int c = 0; c < 128; ++c) {
        float v = __bfloat162float(xs[(size_t)c * PP]);
        #pragma unroll
        for (int j = 0; j < 8; ++j)
            acc[j] = fmaf(Wa2[(o0 + j) * 128 + c], v, acc[j]);
    }
    #pragma unroll
    for (int j = 0; j < 8; ++j) {
        int o = o0 + j;
        float x = acc[j] + ba2[o];
        float sg = 1.0f / (1.0f + expf(-x));
        if (o < 128) {
            float bval = __bfloat162float(bVin[(size_t)(n * 128 + o) * PP + p]);
            amulA[(size_t)(n * 128 + o) * PP + p] = __float2bfloat16(sg * bval);
        } else {
            size_t idx = ((size_t)(n * 512 + (o - 128))) * PP + p;
            float bval = __bfloat162float(txc[idx]);
            txc[idx] = __float2bfloat16(sg * bval);
        }
    }
}

// ---------------------------------------------------------------------------
// NEW Kernel 7b: NCHW -> NHWC transpose of the 640-ch conv input.
// amulH[n][p][640] bf16. LDS 64x68 tile: both global phases coalesced,
// LDS strides 2-way-conflict max (free per m136).
// ---------------------------------------------------------------------------
__global__ void k_nhwc(const __hip_bfloat16* __restrict__ amulA, const __hip_bfloat16* __restrict__ txc,
                       __hip_bfloat16* __restrict__ amulH) {
    __shared__ short T[64 * 68];
    int tid = threadIdx.x;
    int p0 = blockIdx.x * 64;
    int c0 = blockIdx.y * 64;
    int n  = blockIdx.z;
    #pragma unroll
    for (int it = 0; it < 16; ++it) {
        int idx = tid + it * 256;
        int ch = idx >> 6, px = idx & 63;
        int cg = c0 + ch;
        const __hip_bfloat16* src = (cg < 128)
            ? amulA + ((size_t)(n * 128 + cg)) * PP + p0 + px
            : txc   + ((size_t)(n * 512 + (cg - 128))) * PP + p0 + px;
        T[px * 68 + ch] = *(const short*)src;
    }
    __syncthreads();
    #pragma unroll
    for (int it = 0; it < 16; ++it) {
        int idx = tid + it * 256;
        int ch = idx & 63, px = idx >> 6;
        ((short*)amulH)[((size_t)(n * PP + p0 + px)) * 640 + c0 + ch] = T[px * 68 + ch];
    }
}

// ---------------------------------------------------------------------------
// NEW Kernel 7c: weight prep. Wot f32 [256][640][3][3] ->
// Wfrag bf16 in exact A-fragment order: [k9][cc][mt][ks][lane][8]
// lane holds o = mt*16+(lane&15), ch = cc*64+ks*32+(lane>>4)*8 .. +8.
// ---------------------------------------------------------------------------
__global__ void k_wprep(const float* __restrict__ Wot, short* __restrict__ Wfrag) {
    int s = blockIdx.x * 256 + threadIdx.x;      // 184320 slots of 8
    int lane = s & 63;
    int rest = s >> 6;
    int ks = rest & 1;  rest >>= 1;
    int mt = rest & 15; rest >>= 4;
    int cc = rest % 10;
    int k9 = rest / 10;
    int o   = mt * 16 + (lane & 15);
    int ch0 = cc * 64 + ks * 32 + (lane >> 4) * 8;
    short8b v{};
    #pragma unroll
    for (int j = 0; j < 8; ++j) {
        float w = Wot[((size_t)o * 640 + ch0 + j) * 9 + k9];
        __hip_bfloat16 h = __float2bfloat16(w);
        v[j] = *reinterpret_cast<short*>(&h);
    }
    ((short8b*)Wfrag)[s] = v;
}

// ---------------------------------------------------------------------------
// NEW Kernel 8: MFMA implicit-GEMM conv3x3. Block = 256 thr (4 waves, 2m x 2n),
// tile 128 outch x 128 pixels (2 image rows). K-loop: 10 ch-chunks x 9 taps.
// LDS: X tile [4 rows][66 halo cols][64 ch] bf16, XOR-swizzled (T2 analog).
// ---------------------------------------------------------------------------
__global__ __launch_bounds__(256) void k_conv3_mfma(
        const __hip_bfloat16* __restrict__ amulH, const short* __restrict__ Wfrag,
        const float* __restrict__ bot, float* __restrict__ out_a) {
    __shared__ short lds_x[4 * 66 * 64];   // 33792 B
    const int tid  = threadIdx.x;
    const int lane = tid & 63;
    const int wid  = tid >> 6;
    const int mw = wid & 1, nw = wid >> 1;
    const int bx = blockIdx.x;   // outch half (0..1)
    const int by = blockIdx.y;   // row-pair (0..31)
    const int n  = blockIdx.z;

    f32x4 acc[4][4] = {};

    const short8b* wf = (const short8b*)Wfrag;
    for (int cc = 0; cc < 10; ++cc) {
        __syncthreads();
        {   // stage chunk cc: rows 2*by-1..2*by+2, 64 ch, halo cols zeroed
            const int c0 = cc * 64;
            #pragma unroll
            for (int it = 0; it < 8; ++it) {
                int idx = tid + it * 256;
                int rr = idx >> 9, col = (idx >> 3) & 63, cg = idx & 7;
                int gr = by * 2 - 1 + rr;
                short8b v{};
                if (gr >= 0 && gr < 64) {
                    const short* src = (const short*)amulH
                        + ((size_t)(n * PP + gr * 64 + col)) * 640 + c0 + cg * 8;
                    v = *(const short8b*)src;
                }
                int chc = col + 1;
                int elem = ((rr * 66 + chc) * 64 + cg * 8) ^ ((chc & 7) << 3);
                *(short8b*)&lds_x[elem] = v;
            }
            if (tid < 64) {
                int rr = tid >> 4, side = (tid >> 3) & 1, cg = tid & 7;
                int chc = side ? 65 : 0;
                int elem = ((rr * 66 + chc) * 64 + cg * 8) ^ ((chc & 7) << 3);
                short8b z{};
                *(short8b*)&lds_x[elem] = z;
            }
        }
        __syncthreads();
        // compute chunk: 9 taps x (2 ks x 4 mf x 4 nf) MFMAs
        for (int k9 = 0; k9 < 9; ++k9) {
            const int ky = k9 / 3, kx = k9 % 3;   // offsets -1 folded into +1 halo
            short8b afr[4][2];
            #pragma unroll
            for (int mf = 0; mf < 4; ++mf) {
                int mt_g = bx * 8 + mw * 4 + mf;
                #pragma unroll
                for (int ks = 0; ks < 2; ++ks) {
                    size_t fidx = (((size_t)(k9 * 10 + cc) * 16 + mt_g) * 2 + ks) * 64 + lane;
                    afr[mf][ks] = wf[fidx];
                }
            }
            short8b bfr[4][2];
            #pragma unroll
            for (int nf = 0; nf < 4; ++nf) {
                int x = nf * 16 + (lane & 15);
                int chc = x + kx;            // x + (kx-1) + 1
                int row_eff = nw + ky;       // nw + (ky-1) + 1
                #pragma unroll
                for (int ks = 0; ks < 2; ++ks) {
                    int elem = ((row_eff * 66 + chc) * 64 + ks * 32 + (lane >> 4) * 8)
                               ^ ((chc & 7) << 3);
                    bfr[nf][ks] = *(const short8b*)&lds_x[elem];
                }
            }
            #pragma unroll
            for (int ks = 0; ks < 2; ++ks)
                #pragma unroll
                for (int mf = 0; mf < 4; ++mf)
                    #pragma unroll
                    for (int nf = 0; nf < 4; ++nf)
                        acc[mf][nf] = __builtin_amdgcn_mfma_f32_16x16x32_bf16(
                            afr[mf][ks], bfr[nf][ks], acc[mf][nf], 0, 0, 0);
        }
    }
    // epilogue: bias + relu, f32 NCHW store (16-lane 64B runs)
    #pragma unroll
    for (int mf = 0; mf < 4; ++mf) {
        int o = bx * 128 + mw * 64 + mf * 16 + (lane >> 4) * 4;
        #pragma unroll
        for (int r = 0; r < 4; ++r) {
            float bias = bot[o + r];
            #pragma unroll
            for (int nf = 0; nf < 4; ++nf) {
                int p = by * 128 + nw * 64 + nf * 16 + (lane & 15);
                float v = acc[mf][nf][r] + bias;
                out_a[((size_t)(n * 256 + o + r)) * PP + p] = v > 0.f ? v : 0.f;
            }
        }
    }
}

// ---------------------------------------------------------------------------
// Fallback scalar conv3x3 (R3-verified) for small ws_size.
// ---------------------------------------------------------------------------
__global__ void k_conv3(const __hip_bfloat16* __restrict__ amulA, const __hip_bfloat16* __restrict__ txc,
                        const float* __restrict__ Wot, const float* __restrict__ bot,
                        float* __restrict__ out_a) {
    int tid = threadIdx.x;
    int ot = blockIdx.x;
    int pt = blockIdx.y;
    int n  = blockIdx.z;
    int r = tid >> 6, x = tid & 63;
    int y = pt * 4 + r;
    int o0 = ot * 8;
    float acc[8] = {0, 0, 0, 0, 0, 0, 0, 0};
    for (int c = 0; c < 640; ++c) {
        const __hip_bfloat16* base = (c < 128)
            ? amulA + ((size_t)(n * 128 + c)) * PP
            : txc   + ((size_t)(n * 512 + (c - 128))) * PP;
        float v[3][3];
        #pragma unroll
        for (int dy = 0; dy < 3; ++dy) {
            int yy = y + dy - 1;
            #pragma unroll
            for (int dx = 0; dx < 3; ++dx) {
                int xx = x + dx - 1;
                bool okb = (yy >= 0) && (yy < HH) && (xx >= 0) && (xx < WW);
                v[dy][dx] = okb ? __bfloat162float(base[yy * WW + xx]) : 0.0f;
            }
        }
        #pragma unroll
        for (int j = 0; j < 8; ++j) {
            const float* w = Wot + ((size_t)((o0 + j) * 640 + c)) * 9;
            #pragma unroll
            for (int dy = 0; dy < 3; ++dy)
                #pragma unroll
                for (int dx = 0; dx < 3; ++dx)
                    acc[j] = fmaf(w[dy * 3 + dx], v[dy][dx], acc[j]);
        }
    }
    int p = y * WW + x;
    #pragma unroll
    for (int j = 0; j < 8; ++j) {
        float v = acc[j] + bot[o0 + j];
        v = v > 0.0f ? v : 0.0f;
        out_a[(size_t)(n * 256 + o0 + j) * PP + p] = v;
    }
}

// ---------------------------------------------------------------------------
extern "C" void kernel_launch(void* const* d_in, const int* in_sizes, int n_in,
                              void* d_out, int out_size, void* d_ws, size_t ws_size,
                              hipStream_t stream) {
    static const int want[18] = {
        8388608, 8388608, 8388608, 2097152, 196608, 256, 16384, 16384,
        65536, 256, 32768, 128, 81920, 128, 81920, 640, 1474560, 256
    };
    const void* ptr[18];
    bool used[64];
    for (int i = 0; i < 64; ++i) used[i] = false;
    bool ok = (n_in >= 18 && n_in <= 64);
    for (int k = 0; k < 18 && ok; ++k) {
        ptr[k] = nullptr;
        for (int i = 0; i < n_in; ++i) {
            if (!used[i] && in_sizes[i] == want[k]) { ptr[k] = d_in[i]; used[i] = true; break; }
        }
        if (!ptr[k]) ok = false;
    }
    if (!ok) { for (int k = 0; k < 18; ++k) ptr[k] = d_in[k]; }

    const float* sx1  = (const float*)ptr[0];
    const float* sx2  = (const float*)ptr[1];
    const float* t_hx = (const float*)ptr[2];
    const float* tx   = (const float*)ptr[3];
    const float* Wt1  = (const float*)ptr[4];
    const float* bt1  = (const float*)ptr[5];
    const float* Wt2  = (const float*)ptr[6];
    const float* Wt3  = (const float*)ptr[7];
    const float* WU   = (const float*)ptr[8];
    const float* bU   = (const float*)ptr[9];
    const float* WV   = (const float*)ptr[10];
    const float* bV   = (const float*)ptr[11];
    const float* Wa1  = (const float*)ptr[12];
    const float* ba1  = (const float*)ptr[13];
    const float* Wa2  = (const float*)ptr[14];
    const float* ba2  = (const float*)ptr[15];
    const float* Wot  = (const float*)ptr[16];
    const float* bot  = (const float*)ptr[17];

    // Workspace layout:
    //   [0,33.55M)      txc (gated in place by k_amul; rebuilt every launch)
    //   [33.55M,41.94M) a1b  -> dead after k_amul -> reused for Wfrag (2.95M)
    //   [33.55M,50.33M) regB: bU (a1b = first half, amulA = second half)
    //   [50.33M,58.72M) bVb
    //   [58.72M,58.85M) part ; [58.85M,58.86M) wvec
    //   [58.86M,100.80M) amulH (NHWC conv input)   <- new-path only
    char* base = (char*)d_ws;
    __hip_bfloat16* txc  = (__hip_bfloat16*)base;
    char* regB           = base + (size_t)33554432;
    __hip_bfloat16* bUb  = (__hip_bfloat16*)regB;
    __hip_bfloat16* a1b  = (__hip_bfloat16*)regB;
    __hip_bfloat16* amulA= (__hip_bfloat16*)(regB + (size_t)8388608);
    __hip_bfloat16* bVb  = (__hip_bfloat16*)(base + (size_t)50331648);
    float* part = (float*)(base + (size_t)58720256);
    float* wvec = (float*)(base + (size_t)58851328);
    __hip_bfloat16* amulH = (__hip_bfloat16*)(base + (size_t)58859520);   // 41.94 MB
    short* Wfrag = (short*)(base + (size_t)33554432);                     // over dead a1b, 2.95 MB
    const size_t NEED_MFMA = (size_t)58859520 + (size_t)8 * PP * 640 * 2; // 100,802,560

    float* out_a = (float*)d_out;
    float* out_w = out_a + (size_t)8 * 256 * PP;

    k_txc <<<dim3(16, 512, 8), 256, 0, stream>>>(t_hx, tx, txc);
    k_gap <<<dim3(32, 16, 8),  256, 0, stream>>>(sx1, txc, Wt1, bt1, part);
    k_wvec<<<dim3(8),          256, 0, stream>>>(part, Wt2, Wt3, wvec, out_w);
    k_bU  <<<dim3(32, 16, 8),  256, 0, stream>>>(sx2, WU, bU, wvec, bUb);
    k_bV  <<<dim3(16, 16, 8),  256, 0, stream>>>(bUb, WV, bV, bVb);
    k_a1  <<<dim3(16, 16, 8),  256, 0, stream>>>(bVb, txc, Wa1, ba1, a1b);
    k_amul<<<dim3(80, 16, 8),  256, 0, stream>>>(a1b, bVb, txc, Wa2, ba2, amulA);

    if (ws_size >= NEED_MFMA) {
        k_wprep<<<dim3(720),        256, 0, stream>>>(Wot, Wfrag);     // a1b dead now
        k_nhwc <<<dim3(64, 10, 8),  256, 0, stream>>>(amulA, txc, amulH);
        k_conv3_mfma<<<dim3(2, 32, 8), 256, 0, stream>>>(amulH, Wfrag, bot, out_a);
    } else {
        k_conv3<<<dim3(32, 16, 8), 256, 0, stream>>>(amulA, txc, Wot, bot, out_a);
    }
}

// Round 5
// 434.835 us; speedup vs baseline: 9.6770x; 3.0915x over previous
//
#include <hip/hip_runtime.h>
#include <hip/hip_bf16.h>

#define PP 4096          // H*W
#define HH 64
#define WW 64

typedef __attribute__((ext_vector_type(8))) short short8b;   // 8 bf16
typedef __attribute__((ext_vector_type(4))) float f32x4;

static __device__ __forceinline__ float bf2f(short s) {
    union { unsigned int u; float f; } cv; cv.u = ((unsigned int)(unsigned short)s) << 16; return cv.f;
}
static __device__ __forceinline__ short f2bf(float f) {
    __hip_bfloat16 h = __float2bfloat16(f);
    return *reinterpret_cast<short*>(&h);
}

// ---------------------------------------------------------------------------
// Pack f32 weight [M][K] (O,C row-major) into MFMA B-fragment order bf16:
// slot s -> [cc][mt][ks][lane], lane holds o=mt*16+(lane&15),
// ch = cc*64+ks*32+(lane>>4)*8 .. +8. (Same order as R4-validated k_wprep.)
// ---------------------------------------------------------------------------
__global__ void k_wpack(const float* __restrict__ W, short* __restrict__ dst,
                        int MT, int K) {
    int s = blockIdx.x * 256 + threadIdx.x;
    int total = MT * 2 * (K / 64) * 64;      // short8b slots
    if (s >= total) return;
    int lane = s & 63;
    int rest = s >> 6;
    int ks = rest & 1; rest >>= 1;
    int mt = rest % MT;
    int cc = rest / MT;
    int o   = mt * 16 + (lane & 15);
    int ch0 = cc * 64 + ks * 32 + (lane >> 4) * 8;
    short8b v;
    #pragma unroll
    for (int j = 0; j < 8; ++j) v[j] = f2bf(W[(size_t)o * K + ch0 + j]);
    ((short8b*)dst)[s] = v;
}

// ---------------------------------------------------------------------------
// f32 NCHW -> bf16 NHWC transpose (LDS 64x64 tile, +1 pad).
// dst row pitch `pitch` shorts, column offset colOff.
// ---------------------------------------------------------------------------
__global__ void k_t2h(const float* __restrict__ src, short* __restrict__ dst,
                      int C, int P, int pitch, int colOff) {
    __shared__ short T[64 * 65];
    int tid = threadIdx.x;
    int p0 = blockIdx.x * 64, c0 = blockIdx.y * 64, n = blockIdx.z;
    #pragma unroll
    for (int it = 0; it < 16; ++it) {
        int slot = it * 256 + tid;
        int ch = slot >> 6, px = slot & 63;
        T[ch * 65 + px] = f2bf(src[((size_t)(n * C + c0 + ch)) * P + p0 + px]);
    }
    __syncthreads();
    #pragma unroll
    for (int it = 0; it < 16; ++it) {
        int slot = it * 256 + tid;
        int px = slot >> 6, ch = slot & 63;
        dst[((size_t)n * P + p0 + px) * pitch + colOff + c0 + ch] = T[ch * 65 + px];
    }
}

// ---------------------------------------------------------------------------
// Bilinear 2x upsample (align_corners) from txh NHWC [n][1024][256] into
// txc cols 256..511 (pitch 512). 256 thr = 8 px x 32 ch-groups.
// ---------------------------------------------------------------------------
__global__ void k_up(const short* __restrict__ txh, short* __restrict__ txc) {
    int tid = threadIdx.x;
    int cg = tid & 31, pxl = tid >> 5;
    int px = blockIdx.x * 8 + pxl;
    int n  = blockIdx.z;
    int y = px >> 6, x = px & 63;
    const float s = 31.0f / 63.0f;
    float fy = y * s, fx = x * s;
    int y0 = (int)fy, x0 = (int)fx;
    int y1 = min(y0 + 1, 31), x1 = min(x0 + 1, 31);
    float wy = fy - (float)y0, wx = fx - (float)x0;
    const short8b* base = (const short8b*)(txh + ((size_t)n * 1024) * 256);
    short8b a = base[((size_t)(y0 * 32 + x0) * 256 + cg * 8) >> 3];
    short8b b = base[((size_t)(y0 * 32 + x1) * 256 + cg * 8) >> 3];
    short8b c = base[((size_t)(y1 * 32 + x0) * 256 + cg * 8) >> 3];
    short8b d = base[((size_t)(y1 * 32 + x1) * 256 + cg * 8) >> 3];
    short8b r;
    #pragma unroll
    for (int j = 0; j < 8; ++j) {
        float v = (bf2f(a[j]) * (1.f - wy) + bf2f(c[j]) * wy) * (1.f - wx)
                + (bf2f(b[j]) * (1.f - wy) + bf2f(d[j]) * wy) * wx;
        r[j] = f2bf(v);
    }
    *(short8b*)(txc + ((size_t)n * PP + px) * 512 + 256 + cg * 8) = r;
}

// ---------------------------------------------------------------------------
// Shared GEMM helpers: LDS tile [128 px][64 ch] bf16, XOR-swizzled.
// ---------------------------------------------------------------------------
static __device__ __forceinline__ void stage64(const short* __restrict__ src, int pitch,
                                               int c0, size_t rowbase, short* lds, int tid) {
    #pragma unroll
    for (int it = 0; it < 4; ++it) {
        int idx = it * 256 + tid;
        int px = idx >> 3, cg = idx & 7;
        short8b v = *(const short8b*)(src + (rowbase + px) * (size_t)pitch + c0 + cg * 8);
        int elem = (px * 64 + cg * 8) ^ ((px & 7) << 3);
        *(short8b*)&lds[elem] = v;
    }
}
static __device__ __forceinline__ short8b afrag(const short* lds, int pw, int mf, int ks, int lane) {
    int px = pw * 64 + mf * 16 + (lane & 15);
    int elem = (px * 64 + ks * 32 + ((lane >> 4) * 8)) ^ ((px & 7) << 3);
    return *(const short8b*)&lds[elem];
}
#define GEMM_PROLOG \
    int tid = threadIdx.x, lane = tid & 63, wid = tid >> 6; \
    int pw = wid & 1, ow = wid >> 1; \
    int bx = blockIdx.x, pt = blockIdx.y, n = blockIdx.z; \
    size_t rowbase = (size_t)n * PP + pt * 128; \
    f32x4 acc[4][4] = {}; (void)bx;
#define GEMM_STEP(MT) { \
    short8b afr[4][2], bfr[4][2]; \
    _Pragma("unroll") for (int mf = 0; mf < 4; ++mf) \
        _Pragma("unroll") for (int ks = 0; ks < 2; ++ks) afr[mf][ks] = afrag(lds, pw, mf, ks, lane); \
    _Pragma("unroll") for (int nf = 0; nf < 4; ++nf) { \
        int mt_g = bx * 8 + ow * 4 + nf; \
        _Pragma("unroll") for (int ks = 0; ks < 2; ++ks) \
            bfr[nf][ks] = wfv[(((size_t)cc * (MT) + mt_g) * 2 + ks) * 64 + lane]; } \
    _Pragma("unroll") for (int ks = 0; ks < 2; ++ks) \
        _Pragma("unroll") for (int mf = 0; mf < 4; ++mf) \
            _Pragma("unroll") for (int nf = 0; nf < 4; ++nf) \
                acc[mf][nf] = __builtin_amdgcn_mfma_f32_16x16x32_bf16(afr[mf][ks], bfr[nf][ks], acc[mf][nf], 0, 0, 0); }

// ---------------------------------------------------------------------------
// GAP GEMM: D[128px][128o] over K=768 ([sxh1 256ch; txc 512ch]); epilogue
// relu(+bias) then sum over px -> part[n][256][32].
// ---------------------------------------------------------------------------
__global__ __launch_bounds__(256) void k_gemm_gap(const short* __restrict__ sxh1,
        const short* __restrict__ txc, const short* __restrict__ wf,
        const float* __restrict__ bias, float* __restrict__ part) {
    __shared__ short lds[128 * 64];
    __shared__ float red[128 * 2];
    GEMM_PROLOG
    const short8b* wfv = (const short8b*)wf;
    for (int cc = 0; cc < 12; ++cc) {
        __syncthreads();
        if (cc < 4) stage64(sxh1, 256, cc * 64, rowbase, lds, tid);
        else        stage64(txc, 512, (cc - 4) * 64, rowbase, lds, tid);
        __syncthreads();
        GEMM_STEP(16)
    }
    #pragma unroll
    for (int nf = 0; nf < 4; ++nf) {
        int o = bx * 128 + ow * 64 + nf * 16 + (lane & 15);
        float b = bias[o];
        float s = 0.f;
        #pragma unroll
        for (int mf = 0; mf < 4; ++mf)
            #pragma unroll
            for (int r = 0; r < 4; ++r) {
                float v = acc[mf][nf][r] + b;
                s += v > 0.f ? v : 0.f;
            }
        s += __shfl_xor(s, 16);
        s += __shfl_xor(s, 32);
        if (lane < 16) red[(ow * 64 + nf * 16 + lane) * 2 + pw] = s;
    }
    __syncthreads();
    if (tid < 128)
        part[((size_t)n * 256 + bx * 128 + tid) * 32 + pt] = red[tid * 2] + red[tid * 2 + 1];
}

// ---------------------------------------------------------------------------
// bU GEMM: K=256 (sxh2); epilogue relu(+bias)*wvec -> bUh NHWC [n][px][256].
// ---------------------------------------------------------------------------
__global__ __launch_bounds__(256) void k_gemm_bU(const short* __restrict__ sxh2,
        const short* __restrict__ wf, const float* __restrict__ bias,
        const float* __restrict__ wvec, short* __restrict__ bUh) {
    __shared__ short lds[128 * 64];
    GEMM_PROLOG
    const short8b* wfv = (const short8b*)wf;
    for (int cc = 0; cc < 4; ++cc) {
        __syncthreads();
        stage64(sxh2, 256, cc * 64, rowbase, lds, tid);
        __syncthreads();
        GEMM_STEP(16)
    }
    #pragma unroll
    for (int nf = 0; nf < 4; ++nf) {
        int o = bx * 128 + ow * 64 + nf * 16 + (lane & 15);
        float b = bias[o], wv = wvec[n * 256 + o];
        #pragma unroll
        for (int mf = 0; mf < 4; ++mf)
            #pragma unroll
            for (int r = 0; r < 4; ++r) {
                int px = pw * 64 + mf * 16 + (lane >> 4) * 4 + r;
                float v = acc[mf][nf][r] + b;
                v = v > 0.f ? v : 0.f;
                bUh[(rowbase + px) * 256 + o] = f2bf(v * wv);
            }
    }
}

// ---------------------------------------------------------------------------
// bV GEMM: M=128 (bx=0), K=256 (bUh); relu -> bVh [n][px][128].
// ---------------------------------------------------------------------------
__global__ __launch_bounds__(256) void k_gemm_bV(const short* __restrict__ bUh,
        const short* __restrict__ wf, const float* __restrict__ bias,
        short* __restrict__ bVh) {
    __shared__ short lds[128 * 64];
    GEMM_PROLOG
    const short8b* wfv = (const short8b*)wf;
    for (int cc = 0; cc < 4; ++cc) {
        __syncthreads();
        stage64(bUh, 256, cc * 64, rowbase, lds, tid);
        __syncthreads();
        GEMM_STEP(8)
    }
    #pragma unroll
    for (int nf = 0; nf < 4; ++nf) {
        int o = ow * 64 + nf * 16 + (lane & 15);
        float b = bias[o];
        #pragma unroll
        for (int mf = 0; mf < 4; ++mf)
            #pragma unroll
            for (int r = 0; r < 4; ++r) {
                int px = pw * 64 + mf * 16 + (lane >> 4) * 4 + r;
                float v = acc[mf][nf][r] + b;
                bVh[(rowbase + px) * 128 + o] = f2bf(v > 0.f ? v : 0.f);
            }
    }
}

// ---------------------------------------------------------------------------
// a1 GEMM: M=128 (bx=0), K=640 ([bVh 128; txc 512]); relu -> a1h [n][px][128].
// ---------------------------------------------------------------------------
__global__ __launch_bounds__(256) void k_gemm_a1(const short* __restrict__ bVh,
        const short* __restrict__ txc, const short* __restrict__ wf,
        const float* __restrict__ bias, short* __restrict__ a1h) {
    __shared__ short lds[128 * 64];
    GEMM_PROLOG
    const short8b* wfv = (const short8b*)wf;
    for (int cc = 0; cc < 10; ++cc) {
        __syncthreads();
        if (cc < 2) stage64(bVh, 128, cc * 64, rowbase, lds, tid);
        else        stage64(txc, 512, (cc - 2) * 64, rowbase, lds, tid);
        __syncthreads();
        GEMM_STEP(8)
    }
    #pragma unroll
    for (int nf = 0; nf < 4; ++nf) {
        int o = ow * 64 + nf * 16 + (lane & 15);
        float b = bias[o];
        #pragma unroll
        for (int mf = 0; mf < 4; ++mf)
            #pragma unroll
            for (int r = 0; r < 4; ++r) {
                int px = pw * 64 + mf * 16 + (lane >> 4) * 4 + r;
                float v = acc[mf][nf][r] + b;
                a1h[(rowbase + px) * 128 + o] = f2bf(v > 0.f ? v : 0.f);
            }
    }
}

// ---------------------------------------------------------------------------
// amul GEMM: M=640 (bx 0..4), K=128 (a1h); epilogue sigmoid * [bVh;txc]
// -> amulH NHWC [n][px][640].
// ---------------------------------------------------------------------------
__global__ __launch_bounds__(256) void k_gemm_amul(const short* __restrict__ a1h,
        const short* __restrict__ wf, const float* __restrict__ bias,
        const short* __restrict__ bVh, const short* __restrict__ txc,
        short* __restrict__ amulH) {
    __shared__ short lds[128 * 64];
    GEMM_PROLOG
    const short8b* wfv = (const short8b*)wf;
    for (int cc = 0; cc < 2; ++cc) {
        __syncthreads();
        stage64(a1h, 128, cc * 64, rowbase, lds, tid);
        __syncthreads();
        GEMM_STEP(40)
    }
    #pragma unroll
    for (int nf = 0; nf < 4; ++nf) {
        int o = bx * 128 + ow * 64 + nf * 16 + (lane & 15);
        float b = bias[o];
        #pragma unroll
        for (int mf = 0; mf < 4; ++mf)
            #pragma unroll
            for (int r = 0; r < 4; ++r) {
                int px = pw * 64 + mf * 16 + (lane >> 4) * 4 + r;
                float xv = acc[mf][nf][r] + b;
                float sg = 1.0f / (1.0f + expf(-xv));
                float bval = (o < 128) ? bf2f(bVh[(rowbase + px) * 128 + o])
                                       : bf2f(txc[(rowbase + px) * 512 + o - 128]);
                amulH[(rowbase + px) * 640 + o] = f2bf(sg * bval);
            }
    }
}

// ---------------------------------------------------------------------------
// GAP finish (mean over 32 tiles), w2=relu(Wt2 w1), w3=Wt3 w2, L2-normalize.
// ---------------------------------------------------------------------------
__global__ void k_wvec(const float* __restrict__ part, const float* __restrict__ Wt2,
                       const float* __restrict__ Wt3, float* __restrict__ wvec,
                       float* __restrict__ out_w) {
    int n = blockIdx.x, tid = threadIdx.x;
    __shared__ float sm1[256];
    __shared__ float sm2[64];
    __shared__ float smr[4];
    float s = 0.0f;
    #pragma unroll
    for (int t = 0; t < 32; ++t) s += part[(size_t)(n * 256 + tid) * 32 + t];
    sm1[tid] = s * (1.0f / 4096.0f);
    __syncthreads();
    if (tid < 64) {
        float a = 0.0f;
        for (int c = 0; c < 256; ++c) a = fmaf(Wt2[tid * 256 + c], sm1[c], a);
        sm2[tid] = a > 0.0f ? a : 0.0f;
    }
    __syncthreads();
    float w3 = 0.0f;
    for (int e = 0; e < 64; ++e) w3 = fmaf(Wt3[tid * 64 + e], sm2[e], w3);
    float q = w3 * w3;
    int lane = tid & 63, wv = tid >> 6;
    #pragma unroll
    for (int off = 32; off > 0; off >>= 1) q += __shfl_down(q, off);
    if (lane == 0) smr[wv] = q;
    __syncthreads();
    float nrm = sqrtf(smr[0] + smr[1] + smr[2] + smr[3]);
    nrm = fmaxf(nrm, 1e-12f);
    float w = w3 / nrm;
    wvec[n * 256 + tid] = w;
    out_w[n * 256 + tid] = w;
}

// ---------------------------------------------------------------------------
// Conv weight prep (R4-validated): Wot f32 [256][640][3][3] -> A-fragment bf16
// [k9][cc][mt][ks][lane][8].
// ---------------------------------------------------------------------------
__global__ void k_wprep(const float* __restrict__ Wot, short* __restrict__ Wfrag) {
    int s = blockIdx.x * 256 + threadIdx.x;
    int lane = s & 63;
    int rest = s >> 6;
    int ks = rest & 1;  rest >>= 1;
    int mt = rest & 15; rest >>= 4;
    int cc = rest % 10;
    int k9 = rest / 10;
    int o   = mt * 16 + (lane & 15);
    int ch0 = cc * 64 + ks * 32 + (lane >> 4) * 8;
    short8b v{};
    #pragma unroll
    for (int j = 0; j < 8; ++j)
        v[j] = f2bf(Wot[((size_t)o * 640 + ch0 + j) * 9 + k9]);
    ((short8b*)Wfrag)[s] = v;
}

// ---------------------------------------------------------------------------
// MFMA implicit-GEMM conv3x3 (R4-validated). Reads amulH NHWC, writes f32 NCHW.
// ---------------------------------------------------------------------------
__global__ __launch_bounds__(256) void k_conv3_mfma(
        const __hip_bfloat16* __restrict__ amulH, const short* __restrict__ Wfrag,
        const float* __restrict__ bot, float* __restrict__ out_a) {
    __shared__ short lds_x[4 * 66 * 64];   // 33792 B
    const int tid  = threadIdx.x;
    const int lane = tid & 63;
    const int wid  = tid >> 6;
    const int mw = wid & 1, nw = wid >> 1;
    const int bx = blockIdx.x;
    const int by = blockIdx.y;
    const int n  = blockIdx.z;

    f32x4 acc[4][4] = {};

    const short8b* wf = (const short8b*)Wfrag;
    for (int cc = 0; cc < 10; ++cc) {
        __syncthreads();
        {
            const int c0 = cc * 64;
            #pragma unroll
            for (int it = 0; it < 8; ++it) {
                int idx = tid + it * 256;
                int rr = idx >> 9, col = (idx >> 3) & 63, cg = idx & 7;
                int gr = by * 2 - 1 + rr;
                short8b v{};
                if (gr >= 0 && gr < 64) {
                    const short* src = (const short*)amulH
                        + ((size_t)(n * PP + gr * 64 + col)) * 640 + c0 + cg * 8;
                    v = *(const short8b*)src;
                }
                int chc = col + 1;
                int elem = ((rr * 66 + chc) * 64 + cg * 8) ^ ((chc & 7) << 3);
                *(short8b*)&lds_x[elem] = v;
            }
            if (tid < 64) {
                int rr = tid >> 4, side = (tid >> 3) & 1, cg = tid & 7;
                int chc = side ? 65 : 0;
                int elem = ((rr * 66 + chc) * 64 + cg * 8) ^ ((chc & 7) << 3);
                short8b z{};
                *(short8b*)&lds_x[elem] = z;
            }
        }
        __syncthreads();
        for (int k9 = 0; k9 < 9; ++k9) {
            const int ky = k9 / 3, kx = k9 % 3;
            short8b afr[4][2];
            #pragma unroll
            for (int mf = 0; mf < 4; ++mf) {
                int mt_g = bx * 8 + mw * 4 + mf;
                #pragma unroll
                for (int ks = 0; ks < 2; ++ks) {
                    size_t fidx = (((size_t)(k9 * 10 + cc) * 16 + mt_g) * 2 + ks) * 64 + lane;
                    afr[mf][ks] = wf[fidx];
                }
            }
            short8b bfr[4][2];
            #pragma unroll
            for (int nf = 0; nf < 4; ++nf) {
                int x = nf * 16 + (lane & 15);
                int chc = x + kx;
                int row_eff = nw + ky;
                #pragma unroll
                for (int ks = 0; ks < 2; ++ks) {
                    int elem = ((row_eff * 66 + chc) * 64 + ks * 32 + (lane >> 4) * 8)
                               ^ ((chc & 7) << 3);
                    bfr[nf][ks] = *(const short8b*)&lds_x[elem];
                }
            }
            #pragma unroll
            for (int ks = 0; ks < 2; ++ks)
                #pragma unroll
                for (int mf = 0; mf < 4; ++mf)
                    #pragma unroll
                    for (int nf = 0; nf < 4; ++nf)
                        acc[mf][nf] = __builtin_amdgcn_mfma_f32_16x16x32_bf16(
                            afr[mf][ks], bfr[nf][ks], acc[mf][nf], 0, 0, 0);
        }
    }
    #pragma unroll
    for (int mf = 0; mf < 4; ++mf) {
        int o = bx * 128 + mw * 64 + mf * 16 + (lane >> 4) * 4;
        #pragma unroll
        for (int r = 0; r < 4; ++r) {
            float bias = bot[o + r];
            #pragma unroll
            for (int nf = 0; nf < 4; ++nf) {
                int p = by * 128 + nw * 64 + nf * 16 + (lane & 15);
                float v = acc[mf][nf][r] + bias;
                out_a[((size_t)(n * 256 + o + r)) * PP + p] = v > 0.f ? v : 0.f;
            }
        }
    }
}

// ---------------------------------------------------------------------------
extern "C" void kernel_launch(void* const* d_in, const int* in_sizes, int n_in,
                              void* d_out, int out_size, void* d_ws, size_t ws_size,
                              hipStream_t stream) {
    static const int want[18] = {
        8388608, 8388608, 8388608, 2097152, 196608, 256, 16384, 16384,
        65536, 256, 32768, 128, 81920, 128, 81920, 640, 1474560, 256
    };
    const void* ptr[18];
    bool used[64];
    for (int i = 0; i < 64; ++i) used[i] = false;
    bool ok = (n_in >= 18 && n_in <= 64);
    for (int k = 0; k < 18 && ok; ++k) {
        ptr[k] = nullptr;
        for (int i = 0; i < n_in; ++i) {
            if (!used[i] && in_sizes[i] == want[k]) { ptr[k] = d_in[i]; used[i] = true; break; }
        }
        if (!ptr[k]) ok = false;
    }
    if (!ok) { for (int k = 0; k < 18; ++k) ptr[k] = d_in[k]; }

    const float* sx1  = (const float*)ptr[0];
    const float* sx2  = (const float*)ptr[1];
    const float* t_hx = (const float*)ptr[2];
    const float* tx   = (const float*)ptr[3];
    const float* Wt1  = (const float*)ptr[4];
    const float* bt1  = (const float*)ptr[5];
    const float* Wt2  = (const float*)ptr[6];
    const float* Wt3  = (const float*)ptr[7];
    const float* WU   = (const float*)ptr[8];
    const float* bU   = (const float*)ptr[9];
    const float* WV   = (const float*)ptr[10];
    const float* bV   = (const float*)ptr[11];
    const float* Wa1  = (const float*)ptr[12];
    const float* ba1  = (const float*)ptr[13];
    const float* Wa2  = (const float*)ptr[14];
    const float* ba2  = (const float*)ptr[15];
    const float* Wot  = (const float*)ptr[16];
    const float* bot  = (const float*)ptr[17];

    // Workspace (peak 96.42 MB; R4 proved ws_size >= 100.80 MB):
    //   [0, 33.55M)        txc NHWC [8][4096][512]
    //   [33.55M, 75.50M)   amulH [8][4096][640] (written last);
    //                      before that: sxh1 @+33.55M (16.78M), sxh2 @+50.33M (16.78M),
    //                      bUh over sxh1 (alive only between bU and bV)
    //   [75.50M, 83.89M)   bVh [8][4096][128]; txh (4.19M) lives here early
    //   [83.89M, 92.27M)   a1h [8][4096][128]
    //   [92.27M, 92.54M)   part [8][256][32] f32 ; [92.54M, 92.55M) wvec
    //   [92.55M, 93.46M)   packed 1x1 weights ; [93.46M, 96.42M) conv Wfrag
    char* base = (char*)d_ws;
    short* txc   = (short*)base;
    short* sxh1  = (short*)(base + (size_t)33554432);
    short* sxh2  = (short*)(base + (size_t)50331648);
    short* bUh   = sxh1;                                   // reuse (sxh1 dead after gap)
    short* amulH = (short*)(base + (size_t)33554432);
    short* txh   = (short*)(base + (size_t)75497472);
    short* bVh   = (short*)(base + (size_t)75497472);
    short* a1h   = (short*)(base + (size_t)83886080);
    float* part  = (float*)(base + (size_t)92274688);
    float* wvec  = (float*)(base + (size_t)92536832);
    short* Wt1p  = (short*)(base + (size_t)92545024);      // 393216 B
    short* WUp   = (short*)(base + (size_t)92938240);      // 131072 B
    short* WVp   = (short*)(base + (size_t)93069312);      // 65536 B
    short* Wa1p  = (short*)(base + (size_t)93134848);      // 163840 B
    short* Wa2p  = (short*)(base + (size_t)93298688);      // 163840 B
    short* Wotp  = (short*)(base + (size_t)93462528);      // 2949120 B

    float* out_a = (float*)d_out;
    float* out_w = out_a + (size_t)8 * 256 * PP;

    // weight packs (independent of activations)
    k_wpack<<<dim3(96), 256, 0, stream>>>(Wt1, Wt1p, 16, 768);
    k_wpack<<<dim3(32), 256, 0, stream>>>(WU,  WUp,  16, 256);
    k_wpack<<<dim3(16), 256, 0, stream>>>(WV,  WVp,   8, 256);
    k_wpack<<<dim3(40), 256, 0, stream>>>(Wa1, Wa1p,  8, 640);
    k_wpack<<<dim3(40), 256, 0, stream>>>(Wa2, Wa2p, 40, 128);
    k_wprep<<<dim3(720), 256, 0, stream>>>(Wot, Wotp);

    // layout conversion: f32 NCHW -> bf16 NHWC
    k_t2h<<<dim3(64, 4, 8), 256, 0, stream>>>(sx1,  sxh1, 256, 4096, 256, 0);
    k_t2h<<<dim3(64, 4, 8), 256, 0, stream>>>(sx2,  sxh2, 256, 4096, 256, 0);
    k_t2h<<<dim3(64, 4, 8), 256, 0, stream>>>(t_hx, txc,  256, 4096, 512, 0);
    k_t2h<<<dim3(16, 4, 8), 256, 0, stream>>>(tx,   txh,  256, 1024, 256, 0);
    k_up <<<dim3(512, 1, 8), 256, 0, stream>>>(txh, txc);

    // main pipeline
    k_gemm_gap <<<dim3(2, 32, 8), 256, 0, stream>>>(sxh1, txc, Wt1p, bt1, part);
    k_wvec     <<<dim3(8),        256, 0, stream>>>(part, Wt2, Wt3, wvec, out_w);
    k_gemm_bU  <<<dim3(2, 32, 8), 256, 0, stream>>>(sxh2, WUp, bU, wvec, bUh);
    k_gemm_bV  <<<dim3(1, 32, 8), 256, 0, stream>>>(bUh, WVp, bV, bVh);
    k_gemm_a1  <<<dim3(1, 32, 8), 256, 0, stream>>>(bVh, txc, Wa1p, ba1, a1h);
    k_gemm_amul<<<dim3(5, 32, 8), 256, 0, stream>>>(a1h, Wa2p, ba2, bVh, txc, amulH);
    k_conv3_mfma<<<dim3(2, 32, 8), 256, 0, stream>>>((const __hip_bfloat16*)amulH, Wotp, bot, out_a);
}

// Round 6
// 420.449 us; speedup vs baseline: 10.0081x; 1.0342x over previous
//
#include <hip/hip_runtime.h>
#include <hip/hip_bf16.h>

#define PP 4096          // H*W
#define HH 64
#define WW 64

typedef __attribute__((ext_vector_type(8))) short short8b;   // 8 bf16
typedef __attribute__((ext_vector_type(4))) float f32x4;

static __device__ __forceinline__ float bf2f(short s) {
    union { unsigned int u; float f; } cv; cv.u = ((unsigned int)(unsigned short)s) << 16; return cv.f;
}
static __device__ __forceinline__ short f2bf(float f) {
    __hip_bfloat16 h = __float2bfloat16(f);
    return *reinterpret_cast<short*>(&h);
}

// ---------------------------------------------------------------------------
// Pack f32 weight [M][K] (O,C row-major) into MFMA B-fragment order bf16:
// slot s -> [cc][mt][ks][lane], lane holds o=mt*16+(lane&15),
// ch = cc*64+ks*32+(lane>>4)*8 .. +8.
// ---------------------------------------------------------------------------
__global__ void k_wpack(const float* __restrict__ W, short* __restrict__ dst,
                        int MT, int K) {
    int s = blockIdx.x * 256 + threadIdx.x;
    int total = MT * 2 * (K / 64) * 64;      // short8b slots
    if (s >= total) return;
    int lane = s & 63;
    int rest = s >> 6;
    int ks = rest & 1; rest >>= 1;
    int mt = rest % MT;
    int cc = rest / MT;
    int o   = mt * 16 + (lane & 15);
    int ch0 = cc * 64 + ks * 32 + (lane >> 4) * 8;
    short8b v;
    #pragma unroll
    for (int j = 0; j < 8; ++j) v[j] = f2bf(W[(size_t)o * K + ch0 + j]);
    ((short8b*)dst)[s] = v;
}

// ---------------------------------------------------------------------------
// f32 NCHW -> bf16 NHWC transpose (LDS 64x64 tile, +1 pad).
// ---------------------------------------------------------------------------
__global__ void k_t2h(const float* __restrict__ src, short* __restrict__ dst,
                      int C, int P, int pitch, int colOff) {
    __shared__ short T[64 * 65];
    int tid = threadIdx.x;
    int p0 = blockIdx.x * 64, c0 = blockIdx.y * 64, n = blockIdx.z;
    #pragma unroll
    for (int it = 0; it < 16; ++it) {
        int slot = it * 256 + tid;
        int ch = slot >> 6, px = slot & 63;
        T[ch * 65 + px] = f2bf(src[((size_t)(n * C + c0 + ch)) * P + p0 + px]);
    }
    __syncthreads();
    #pragma unroll
    for (int it = 0; it < 16; ++it) {
        int slot = it * 256 + tid;
        int px = slot >> 6, ch = slot & 63;
        dst[((size_t)n * P + p0 + px) * pitch + colOff + c0 + ch] = T[ch * 65 + px];
    }
}

// ---------------------------------------------------------------------------
// Bilinear 2x upsample (align_corners) txh NHWC [n][1024][256] -> txc cols 256..511.
// ---------------------------------------------------------------------------
__global__ void k_up(const short* __restrict__ txh, short* __restrict__ txc) {
    int tid = threadIdx.x;
    int cg = tid & 31, pxl = tid >> 5;
    int px = blockIdx.x * 8 + pxl;
    int n  = blockIdx.z;
    int y = px >> 6, x = px & 63;
    const float s = 31.0f / 63.0f;
    float fy = y * s, fx = x * s;
    int y0 = (int)fy, x0 = (int)fx;
    int y1 = min(y0 + 1, 31), x1 = min(x0 + 1, 31);
    float wy = fy - (float)y0, wx = fx - (float)x0;
    const short8b* base = (const short8b*)(txh + ((size_t)n * 1024) * 256);
    short8b a = base[((size_t)(y0 * 32 + x0) * 256 + cg * 8) >> 3];
    short8b b = base[((size_t)(y0 * 32 + x1) * 256 + cg * 8) >> 3];
    short8b c = base[((size_t)(y1 * 32 + x0) * 256 + cg * 8) >> 3];
    short8b d = base[((size_t)(y1 * 32 + x1) * 256 + cg * 8) >> 3];
    short8b r;
    #pragma unroll
    for (int j = 0; j < 8; ++j) {
        float v = (bf2f(a[j]) * (1.f - wy) + bf2f(c[j]) * wy) * (1.f - wx)
                + (bf2f(b[j]) * (1.f - wy) + bf2f(d[j]) * wy) * wx;
        r[j] = f2bf(v);
    }
    *(short8b*)(txc + ((size_t)n * PP + px) * 512 + 256 + cg * 8) = r;
}

// ---------------------------------------------------------------------------
// Shared GEMM helpers: LDS tile [128 px][64 ch] bf16, XOR-swizzled.
// ---------------------------------------------------------------------------
static __device__ __forceinline__ void stage64(const short* __restrict__ src, int pitch,
                                               int c0, size_t rowbase, short* lds, int tid) {
    #pragma unroll
    for (int it = 0; it < 4; ++it) {
        int idx = it * 256 + tid;
        int px = idx >> 3, cg = idx & 7;
        short8b v = *(const short8b*)(src + (rowbase + px) * (size_t)pitch + c0 + cg * 8);
        int elem = (px * 64 + cg * 8) ^ ((px & 7) << 3);
        *(short8b*)&lds[elem] = v;
    }
}
static __device__ __forceinline__ short8b afrag(const short* lds, int pw, int mf, int ks, int lane) {
    int px = pw * 64 + mf * 16 + (lane & 15);
    int elem = (px * 64 + ks * 32 + ((lane >> 4) * 8)) ^ ((px & 7) << 3);
    return *(const short8b*)&lds[elem];
}
#define GEMM_PROLOG \
    int tid = threadIdx.x, lane = tid & 63, wid = tid >> 6; \
    int pw = wid & 1, ow = wid >> 1; \
    int bx = blockIdx.x, pt = blockIdx.y, n = blockIdx.z; \
    size_t rowbase = (size_t)n * PP + pt * 128; \
    f32x4 acc[4][4] = {}; (void)bx;
#define GEMM_STEP(MT) { \
    short8b afr[4][2], bfr[4][2]; \
    _Pragma("unroll") for (int mf = 0; mf < 4; ++mf) \
        _Pragma("unroll") for (int ks = 0; ks < 2; ++ks) afr[mf][ks] = afrag(lds, pw, mf, ks, lane); \
    _Pragma("unroll") for (int nf = 0; nf < 4; ++nf) { \
        int mt_g = bx * 8 + ow * 4 + nf; \
        _Pragma("unroll") for (int ks = 0; ks < 2; ++ks) \
            bfr[nf][ks] = wfv[(((size_t)cc * (MT) + mt_g) * 2 + ks) * 64 + lane]; } \
    _Pragma("unroll") for (int ks = 0; ks < 2; ++ks) \
        _Pragma("unroll") for (int mf = 0; mf < 4; ++mf) \
            _Pragma("unroll") for (int nf = 0; nf < 4; ++nf) \
                acc[mf][nf] = __builtin_amdgcn_mfma_f32_16x16x32_bf16(afr[mf][ks], bfr[nf][ks], acc[mf][nf], 0, 0, 0); }

// ---------------------------------------------------------------------------
// GAP GEMM: D[128px][128o] over K=768; epilogue relu(+bias), px-sum -> part.
// ---------------------------------------------------------------------------
__global__ __launch_bounds__(256) void k_gemm_gap(const short* __restrict__ sxh1,
        const short* __restrict__ txc, const short* __restrict__ wf,
        const float* __restrict__ bias, float* __restrict__ part) {
    __shared__ short lds[128 * 64];
    __shared__ float red[128 * 2];
    GEMM_PROLOG
    const short8b* wfv = (const short8b*)wf;
    for (int cc = 0; cc < 12; ++cc) {
        __syncthreads();
        if (cc < 4) stage64(sxh1, 256, cc * 64, rowbase, lds, tid);
        else        stage64(txc, 512, (cc - 4) * 64, rowbase, lds, tid);
        __syncthreads();
        GEMM_STEP(16)
    }
    #pragma unroll
    for (int nf = 0; nf < 4; ++nf) {
        int o = bx * 128 + ow * 64 + nf * 16 + (lane & 15);
        float b = bias[o];
        float s = 0.f;
        #pragma unroll
        for (int mf = 0; mf < 4; ++mf)
            #pragma unroll
            for (int r = 0; r < 4; ++r) {
                float v = acc[mf][nf][r] + b;
                s += v > 0.f ? v : 0.f;
            }
        s += __shfl_xor(s, 16);
        s += __shfl_xor(s, 32);
        if (lane < 16) red[(ow * 64 + nf * 16 + lane) * 2 + pw] = s;
    }
    __syncthreads();
    if (tid < 128)
        part[((size_t)n * 256 + bx * 128 + tid) * 32 + pt] = red[tid * 2] + red[tid * 2 + 1];
}

// ---------------------------------------------------------------------------
// bU GEMM: K=256; relu(+bias)*wvec -> bUh NHWC [n][px][256].
// ---------------------------------------------------------------------------
__global__ __launch_bounds__(256) void k_gemm_bU(const short* __restrict__ sxh2,
        const short* __restrict__ wf, const float* __restrict__ bias,
        const float* __restrict__ wvec, short* __restrict__ bUh) {
    __shared__ short lds[128 * 64];
    GEMM_PROLOG
    const short8b* wfv = (const short8b*)wf;
    for (int cc = 0; cc < 4; ++cc) {
        __syncthreads();
        stage64(sxh2, 256, cc * 64, rowbase, lds, tid);
        __syncthreads();
        GEMM_STEP(16)
    }
    #pragma unroll
    for (int nf = 0; nf < 4; ++nf) {
        int o = bx * 128 + ow * 64 + nf * 16 + (lane & 15);
        float b = bias[o], wv = wvec[n * 256 + o];
        #pragma unroll
        for (int mf = 0; mf < 4; ++mf)
            #pragma unroll
            for (int r = 0; r < 4; ++r) {
                int px = pw * 64 + mf * 16 + (lane >> 4) * 4 + r;
                float v = acc[mf][nf][r] + b;
                v = v > 0.f ? v : 0.f;
                bUh[(rowbase + px) * 256 + o] = f2bf(v * wv);
            }
    }
}

// ---------------------------------------------------------------------------
// bV GEMM: M=128, K=256 (bUh); relu -> bVh [n][px][128].
// ---------------------------------------------------------------------------
__global__ __launch_bounds__(256) void k_gemm_bV(const short* __restrict__ bUh,
        const short* __restrict__ wf, const float* __restrict__ bias,
        short* __restrict__ bVh) {
    __shared__ short lds[128 * 64];
    GEMM_PROLOG
    const short8b* wfv = (const short8b*)wf;
    for (int cc = 0; cc < 4; ++cc) {
        __syncthreads();
        stage64(bUh, 256, cc * 64, rowbase, lds, tid);
        __syncthreads();
        GEMM_STEP(8)
    }
    #pragma unroll
    for (int nf = 0; nf < 4; ++nf) {
        int o = ow * 64 + nf * 16 + (lane & 15);
        float b = bias[o];
        #pragma unroll
        for (int mf = 0; mf < 4; ++mf)
            #pragma unroll
            for (int r = 0; r < 4; ++r) {
                int px = pw * 64 + mf * 16 + (lane >> 4) * 4 + r;
                float v = acc[mf][nf][r] + b;
                bVh[(rowbase + px) * 128 + o] = f2bf(v > 0.f ? v : 0.f);
            }
    }
}

// ---------------------------------------------------------------------------
// a1 GEMM: M=128, K=640 ([bVh;txc]); relu -> a1h [n][px][128].
// ---------------------------------------------------------------------------
__global__ __launch_bounds__(256) void k_gemm_a1(const short* __restrict__ bVh,
        const short* __restrict__ txc, const short* __restrict__ wf,
        const float* __restrict__ bias, short* __restrict__ a1h) {
    __shared__ short lds[128 * 64];
    GEMM_PROLOG
    const short8b* wfv = (const short8b*)wf;
    for (int cc = 0; cc < 10; ++cc) {
        __syncthreads();
        if (cc < 2) stage64(bVh, 128, cc * 64, rowbase, lds, tid);
        else        stage64(txc, 512, (cc - 2) * 64, rowbase, lds, tid);
        __syncthreads();
        GEMM_STEP(8)
    }
    #pragma unroll
    for (int nf = 0; nf < 4; ++nf) {
        int o = ow * 64 + nf * 16 + (lane & 15);
        float b = bias[o];
        #pragma unroll
        for (int mf = 0; mf < 4; ++mf)
            #pragma unroll
            for (int r = 0; r < 4; ++r) {
                int px = pw * 64 + mf * 16 + (lane >> 4) * 4 + r;
                float v = acc[mf][nf][r] + b;
                a1h[(rowbase + px) * 128 + o] = f2bf(v > 0.f ? v : 0.f);
            }
    }
}

// ---------------------------------------------------------------------------
// amul GEMM: M=640, K=128 (a1h); sigmoid * [bVh;txc] -> amulH NHWC [n][px][640].
// ---------------------------------------------------------------------------
__global__ __launch_bounds__(256) void k_gemm_amul(const short* __restrict__ a1h,
        const short* __restrict__ wf, const float* __restrict__ bias,
        const short* __restrict__ bVh, const short* __restrict__ txc,
        short* __restrict__ amulH) {
    __shared__ short lds[128 * 64];
    GEMM_PROLOG
    const short8b* wfv = (const short8b*)wf;
    for (int cc = 0; cc < 2; ++cc) {
        __syncthreads();
        stage64(a1h, 128, cc * 64, rowbase, lds, tid);
        __syncthreads();
        GEMM_STEP(40)
    }
    #pragma unroll
    for (int nf = 0; nf < 4; ++nf) {
        int o = bx * 128 + ow * 64 + nf * 16 + (lane & 15);
        float b = bias[o];
        #pragma unroll
        for (int mf = 0; mf < 4; ++mf)
            #pragma unroll
            for (int r = 0; r < 4; ++r) {
                int px = pw * 64 + mf * 16 + (lane >> 4) * 4 + r;
                float xv = acc[mf][nf][r] + b;
                float sg = 1.0f / (1.0f + expf(-xv));
                float bval = (o < 128) ? bf2f(bVh[(rowbase + px) * 128 + o])
                                       : bf2f(txc[(rowbase + px) * 512 + o - 128]);
                amulH[(rowbase + px) * 640 + o] = f2bf(sg * bval);
            }
    }
}

// ---------------------------------------------------------------------------
// GAP finish + squeeze MLP + L2-normalize.
// ---------------------------------------------------------------------------
__global__ void k_wvec(const float* __restrict__ part, const float* __restrict__ Wt2,
                       const float* __restrict__ Wt3, float* __restrict__ wvec,
                       float* __restrict__ out_w) {
    int n = blockIdx.x, tid = threadIdx.x;
    __shared__ float sm1[256];
    __shared__ float sm2[64];
    __shared__ float smr[4];
    float s = 0.0f;
    #pragma unroll
    for (int t = 0; t < 32; ++t) s += part[(size_t)(n * 256 + tid) * 32 + t];
    sm1[tid] = s * (1.0f / 4096.0f);
    __syncthreads();
    if (tid < 64) {
        float a = 0.0f;
        for (int c = 0; c < 256; ++c) a = fmaf(Wt2[tid * 256 + c], sm1[c], a);
        sm2[tid] = a > 0.0f ? a : 0.0f;
    }
    __syncthreads();
    float w3 = 0.0f;
    for (int e = 0; e < 64; ++e) w3 = fmaf(Wt3[tid * 64 + e], sm2[e], w3);
    float q = w3 * w3;
    int lane = tid & 63, wv = tid >> 6;
    #pragma unroll
    for (int off = 32; off > 0; off >>= 1) q += __shfl_down(q, off);
    if (lane == 0) smr[wv] = q;
    __syncthreads();
    float nrm = sqrtf(smr[0] + smr[1] + smr[2] + smr[3]);
    nrm = fmaxf(nrm, 1e-12f);
    float w = w3 / nrm;
    wvec[n * 256 + tid] = w;
    out_w[n * 256 + tid] = w;
}

// ---------------------------------------------------------------------------
// Conv weight prep (R4-validated): Wot f32 [256][640][3][3] -> A-fragment bf16
// [k9][cc][mt][ks][lane][8].
// ---------------------------------------------------------------------------
__global__ void k_wprep(const float* __restrict__ Wot, short* __restrict__ Wfrag) {
    int s = blockIdx.x * 256 + threadIdx.x;
    int lane = s & 63;
    int rest = s >> 6;
    int ks = rest & 1;  rest >>= 1;
    int mt = rest & 15; rest >>= 4;
    int cc = rest % 10;
    int k9 = rest / 10;
    int o   = mt * 16 + (lane & 15);
    int ch0 = cc * 64 + ks * 32 + (lane >> 4) * 8;
    short8b v{};
    #pragma unroll
    for (int j = 0; j < 8; ++j)
        v[j] = f2bf(Wot[((size_t)o * 640 + ch0 + j) * 9 + k9]);
    ((short8b*)Wfrag)[s] = v;
}

// ---------------------------------------------------------------------------
// MFMA implicit-GEMM conv3x3, v2: tile 128o x 64px (1 image row), grid
// (2,64,8)=1024 blocks -> 4 blocks/CU. T14 async-stage: next chunk's global
// loads issued before current chunk's MFMAs; halo zeroed once.
// ---------------------------------------------------------------------------
__global__ __launch_bounds__(256, 4) void k_conv3_mfma(
        const short* __restrict__ amulH, const short* __restrict__ Wfrag,
        const float* __restrict__ bot, float* __restrict__ out_a) {
    __shared__ short lds_x[3 * 66 * 64];   // 25344 B
    const int tid  = threadIdx.x;
    const int lane = tid & 63;
    const int wid  = tid >> 6;
    const int mw = wid & 1, pw = wid >> 1;   // outch-half, px-half within tile
    const int bx = blockIdx.x;   // outch half of 256 (0..1)
    const int y  = blockIdx.y;   // output row (0..63)
    const int n  = blockIdx.z;

    f32x4 acc[4][2] = {};
    const short8b* wf = (const short8b*)Wfrag;

    // staging map: 6 slots/thread, idx = it*256+tid in [0,1536)
    // rr = idx>>9 (3 rows), col = (idx>>3)&63, cg = idx&7
    short8b vreg[6];
    {   // prefetch chunk 0
        #pragma unroll
        for (int it = 0; it < 6; ++it) {
            int idx = it * 256 + tid;
            int rr = idx >> 9, col = (idx >> 3) & 63, cg = idx & 7;
            int gr = y - 1 + rr;
            short8b t{};
            if (gr >= 0 && gr < 64)
                t = *(const short8b*)(amulH + ((size_t)(n * PP + gr * 64 + col)) * 640 + cg * 8);
            vreg[it] = t;
        }
    }
    // zero halo columns once (chc = 0 and 65; never overwritten)
    if (tid < 48) {
        int rr = tid >> 4, side = (tid >> 3) & 1, cg = tid & 7;
        int chc = side ? 65 : 0;
        int elem = ((rr * 66 + chc) * 64 + cg * 8) ^ ((chc & 7) << 3);
        *(short8b*)&lds_x[elem] = short8b{};
    }

    for (int cc = 0; cc < 10; ++cc) {
        __syncthreads();   // previous compute (and halo-zero) done
        #pragma unroll
        for (int it = 0; it < 6; ++it) {
            int idx = it * 256 + tid;
            int rr = idx >> 9, col = (idx >> 3) & 63, cg = idx & 7;
            int chc = col + 1;
            int elem = ((rr * 66 + chc) * 64 + cg * 8) ^ ((chc & 7) << 3);
            *(short8b*)&lds_x[elem] = vreg[it];
        }
        if (cc < 9) {      // issue next chunk's loads; latency hides under MFMAs
            #pragma unroll
            for (int it = 0; it < 6; ++it) {
                int idx = it * 256 + tid;
                int rr = idx >> 9, col = (idx >> 3) & 63, cg = idx & 7;
                int gr = y - 1 + rr;
                short8b t{};
                if (gr >= 0 && gr < 64)
                    t = *(const short8b*)(amulH + ((size_t)(n * PP + gr * 64 + col)) * 640
                                          + (cc + 1) * 64 + cg * 8);
                vreg[it] = t;
            }
        }
        __syncthreads();
        #pragma unroll
        for (int k9 = 0; k9 < 9; ++k9) {
            const int ky = k9 / 3, kx = k9 % 3;
            #pragma unroll
            for (int ks = 0; ks < 2; ++ks) {
                short8b afr[4];
                #pragma unroll
                for (int mf = 0; mf < 4; ++mf) {
                    int mt_g = bx * 8 + mw * 4 + mf;
                    afr[mf] = wf[(((size_t)(k9 * 10 + cc) * 16 + mt_g) * 2 + ks) * 64 + lane];
                }
                short8b bfr[2];
                #pragma unroll
                for (int nf = 0; nf < 2; ++nf) {
                    int px = pw * 32 + nf * 16 + (lane & 15);
                    int chc = px + kx;
                    int elem = ((ky * 66 + chc) * 64 + ks * 32 + (lane >> 4) * 8)
                               ^ ((chc & 7) << 3);
                    bfr[nf] = *(const short8b*)&lds_x[elem];
                }
                #pragma unroll
                for (int mf = 0; mf < 4; ++mf)
                    #pragma unroll
                    for (int nf = 0; nf < 2; ++nf)
                        acc[mf][nf] = __builtin_amdgcn_mfma_f32_16x16x32_bf16(
                            afr[mf], bfr[nf], acc[mf][nf], 0, 0, 0);
            }
        }
    }
    // epilogue: bias + relu, f32 NCHW store
    #pragma unroll
    for (int mf = 0; mf < 4; ++mf) {
        int o = bx * 128 + mw * 64 + mf * 16 + (lane >> 4) * 4;
        #pragma unroll
        for (int r = 0; r < 4; ++r) {
            float bias = bot[o + r];
            #pragma unroll
            for (int nf = 0; nf < 2; ++nf) {
                int p = y * 64 + pw * 32 + nf * 16 + (lane & 15);
                float v = acc[mf][nf][r] + bias;
                out_a[((size_t)(n * 256 + o + r)) * PP + p] = v > 0.f ? v : 0.f;
            }
        }
    }
}

// ---------------------------------------------------------------------------
extern "C" void kernel_launch(void* const* d_in, const int* in_sizes, int n_in,
                              void* d_out, int out_size, void* d_ws, size_t ws_size,
                              hipStream_t stream) {
    static const int want[18] = {
        8388608, 8388608, 8388608, 2097152, 196608, 256, 16384, 16384,
        65536, 256, 32768, 128, 81920, 128, 81920, 640, 1474560, 256
    };
    const void* ptr[18];
    bool used[64];
    for (int i = 0; i < 64; ++i) used[i] = false;
    bool ok = (n_in >= 18 && n_in <= 64);
    for (int k = 0; k < 18 && ok; ++k) {
        ptr[k] = nullptr;
        for (int i = 0; i < n_in; ++i) {
            if (!used[i] && in_sizes[i] == want[k]) { ptr[k] = d_in[i]; used[i] = true; break; }
        }
        if (!ptr[k]) ok = false;
    }
    if (!ok) { for (int k = 0; k < 18; ++k) ptr[k] = d_in[k]; }

    const float* sx1  = (const float*)ptr[0];
    const float* sx2  = (const float*)ptr[1];
    const float* t_hx = (const float*)ptr[2];
    const float* tx   = (const float*)ptr[3];
    const float* Wt1  = (const float*)ptr[4];
    const float* bt1  = (const float*)ptr[5];
    const float* Wt2  = (const float*)ptr[6];
    const float* Wt3  = (const float*)ptr[7];
    const float* WU   = (const float*)ptr[8];
    const float* bU   = (const float*)ptr[9];
    const float* WV   = (const float*)ptr[10];
    const float* bV   = (const float*)ptr[11];
    const float* Wa1  = (const float*)ptr[12];
    const float* ba1  = (const float*)ptr[13];
    const float* Wa2  = (const float*)ptr[14];
    const float* ba2  = (const float*)ptr[15];
    const float* Wot  = (const float*)ptr[16];
    const float* bot  = (const float*)ptr[17];

    // Workspace (peak 96.42 MB; proven available in R4/R5):
    char* base = (char*)d_ws;
    short* txc   = (short*)base;
    short* sxh1  = (short*)(base + (size_t)33554432);
    short* sxh2  = (short*)(base + (size_t)50331648);
    short* bUh   = sxh1;                                   // reuse (sxh1 dead after gap)
    short* amulH = (short*)(base + (size_t)33554432);
    short* txh   = (short*)(base + (size_t)75497472);
    short* bVh   = (short*)(base + (size_t)75497472);
    short* a1h   = (short*)(base + (size_t)83886080);
    float* part  = (float*)(base + (size_t)92274688);
    float* wvec  = (float*)(base + (size_t)92536832);
    short* Wt1p  = (short*)(base + (size_t)92545024);
    short* WUp   = (short*)(base + (size_t)92938240);
    short* WVp   = (short*)(base + (size_t)93069312);
    short* Wa1p  = (short*)(base + (size_t)93134848);
    short* Wa2p  = (short*)(base + (size_t)93298688);
    short* Wotp  = (short*)(base + (size_t)93462528);

    float* out_a = (float*)d_out;
    float* out_w = out_a + (size_t)8 * 256 * PP;

    // weight packs
    k_wpack<<<dim3(96), 256, 0, stream>>>(Wt1, Wt1p, 16, 768);
    k_wpack<<<dim3(32), 256, 0, stream>>>(WU,  WUp,  16, 256);
    k_wpack<<<dim3(16), 256, 0, stream>>>(WV,  WVp,   8, 256);
    k_wpack<<<dim3(40), 256, 0, stream>>>(Wa1, Wa1p,  8, 640);
    k_wpack<<<dim3(40), 256, 0, stream>>>(Wa2, Wa2p, 40, 128);
    k_wprep<<<dim3(720), 256, 0, stream>>>(Wot, Wotp);

    // layout conversion: f32 NCHW -> bf16 NHWC
    k_t2h<<<dim3(64, 4, 8), 256, 0, stream>>>(sx1,  sxh1, 256, 4096, 256, 0);
    k_t2h<<<dim3(64, 4, 8), 256, 0, stream>>>(sx2,  sxh2, 256, 4096, 256, 0);
    k_t2h<<<dim3(64, 4, 8), 256, 0, stream>>>(t_hx, txc,  256, 4096, 512, 0);
    k_t2h<<<dim3(16, 4, 8), 256, 0, stream>>>(tx,   txh,  256, 1024, 256, 0);
    k_up <<<dim3(512, 1, 8), 256, 0, stream>>>(txh, txc);

    // main pipeline
    k_gemm_gap <<<dim3(2, 32, 8), 256, 0, stream>>>(sxh1, txc, Wt1p, bt1, part);
    k_wvec     <<<dim3(8),        256, 0, stream>>>(part, Wt2, Wt3, wvec, out_w);
    k_gemm_bU  <<<dim3(2, 32, 8), 256, 0, stream>>>(sxh2, WUp, bU, wvec, bUh);
    k_gemm_bV  <<<dim3(1, 32, 8), 256, 0, stream>>>(bUh, WVp, bV, bVh);
    k_gemm_a1  <<<dim3(1, 32, 8), 256, 0, stream>>>(bVh, txc, Wa1p, ba1, a1h);
    k_gemm_amul<<<dim3(5, 32, 8), 256, 0, stream>>>(a1h, Wa2p, ba2, bVh, txc, amulH);
    k_conv3_mfma<<<dim3(2, 64, 8), 256, 0, stream>>>(amulH, Wotp, bot, out_a);
}

// Round 7
// 371.334 us; speedup vs baseline: 11.3318x; 1.1323x over previous
//
#include <hip/hip_runtime.h>
#include <hip/hip_bf16.h>

#define PP 4096          // H*W
#define HH 64
#define WW 64

typedef __attribute__((ext_vector_type(8))) short short8b;   // 8 bf16
typedef __attribute__((ext_vector_type(4))) float f32x4;

static __device__ __forceinline__ float bf2f(short s) {
    union { unsigned int u; float f; } cv; cv.u = ((unsigned int)(unsigned short)s) << 16; return cv.f;
}
static __device__ __forceinline__ short f2bf(float f) {
    __hip_bfloat16 h = __float2bfloat16(f);
    return *reinterpret_cast<short*>(&h);
}

// ---------------------------------------------------------------------------
// Pack f32 weight [M][K] into MFMA B-fragment order bf16 (R4/R5-validated).
// ---------------------------------------------------------------------------
__global__ void k_wpack(const float* __restrict__ W, short* __restrict__ dst,
                        int MT, int K) {
    int s = blockIdx.x * 256 + threadIdx.x;
    int total = MT * 2 * (K / 64) * 64;      // short8b slots
    if (s >= total) return;
    int lane = s & 63;
    int rest = s >> 6;
    int ks = rest & 1; rest >>= 1;
    int mt = rest % MT;
    int cc = rest / MT;
    int o   = mt * 16 + (lane & 15);
    int ch0 = cc * 64 + ks * 32 + (lane >> 4) * 8;
    short8b v;
    #pragma unroll
    for (int j = 0; j < 8; ++j) v[j] = f2bf(W[(size_t)o * K + ch0 + j]);
    ((short8b*)dst)[s] = v;
}

// ---------------------------------------------------------------------------
// f32 NCHW -> bf16 NHWC transpose (LDS 64x64 tile, +1 pad).
// ---------------------------------------------------------------------------
__global__ void k_t2h(const float* __restrict__ src, short* __restrict__ dst,
                      int C, int P, int pitch, int colOff) {
    __shared__ short T[64 * 65];
    int tid = threadIdx.x;
    int p0 = blockIdx.x * 64, c0 = blockIdx.y * 64, n = blockIdx.z;
    #pragma unroll
    for (int it = 0; it < 16; ++it) {
        int slot = it * 256 + tid;
        int ch = slot >> 6, px = slot & 63;
        T[ch * 65 + px] = f2bf(src[((size_t)(n * C + c0 + ch)) * P + p0 + px]);
    }
    __syncthreads();
    #pragma unroll
    for (int it = 0; it < 16; ++it) {
        int slot = it * 256 + tid;
        int px = slot >> 6, ch = slot & 63;
        dst[((size_t)n * P + p0 + px) * pitch + colOff + c0 + ch] = T[ch * 65 + px];
    }
}

// ---------------------------------------------------------------------------
// Bilinear 2x upsample (align_corners) txh NHWC [n][1024][256] -> txc cols 256..511.
// ---------------------------------------------------------------------------
__global__ void k_up(const short* __restrict__ txh, short* __restrict__ txc) {
    int tid = threadIdx.x;
    int cg = tid & 31, pxl = tid >> 5;
    int px = blockIdx.x * 8 + pxl;
    int n  = blockIdx.z;
    int y = px >> 6, x = px & 63;
    const float s = 31.0f / 63.0f;
    float fy = y * s, fx = x * s;
    int y0 = (int)fy, x0 = (int)fx;
    int y1 = min(y0 + 1, 31), x1 = min(x0 + 1, 31);
    float wy = fy - (float)y0, wx = fx - (float)x0;
    const short8b* base = (const short8b*)(txh + ((size_t)n * 1024) * 256);
    short8b a = base[((size_t)(y0 * 32 + x0) * 256 + cg * 8) >> 3];
    short8b b = base[((size_t)(y0 * 32 + x1) * 256 + cg * 8) >> 3];
    short8b c = base[((size_t)(y1 * 32 + x0) * 256 + cg * 8) >> 3];
    short8b d = base[((size_t)(y1 * 32 + x1) * 256 + cg * 8) >> 3];
    short8b r;
    #pragma unroll
    for (int j = 0; j < 8; ++j) {
        float v = (bf2f(a[j]) * (1.f - wy) + bf2f(c[j]) * wy) * (1.f - wx)
                + (bf2f(b[j]) * (1.f - wy) + bf2f(d[j]) * wy) * wx;
        r[j] = f2bf(v);
    }
    *(short8b*)(txc + ((size_t)n * PP + px) * 512 + 256 + cg * 8) = r;
}

// ---------------------------------------------------------------------------
// Shared GEMM helpers: LDS tile [128 px][64 ch] bf16, XOR-swizzled.
// ---------------------------------------------------------------------------
static __device__ __forceinline__ void stage64(const short* __restrict__ src, int pitch,
                                               int c0, size_t rowbase, short* lds, int tid) {
    #pragma unroll
    for (int it = 0; it < 4; ++it) {
        int idx = it * 256 + tid;
        int px = idx >> 3, cg = idx & 7;
        short8b v = *(const short8b*)(src + (rowbase + px) * (size_t)pitch + c0 + cg * 8);
        int elem = (px * 64 + cg * 8) ^ ((px & 7) << 3);
        *(short8b*)&lds[elem] = v;
    }
}
static __device__ __forceinline__ short8b afrag(const short* lds, int pw, int mf, int ks, int lane) {
    int px = pw * 64 + mf * 16 + (lane & 15);
    int elem = (px * 64 + ks * 32 + ((lane >> 4) * 8)) ^ ((px & 7) << 3);
    return *(const short8b*)&lds[elem];
}
#define GEMM_PROLOG \
    int tid = threadIdx.x, lane = tid & 63, wid = tid >> 6; \
    int pw = wid & 1, ow = wid >> 1; \
    int bx = blockIdx.x, pt = blockIdx.y, n = blockIdx.z; \
    size_t rowbase = (size_t)n * PP + pt * 128; \
    f32x4 acc[4][4] = {}; (void)bx;
#define GEMM_STEP(MT) { \
    short8b afr[4][2], bfr[4][2]; \
    _Pragma("unroll") for (int mf = 0; mf < 4; ++mf) \
        _Pragma("unroll") for (int ks = 0; ks < 2; ++ks) afr[mf][ks] = afrag(lds, pw, mf, ks, lane); \
    _Pragma("unroll") for (int nf = 0; nf < 4; ++nf) { \
        int mt_g = bx * 8 + ow * 4 + nf; \
        _Pragma("unroll") for (int ks = 0; ks < 2; ++ks) \
            bfr[nf][ks] = wfv[(((size_t)cc * (MT) + mt_g) * 2 + ks) * 64 + lane]; } \
    _Pragma("unroll") for (int ks = 0; ks < 2; ++ks) \
        _Pragma("unroll") for (int mf = 0; mf < 4; ++mf) \
            _Pragma("unroll") for (int nf = 0; nf < 4; ++nf) \
                acc[mf][nf] = __builtin_amdgcn_mfma_f32_16x16x32_bf16(afr[mf][ks], bfr[nf][ks], acc[mf][nf], 0, 0, 0); }

// ---------------------------------------------------------------------------
// GAP GEMM: D[128px][128o] over K=768; epilogue relu(+bias), px-sum -> part.
// ---------------------------------------------------------------------------
__global__ __launch_bounds__(256) void k_gemm_gap(const short* __restrict__ sxh1,
        const short* __restrict__ txc, const short* __restrict__ wf,
        const float* __restrict__ bias, float* __restrict__ part) {
    __shared__ short lds[128 * 64];
    __shared__ float red[128 * 2];
    GEMM_PROLOG
    const short8b* wfv = (const short8b*)wf;
    for (int cc = 0; cc < 12; ++cc) {
        __syncthreads();
        if (cc < 4) stage64(sxh1, 256, cc * 64, rowbase, lds, tid);
        else        stage64(txc, 512, (cc - 4) * 64, rowbase, lds, tid);
        __syncthreads();
        GEMM_STEP(16)
    }
    #pragma unroll
    for (int nf = 0; nf < 4; ++nf) {
        int o = bx * 128 + ow * 64 + nf * 16 + (lane & 15);
        float b = bias[o];
        float s = 0.f;
        #pragma unroll
        for (int mf = 0; mf < 4; ++mf)
            #pragma unroll
            for (int r = 0; r < 4; ++r) {
                float v = acc[mf][nf][r] + b;
                s += v > 0.f ? v : 0.f;
            }
        s += __shfl_xor(s, 16);
        s += __shfl_xor(s, 32);
        if (lane < 16) red[(ow * 64 + nf * 16 + lane) * 2 + pw] = s;
    }
    __syncthreads();
    if (tid < 128)
        part[((size_t)n * 256 + bx * 128 + tid) * 32 + pt] = red[tid * 2] + red[tid * 2 + 1];
}

// ---------------------------------------------------------------------------
// bU GEMM: K=256; relu(+bias)*wvec -> bUh NHWC [n][px][256].
// ---------------------------------------------------------------------------
__global__ __launch_bounds__(256) void k_gemm_bU(const short* __restrict__ sxh2,
        const short* __restrict__ wf, const float* __restrict__ bias,
        const float* __restrict__ wvec, short* __restrict__ bUh) {
    __shared__ short lds[128 * 64];
    GEMM_PROLOG
    const short8b* wfv = (const short8b*)wf;
    for (int cc = 0; cc < 4; ++cc) {
        __syncthreads();
        stage64(sxh2, 256, cc * 64, rowbase, lds, tid);
        __syncthreads();
        GEMM_STEP(16)
    }
    #pragma unroll
    for (int nf = 0; nf < 4; ++nf) {
        int o = bx * 128 + ow * 64 + nf * 16 + (lane & 15);
        float b = bias[o], wv = wvec[n * 256 + o];
        #pragma unroll
        for (int mf = 0; mf < 4; ++mf)
            #pragma unroll
            for (int r = 0; r < 4; ++r) {
                int px = pw * 64 + mf * 16 + (lane >> 4) * 4 + r;
                float v = acc[mf][nf][r] + b;
                v = v > 0.f ? v : 0.f;
                bUh[(rowbase + px) * 256 + o] = f2bf(v * wv);
            }
    }
}

// ---------------------------------------------------------------------------
// bV GEMM: M=128, K=256 (bUh); relu -> bVh [n][px][128].
// ---------------------------------------------------------------------------
__global__ __launch_bounds__(256) void k_gemm_bV(const short* __restrict__ bUh,
        const short* __restrict__ wf, const float* __restrict__ bias,
        short* __restrict__ bVh) {
    __shared__ short lds[128 * 64];
    GEMM_PROLOG
    const short8b* wfv = (const short8b*)wf;
    for (int cc = 0; cc < 4; ++cc) {
        __syncthreads();
        stage64(bUh, 256, cc * 64, rowbase, lds, tid);
        __syncthreads();
        GEMM_STEP(8)
    }
    #pragma unroll
    for (int nf = 0; nf < 4; ++nf) {
        int o = ow * 64 + nf * 16 + (lane & 15);
        float b = bias[o];
        #pragma unroll
        for (int mf = 0; mf < 4; ++mf)
            #pragma unroll
            for (int r = 0; r < 4; ++r) {
                int px = pw * 64 + mf * 16 + (lane >> 4) * 4 + r;
                float v = acc[mf][nf][r] + b;
                bVh[(rowbase + px) * 128 + o] = f2bf(v > 0.f ? v : 0.f);
            }
    }
}

// ---------------------------------------------------------------------------
// a1 GEMM: M=128, K=640 ([bVh;txc]); relu -> a1h [n][px][128].
// ---------------------------------------------------------------------------
__global__ __launch_bounds__(256) void k_gemm_a1(const short* __restrict__ bVh,
        const short* __restrict__ txc, const short* __restrict__ wf,
        const float* __restrict__ bias, short* __restrict__ a1h) {
    __shared__ short lds[128 * 64];
    GEMM_PROLOG
    const short8b* wfv = (const short8b*)wf;
    for (int cc = 0; cc < 10; ++cc) {
        __syncthreads();
        if (cc < 2) stage64(bVh, 128, cc * 64, rowbase, lds, tid);
        else        stage64(txc, 512, (cc - 2) * 64, rowbase, lds, tid);
        __syncthreads();
        GEMM_STEP(8)
    }
    #pragma unroll
    for (int nf = 0; nf < 4; ++nf) {
        int o = ow * 64 + nf * 16 + (lane & 15);
        float b = bias[o];
        #pragma unroll
        for (int mf = 0; mf < 4; ++mf)
            #pragma unroll
            for (int r = 0; r < 4; ++r) {
                int px = pw * 64 + mf * 16 + (lane >> 4) * 4 + r;
                float v = acc[mf][nf][r] + b;
                a1h[(rowbase + px) * 128 + o] = f2bf(v > 0.f ? v : 0.f);
            }
    }
}

// ---------------------------------------------------------------------------
// amul GEMM: M=640, K=128 (a1h); sigmoid * [bVh;txc] -> amulH NHWC [n][px][640].
// ---------------------------------------------------------------------------
__global__ __launch_bounds__(256) void k_gemm_amul(const short* __restrict__ a1h,
        const short* __restrict__ wf, const float* __restrict__ bias,
        const short* __restrict__ bVh, const short* __restrict__ txc,
        short* __restrict__ amulH) {
    __shared__ short lds[128 * 64];
    GEMM_PROLOG
    const short8b* wfv = (const short8b*)wf;
    for (int cc = 0; cc < 2; ++cc) {
        __syncthreads();
        stage64(a1h, 128, cc * 64, rowbase, lds, tid);
        __syncthreads();
        GEMM_STEP(40)
    }
    #pragma unroll
    for (int nf = 0; nf < 4; ++nf) {
        int o = bx * 128 + ow * 64 + nf * 16 + (lane & 15);
        float b = bias[o];
        #pragma unroll
        for (int mf = 0; mf < 4; ++mf)
            #pragma unroll
            for (int r = 0; r < 4; ++r) {
                int px = pw * 64 + mf * 16 + (lane >> 4) * 4 + r;
                float xv = acc[mf][nf][r] + b;
                float sg = 1.0f / (1.0f + expf(-xv));
                float bval = (o < 128) ? bf2f(bVh[(rowbase + px) * 128 + o])
                                       : bf2f(txc[(rowbase + px) * 512 + o - 128]);
                amulH[(rowbase + px) * 640 + o] = f2bf(sg * bval);
            }
    }
}

// ---------------------------------------------------------------------------
// GAP finish + squeeze MLP + L2-normalize.
// ---------------------------------------------------------------------------
__global__ void k_wvec(const float* __restrict__ part, const float* __restrict__ Wt2,
                       const float* __restrict__ Wt3, float* __restrict__ wvec,
                       float* __restrict__ out_w) {
    int n = blockIdx.x, tid = threadIdx.x;
    __shared__ float sm1[256];
    __shared__ float sm2[64];
    __shared__ float smr[4];
    float s = 0.0f;
    #pragma unroll
    for (int t = 0; t < 32; ++t) s += part[(size_t)(n * 256 + tid) * 32 + t];
    sm1[tid] = s * (1.0f / 4096.0f);
    __syncthreads();
    if (tid < 64) {
        float a = 0.0f;
        for (int c = 0; c < 256; ++c) a = fmaf(Wt2[tid * 256 + c], sm1[c], a);
        sm2[tid] = a > 0.0f ? a : 0.0f;
    }
    __syncthreads();
    float w3 = 0.0f;
    for (int e = 0; e < 64; ++e) w3 = fmaf(Wt3[tid * 64 + e], sm2[e], w3);
    float q = w3 * w3;
    int lane = tid & 63, wv = tid >> 6;
    #pragma unroll
    for (int off = 32; off > 0; off >>= 1) q += __shfl_down(q, off);
    if (lane == 0) smr[wv] = q;
    __syncthreads();
    float nrm = sqrtf(smr[0] + smr[1] + smr[2] + smr[3]);
    nrm = fmaxf(nrm, 1e-12f);
    float w = w3 / nrm;
    wvec[n * 256 + tid] = w;
    out_w[n * 256 + tid] = w;
}

// ---------------------------------------------------------------------------
// Conv weight prep (R4-validated): Wot f32 [256][640][3][3] -> A-fragment bf16
// [k9][cc][mt][ks][lane][8]. Chunk u = k9*10+cc has stride 2048 short8b.
// ---------------------------------------------------------------------------
__global__ void k_wprep(const float* __restrict__ Wot, short* __restrict__ Wfrag) {
    int s = blockIdx.x * 256 + threadIdx.x;
    int lane = s & 63;
    int rest = s >> 6;
    int ks = rest & 1;  rest >>= 1;
    int mt = rest & 15; rest >>= 4;
    int cc = rest % 10;
    int k9 = rest / 10;
    int o   = mt * 16 + (lane & 15);
    int ch0 = cc * 64 + ks * 32 + (lane >> 4) * 8;
    short8b v{};
    #pragma unroll
    for (int j = 0; j < 8; ++j)
        v[j] = f2bf(Wot[((size_t)o * 640 + ch0 + j) * 9 + k9]);
    ((short8b*)Wfrag)[s] = v;
}

// ---------------------------------------------------------------------------
// MFMA implicit-GEMM conv3x3, v3: tile 128o x 64px, grid (2,64,8).
// Explicit weight double-buffer (wA/wB): every 4-load batch from L2 is
// covered by 8 MFMAs -> latency hidden regardless of compiler heuristics.
// x-tile staged via registers (issue-early, T14). Halo zeroed once.
// ---------------------------------------------------------------------------
#define WLOAD(dst, u, kss) { \
    _Pragma("unroll") for (int mf = 0; mf < 4; ++mf) { \
        int mt_g = bx * 8 + mw * 4 + mf; \
        dst[mf] = wf[(((size_t)(u) * 16 + mt_g) * 2 + (kss)) * 64 + lane]; } }

__global__ __launch_bounds__(256, 4) void k_conv3_mfma(
        const short* __restrict__ amulH, const short* __restrict__ Wfrag,
        const float* __restrict__ bot, float* __restrict__ out_a) {
    __shared__ short lds_x[3 * 66 * 64];   // 25344 B
    const int tid  = threadIdx.x;
    const int lane = tid & 63;
    const int wid  = tid >> 6;
    const int mw = wid & 1, pw = wid >> 1;
    const int bx = blockIdx.x;   // outch half (0..1)
    const int y  = blockIdx.y;   // output row (0..63)
    const int n  = blockIdx.z;

    f32x4 acc[4][2] = {};
    const short8b* wf = (const short8b*)Wfrag;

    // x staging: 6 slots/thread, idx = it*256+tid; rr=idx>>9, col=(idx>>3)&63, cg=idx&7
    short8b vreg[6];
    #pragma unroll
    for (int it = 0; it < 6; ++it) {
        int idx = it * 256 + tid;
        int rr = idx >> 9, col = (idx >> 3) & 63, cg = idx & 7;
        int gr = y - 1 + rr;
        short8b t{};
        if (gr >= 0 && gr < 64)
            t = *(const short8b*)(amulH + ((size_t)(n * PP + gr * 64 + col)) * 640 + cg * 8);
        vreg[it] = t;
    }
    // zero halo columns once (chc = 0 and 65; never overwritten)
    if (tid < 48) {
        int rr = tid >> 4, side = (tid >> 3) & 1, cg = tid & 7;
        int chc = side ? 65 : 0;
        int elem = ((rr * 66 + chc) * 64 + cg * 8) ^ ((chc & 7) << 3);
        *(short8b*)&lds_x[elem] = short8b{};
    }

    short8b wA[4], wB[4];
    WLOAD(wA, 0, 0)    // chunk u=0 (k9=0,cc=0), ks=0

    for (int cc = 0; cc < 10; ++cc) {
        __syncthreads();
        #pragma unroll
        for (int it = 0; it < 6; ++it) {
            int idx = it * 256 + tid;
            int rr = idx >> 9, col = (idx >> 3) & 63, cg = idx & 7;
            int chc = col + 1;
            int elem = ((rr * 66 + chc) * 64 + cg * 8) ^ ((chc & 7) << 3);
            *(short8b*)&lds_x[elem] = vreg[it];
        }
        if (cc < 9) {
            #pragma unroll
            for (int it = 0; it < 6; ++it) {
                int idx = it * 256 + tid;
                int rr = idx >> 9, col = (idx >> 3) & 63, cg = idx & 7;
                int gr = y - 1 + rr;
                short8b t{};
                if (gr >= 0 && gr < 64)
                    t = *(const short8b*)(amulH + ((size_t)(n * PP + gr * 64 + col)) * 640
                                          + (cc + 1) * 64 + cg * 8);
                vreg[it] = t;
            }
        }
        __syncthreads();
        #pragma unroll
        for (int k9 = 0; k9 < 9; ++k9) {
            const int ky = k9 / 3, kx = k9 % 3;
            const int u = k9 * 10 + cc;
            // prefetch ks=1 weights; latency hides under ks=0 MFMAs
            WLOAD(wB, u, 1)
            {   // ks = 0
                short8b bfr[2];
                #pragma unroll
                for (int nf = 0; nf < 2; ++nf) {
                    int px = pw * 32 + nf * 16 + (lane & 15);
                    int chc = px + kx;
                    int elem = ((ky * 66 + chc) * 64 + 0 * 32 + (lane >> 4) * 8)
                               ^ ((chc & 7) << 3);
                    bfr[nf] = *(const short8b*)&lds_x[elem];
                }
                #pragma unroll
                for (int mf = 0; mf < 4; ++mf)
                    #pragma unroll
                    for (int nf = 0; nf < 2; ++nf)
                        acc[mf][nf] = __builtin_amdgcn_mfma_f32_16x16x32_bf16(
                            wA[mf], bfr[nf], acc[mf][nf], 0, 0, 0);
            }
            // prefetch next half-iteration's ks=0 weights (chunk u+10, or next cc's
            // k9=0 chunk = cc+1; always in-bounds, garbage harmless on last iter)
            {
                const int unext = (k9 < 8) ? (u + 10) : (cc + 1);
                WLOAD(wA, unext, 0)
            }
            {   // ks = 1
                short8b bfr[2];
                #pragma unroll
                for (int nf = 0; nf < 2; ++nf) {
                    int px = pw * 32 + nf * 16 + (lane & 15);
                    int chc = px + kx;
                    int elem = ((ky * 66 + chc) * 64 + 1 * 32 + (lane >> 4) * 8)
                               ^ ((chc & 7) << 3);
                    bfr[nf] = *(const short8b*)&lds_x[elem];
                }
                #pragma unroll
                for (int mf = 0; mf < 4; ++mf)
                    #pragma unroll
                    for (int nf = 0; nf < 2; ++nf)
                        acc[mf][nf] = __builtin_amdgcn_mfma_f32_16x16x32_bf16(
                            wB[mf], bfr[nf], acc[mf][nf], 0, 0, 0);
            }
        }
    }
    // epilogue: bias + relu, f32 NCHW store
    #pragma unroll
    for (int mf = 0; mf < 4; ++mf) {
        int o = bx * 128 + mw * 64 + mf * 16 + (lane >> 4) * 4;
        #pragma unroll
        for (int r = 0; r < 4; ++r) {
            float bias = bot[o + r];
            #pragma unroll
            for (int nf = 0; nf < 2; ++nf) {
                int p = y * 64 + pw * 32 + nf * 16 + (lane & 15);
                float v = acc[mf][nf][r] + bias;
                out_a[((size_t)(n * 256 + o + r)) * PP + p] = v > 0.f ? v : 0.f;
            }
        }
    }
}

// ---------------------------------------------------------------------------
extern "C" void kernel_launch(void* const* d_in, const int* in_sizes, int n_in,
                              void* d_out, int out_size, void* d_ws, size_t ws_size,
                              hipStream_t stream) {
    static const int want[18] = {
        8388608, 8388608, 8388608, 2097152, 196608, 256, 16384, 16384,
        65536, 256, 32768, 128, 81920, 128, 81920, 640, 1474560, 256
    };
    const void* ptr[18];
    bool used[64];
    for (int i = 0; i < 64; ++i) used[i] = false;
    bool ok = (n_in >= 18 && n_in <= 64);
    for (int k = 0; k < 18 && ok; ++k) {
        ptr[k] = nullptr;
        for (int i = 0; i < n_in; ++i) {
            if (!used[i] && in_sizes[i] == want[k]) { ptr[k] = d_in[i]; used[i] = true; break; }
        }
        if (!ptr[k]) ok = false;
    }
    if (!ok) { for (int k = 0; k < 18; ++k) ptr[k] = d_in[k]; }

    const float* sx1  = (const float*)ptr[0];
    const float* sx2  = (const float*)ptr[1];
    const float* t_hx = (const float*)ptr[2];
    const float* tx   = (const float*)ptr[3];
    const float* Wt1  = (const float*)ptr[4];
    const float* bt1  = (const float*)ptr[5];
    const float* Wt2  = (const float*)ptr[6];
    const float* Wt3  = (const float*)ptr[7];
    const float* WU   = (const float*)ptr[8];
    const float* bU   = (const float*)ptr[9];
    const float* WV   = (const float*)ptr[10];
    const float* bV   = (const float*)ptr[11];
    const float* Wa1  = (const float*)ptr[12];
    const float* ba1  = (const float*)ptr[13];
    const float* Wa2  = (const float*)ptr[14];
    const float* ba2  = (const float*)ptr[15];
    const float* Wot  = (const float*)ptr[16];
    const float* bot  = (const float*)ptr[17];

    // Workspace (peak 96.42 MB; proven available in R4/R5):
    char* base = (char*)d_ws;
    short* txc   = (short*)base;
    short* sxh1  = (short*)(base + (size_t)33554432);
    short* sxh2  = (short*)(base + (size_t)50331648);
    short* bUh   = sxh1;                                   // reuse (sxh1 dead after gap)
    short* amulH = (short*)(base + (size_t)33554432);
    short* txh   = (short*)(base + (size_t)75497472);
    short* bVh   = (short*)(base + (size_t)75497472);
    short* a1h   = (short*)(base + (size_t)83886080);
    float* part  = (float*)(base + (size_t)92274688);
    float* wvec  = (float*)(base + (size_t)92536832);
    short* Wt1p  = (short*)(base + (size_t)92545024);
    short* WUp   = (short*)(base + (size_t)92938240);
    short* WVp   = (short*)(base + (size_t)93069312);
    short* Wa1p  = (short*)(base + (size_t)93134848);
    short* Wa2p  = (short*)(base + (size_t)93298688);
    short* Wotp  = (short*)(base + (size_t)93462528);

    float* out_a = (float*)d_out;
    float* out_w = out_a + (size_t)8 * 256 * PP;

    // weight packs
    k_wpack<<<dim3(96), 256, 0, stream>>>(Wt1, Wt1p, 16, 768);
    k_wpack<<<dim3(32), 256, 0, stream>>>(WU,  WUp,  16, 256);
    k_wpack<<<dim3(16), 256, 0, stream>>>(WV,  WVp,   8, 256);
    k_wpack<<<dim3(40), 256, 0, stream>>>(Wa1, Wa1p,  8, 640);
    k_wpack<<<dim3(40), 256, 0, stream>>>(Wa2, Wa2p, 40, 128);
    k_wprep<<<dim3(720), 256, 0, stream>>>(Wot, Wotp);

    // layout conversion: f32 NCHW -> bf16 NHWC
    k_t2h<<<dim3(64, 4, 8), 256, 0, stream>>>(sx1,  sxh1, 256, 4096, 256, 0);
    k_t2h<<<dim3(64, 4, 8), 256, 0, stream>>>(sx2,  sxh2, 256, 4096, 256, 0);
    k_t2h<<<dim3(64, 4, 8), 256, 0, stream>>>(t_hx, txc,  256, 4096, 512, 0);
    k_t2h<<<dim3(16, 4, 8), 256, 0, stream>>>(tx,   txh,  256, 1024, 256, 0);
    k_up <<<dim3(512, 1, 8), 256, 0, stream>>>(txh, txc);

    // main pipeline
    k_gemm_gap <<<dim3(2, 32, 8), 256, 0, stream>>>(sxh1, txc, Wt1p, bt1, part);
    k_wvec     <<<dim3(8),        256, 0, stream>>>(part, Wt2, Wt3, wvec, out_w);
    k_gemm_bU  <<<dim3(2, 32, 8), 256, 0, stream>>>(sxh2, WUp, bU, wvec, bUh);
    k_gemm_bV  <<<dim3(1, 32, 8), 256, 0, stream>>>(bUh, WVp, bV, bVh);
    k_gemm_a1  <<<dim3(1, 32, 8), 256, 0, stream>>>(bVh, txc, Wa1p, ba1, a1h);
    k_gemm_amul<<<dim3(5, 32, 8), 256, 0, stream>>>(a1h, Wa2p, ba2, bVh, txc, amulH);
    k_conv3_mfma<<<dim3(2, 64, 8), 256, 0, stream>>>(amulH, Wotp, bot, out_a);
}

// Round 8
// 367.320 us; speedup vs baseline: 11.4557x; 1.0109x over previous
//
#include <hip/hip_runtime.h>
#include <hip/hip_bf16.h>

#define PP 4096          // H*W
#define HH 64
#define WW 64

typedef __attribute__((ext_vector_type(8))) short short8b;   // 8 bf16
typedef __attribute__((ext_vector_type(4))) float f32x4;

static __device__ __forceinline__ float bf2f(short s) {
    union { unsigned int u; float f; } cv; cv.u = ((unsigned int)(unsigned short)s) << 16; return cv.f;
}
static __device__ __forceinline__ short f2bf(float f) {
    __hip_bfloat16 h = __float2bfloat16(f);
    return *reinterpret_cast<short*>(&h);
}

// ---------------------------------------------------------------------------
// Pack f32 weight [M][K] into MFMA B-fragment order bf16 (R4/R5-validated).
// ---------------------------------------------------------------------------
__global__ void k_wpack(const float* __restrict__ W, short* __restrict__ dst,
                        int MT, int K) {
    int s = blockIdx.x * 256 + threadIdx.x;
    int total = MT * 2 * (K / 64) * 64;      // short8b slots
    if (s >= total) return;
    int lane = s & 63;
    int rest = s >> 6;
    int ks = rest & 1; rest >>= 1;
    int mt = rest % MT;
    int cc = rest / MT;
    int o   = mt * 16 + (lane & 15);
    int ch0 = cc * 64 + ks * 32 + (lane >> 4) * 8;
    short8b v;
    #pragma unroll
    for (int j = 0; j < 8; ++j) v[j] = f2bf(W[(size_t)o * K + ch0 + j]);
    ((short8b*)dst)[s] = v;
}

// ---------------------------------------------------------------------------
// f32 NCHW -> bf16 NHWC transpose (LDS 64x64 tile, +1 pad).
// ---------------------------------------------------------------------------
__global__ void k_t2h(const float* __restrict__ src, short* __restrict__ dst,
                      int C, int P, int pitch, int colOff) {
    __shared__ short T[64 * 65];
    int tid = threadIdx.x;
    int p0 = blockIdx.x * 64, c0 = blockIdx.y * 64, n = blockIdx.z;
    #pragma unroll
    for (int it = 0; it < 16; ++it) {
        int slot = it * 256 + tid;
        int ch = slot >> 6, px = slot & 63;
        T[ch * 65 + px] = f2bf(src[((size_t)(n * C + c0 + ch)) * P + p0 + px]);
    }
    __syncthreads();
    #pragma unroll
    for (int it = 0; it < 16; ++it) {
        int slot = it * 256 + tid;
        int px = slot >> 6, ch = slot & 63;
        dst[((size_t)n * P + p0 + px) * pitch + colOff + c0 + ch] = T[ch * 65 + px];
    }
}

// ---------------------------------------------------------------------------
// Bilinear 2x upsample (align_corners) txh NHWC [n][1024][256] -> txc cols 256..511.
// ---------------------------------------------------------------------------
__global__ void k_up(const short* __restrict__ txh, short* __restrict__ txc) {
    int tid = threadIdx.x;
    int cg = tid & 31, pxl = tid >> 5;
    int px = blockIdx.x * 8 + pxl;
    int n  = blockIdx.z;
    int y = px >> 6, x = px & 63;
    const float s = 31.0f / 63.0f;
    float fy = y * s, fx = x * s;
    int y0 = (int)fy, x0 = (int)fx;
    int y1 = min(y0 + 1, 31), x1 = min(x0 + 1, 31);
    float wy = fy - (float)y0, wx = fx - (float)x0;
    const short8b* base = (const short8b*)(txh + ((size_t)n * 1024) * 256);
    short8b a = base[((size_t)(y0 * 32 + x0) * 256 + cg * 8) >> 3];
    short8b b = base[((size_t)(y0 * 32 + x1) * 256 + cg * 8) >> 3];
    short8b c = base[((size_t)(y1 * 32 + x0) * 256 + cg * 8) >> 3];
    short8b d = base[((size_t)(y1 * 32 + x1) * 256 + cg * 8) >> 3];
    short8b r;
    #pragma unroll
    for (int j = 0; j < 8; ++j) {
        float v = (bf2f(a[j]) * (1.f - wy) + bf2f(c[j]) * wy) * (1.f - wx)
                + (bf2f(b[j]) * (1.f - wy) + bf2f(d[j]) * wy) * wx;
        r[j] = f2bf(v);
    }
    *(short8b*)(txc + ((size_t)n * PP + px) * 512 + 256 + cg * 8) = r;
}

// ---------------------------------------------------------------------------
// Shared GEMM helpers: LDS tile [128 px][64 ch] bf16, XOR-swizzled.
// ---------------------------------------------------------------------------
static __device__ __forceinline__ void stage64(const short* __restrict__ src, int pitch,
                                               int c0, size_t rowbase, short* lds, int tid) {
    #pragma unroll
    for (int it = 0; it < 4; ++it) {
        int idx = it * 256 + tid;
        int px = idx >> 3, cg = idx & 7;
        short8b v = *(const short8b*)(src + (rowbase + px) * (size_t)pitch + c0 + cg * 8);
        int elem = (px * 64 + cg * 8) ^ ((px & 7) << 3);
        *(short8b*)&lds[elem] = v;
    }
}
static __device__ __forceinline__ short8b afrag(const short* lds, int pw, int mf, int ks, int lane) {
    int px = pw * 64 + mf * 16 + (lane & 15);
    int elem = (px * 64 + ks * 32 + ((lane >> 4) * 8)) ^ ((px & 7) << 3);
    return *(const short8b*)&lds[elem];
}
#define GEMM_PROLOG \
    int tid = threadIdx.x, lane = tid & 63, wid = tid >> 6; \
    int pw = wid & 1, ow = wid >> 1; \
    int bx = blockIdx.x, pt = blockIdx.y, n = blockIdx.z; \
    size_t rowbase = (size_t)n * PP + pt * 128; \
    f32x4 acc[4][4] = {}; (void)bx;
#define GEMM_STEP(MT) { \
    short8b afr[4][2], bfr[4][2]; \
    _Pragma("unroll") for (int mf = 0; mf < 4; ++mf) \
        _Pragma("unroll") for (int ks = 0; ks < 2; ++ks) afr[mf][ks] = afrag(lds, pw, mf, ks, lane); \
    _Pragma("unroll") for (int nf = 0; nf < 4; ++nf) { \
        int mt_g = bx * 8 + ow * 4 + nf; \
        _Pragma("unroll") for (int ks = 0; ks < 2; ++ks) \
            bfr[nf][ks] = wfv[(((size_t)cc * (MT) + mt_g) * 2 + ks) * 64 + lane]; } \
    _Pragma("unroll") for (int ks = 0; ks < 2; ++ks) \
        _Pragma("unroll") for (int mf = 0; mf < 4; ++mf) \
            _Pragma("unroll") for (int nf = 0; nf < 4; ++nf) \
                acc[mf][nf] = __builtin_amdgcn_mfma_f32_16x16x32_bf16(afr[mf][ks], bfr[nf][ks], acc[mf][nf], 0, 0, 0); }

// ---------------------------------------------------------------------------
// GAP GEMM: D[128px][128o] over K=768; epilogue relu(+bias), px-sum -> part.
// ---------------------------------------------------------------------------
__global__ __launch_bounds__(256) void k_gemm_gap(const short* __restrict__ sxh1,
        const short* __restrict__ txc, const short* __restrict__ wf,
        const float* __restrict__ bias, float* __restrict__ part) {
    __shared__ short lds[128 * 64];
    __shared__ float red[128 * 2];
    GEMM_PROLOG
    const short8b* wfv = (const short8b*)wf;
    for (int cc = 0; cc < 12; ++cc) {
        __syncthreads();
        if (cc < 4) stage64(sxh1, 256, cc * 64, rowbase, lds, tid);
        else        stage64(txc, 512, (cc - 4) * 64, rowbase, lds, tid);
        __syncthreads();
        GEMM_STEP(16)
    }
    #pragma unroll
    for (int nf = 0; nf < 4; ++nf) {
        int o = bx * 128 + ow * 64 + nf * 16 + (lane & 15);
        float b = bias[o];
        float s = 0.f;
        #pragma unroll
        for (int mf = 0; mf < 4; ++mf)
            #pragma unroll
            for (int r = 0; r < 4; ++r) {
                float v = acc[mf][nf][r] + b;
                s += v > 0.f ? v : 0.f;
            }
        s += __shfl_xor(s, 16);
        s += __shfl_xor(s, 32);
        if (lane < 16) red[(ow * 64 + nf * 16 + lane) * 2 + pw] = s;
    }
    __syncthreads();
    if (tid < 128)
        part[((size_t)n * 256 + bx * 128 + tid) * 32 + pt] = red[tid * 2] + red[tid * 2 + 1];
}

// ---------------------------------------------------------------------------
// bU GEMM: K=256; relu(+bias)*wvec -> bUh NHWC [n][px][256].
// ---------------------------------------------------------------------------
__global__ __launch_bounds__(256) void k_gemm_bU(const short* __restrict__ sxh2,
        const short* __restrict__ wf, const float* __restrict__ bias,
        const float* __restrict__ wvec, short* __restrict__ bUh) {
    __shared__ short lds[128 * 64];
    GEMM_PROLOG
    const short8b* wfv = (const short8b*)wf;
    for (int cc = 0; cc < 4; ++cc) {
        __syncthreads();
        stage64(sxh2, 256, cc * 64, rowbase, lds, tid);
        __syncthreads();
        GEMM_STEP(16)
    }
    #pragma unroll
    for (int nf = 0; nf < 4; ++nf) {
        int o = bx * 128 + ow * 64 + nf * 16 + (lane & 15);
        float b = bias[o], wv = wvec[n * 256 + o];
        #pragma unroll
        for (int mf = 0; mf < 4; ++mf)
            #pragma unroll
            for (int r = 0; r < 4; ++r) {
                int px = pw * 64 + mf * 16 + (lane >> 4) * 4 + r;
                float v = acc[mf][nf][r] + b;
                v = v > 0.f ? v : 0.f;
                bUh[(rowbase + px) * 256 + o] = f2bf(v * wv);
            }
    }
}

// ---------------------------------------------------------------------------
// bV GEMM: M=128, K=256 (bUh); relu -> bVh [n][px][128].
// ---------------------------------------------------------------------------
__global__ __launch_bounds__(256) void k_gemm_bV(const short* __restrict__ bUh,
        const short* __restrict__ wf, const float* __restrict__ bias,
        short* __restrict__ bVh) {
    __shared__ short lds[128 * 64];
    GEMM_PROLOG
    const short8b* wfv = (const short8b*)wf;
    for (int cc = 0; cc < 4; ++cc) {
        __syncthreads();
        stage64(bUh, 256, cc * 64, rowbase, lds, tid);
        __syncthreads();
        GEMM_STEP(8)
    }
    #pragma unroll
    for (int nf = 0; nf < 4; ++nf) {
        int o = ow * 64 + nf * 16 + (lane & 15);
        float b = bias[o];
        #pragma unroll
        for (int mf = 0; mf < 4; ++mf)
            #pragma unroll
            for (int r = 0; r < 4; ++r) {
                int px = pw * 64 + mf * 16 + (lane >> 4) * 4 + r;
                float v = acc[mf][nf][r] + b;
                bVh[(rowbase + px) * 128 + o] = f2bf(v > 0.f ? v : 0.f);
            }
    }
}

// ---------------------------------------------------------------------------
// a1 GEMM: M=128, K=640 ([bVh;txc]); relu -> a1h [n][px][128].
// ---------------------------------------------------------------------------
__global__ __launch_bounds__(256) void k_gemm_a1(const short* __restrict__ bVh,
        const short* __restrict__ txc, const short* __restrict__ wf,
        const float* __restrict__ bias, short* __restrict__ a1h) {
    __shared__ short lds[128 * 64];
    GEMM_PROLOG
    const short8b* wfv = (const short8b*)wf;
    for (int cc = 0; cc < 10; ++cc) {
        __syncthreads();
        if (cc < 2) stage64(bVh, 128, cc * 64, rowbase, lds, tid);
        else        stage64(txc, 512, (cc - 2) * 64, rowbase, lds, tid);
        __syncthreads();
        GEMM_STEP(8)
    }
    #pragma unroll
    for (int nf = 0; nf < 4; ++nf) {
        int o = ow * 64 + nf * 16 + (lane & 15);
        float b = bias[o];
        #pragma unroll
        for (int mf = 0; mf < 4; ++mf)
            #pragma unroll
            for (int r = 0; r < 4; ++r) {
                int px = pw * 64 + mf * 16 + (lane >> 4) * 4 + r;
                float v = acc[mf][nf][r] + b;
                a1h[(rowbase + px) * 128 + o] = f2bf(v > 0.f ? v : 0.f);
            }
    }
}

// ---------------------------------------------------------------------------
// amul GEMM: M=640, K=128 (a1h); sigmoid * [bVh;txc] -> amulH NHWC [n][px][640].
// ---------------------------------------------------------------------------
__global__ __launch_bounds__(256) void k_gemm_amul(const short* __restrict__ a1h,
        const short* __restrict__ wf, const float* __restrict__ bias,
        const short* __restrict__ bVh, const short* __restrict__ txc,
        short* __restrict__ amulH) {
    __shared__ short lds[128 * 64];
    GEMM_PROLOG
    const short8b* wfv = (const short8b*)wf;
    for (int cc = 0; cc < 2; ++cc) {
        __syncthreads();
        stage64(a1h, 128, cc * 64, rowbase, lds, tid);
        __syncthreads();
        GEMM_STEP(40)
    }
    #pragma unroll
    for (int nf = 0; nf < 4; ++nf) {
        int o = bx * 128 + ow * 64 + nf * 16 + (lane & 15);
        float b = bias[o];
        #pragma unroll
        for (int mf = 0; mf < 4; ++mf)
            #pragma unroll
            for (int r = 0; r < 4; ++r) {
                int px = pw * 64 + mf * 16 + (lane >> 4) * 4 + r;
                float xv = acc[mf][nf][r] + b;
                float sg = 1.0f / (1.0f + expf(-xv));
                float bval = (o < 128) ? bf2f(bVh[(rowbase + px) * 128 + o])
                                       : bf2f(txc[(rowbase + px) * 512 + o - 128]);
                amulH[(rowbase + px) * 640 + o] = f2bf(sg * bval);
            }
    }
}

// ---------------------------------------------------------------------------
// GAP finish + squeeze MLP + L2-normalize.
// ---------------------------------------------------------------------------
__global__ void k_wvec(const float* __restrict__ part, const float* __restrict__ Wt2,
                       const float* __restrict__ Wt3, float* __restrict__ wvec,
                       float* __restrict__ out_w) {
    int n = blockIdx.x, tid = threadIdx.x;
    __shared__ float sm1[256];
    __shared__ float sm2[64];
    __shared__ float smr[4];
    float s = 0.0f;
    #pragma unroll
    for (int t = 0; t < 32; ++t) s += part[(size_t)(n * 256 + tid) * 32 + t];
    sm1[tid] = s * (1.0f / 4096.0f);
    __syncthreads();
    if (tid < 64) {
        float a = 0.0f;
        for (int c = 0; c < 256; ++c) a = fmaf(Wt2[tid * 256 + c], sm1[c], a);
        sm2[tid] = a > 0.0f ? a : 0.0f;
    }
    __syncthreads();
    float w3 = 0.0f;
    for (int e = 0; e < 64; ++e) w3 = fmaf(Wt3[tid * 64 + e], sm2[e], w3);
    float q = w3 * w3;
    int lane = tid & 63, wv = tid >> 6;
    #pragma unroll
    for (int off = 32; off > 0; off >>= 1) q += __shfl_down(q, off);
    if (lane == 0) smr[wv] = q;
    __syncthreads();
    float nrm = sqrtf(smr[0] + smr[1] + smr[2] + smr[3]);
    nrm = fmaxf(nrm, 1e-12f);
    float w = w3 / nrm;
    wvec[n * 256 + tid] = w;
    out_w[n * 256 + tid] = w;
}

// ---------------------------------------------------------------------------
// Conv weight prep (R4-validated): Wot f32 [256][640][3][3] -> A-fragment bf16
// [k9][cc][mt][ks][lane][8]. Chunk u = k9*10+cc has stride 2048 short8b.
// ---------------------------------------------------------------------------
__global__ void k_wprep(const float* __restrict__ Wot, short* __restrict__ Wfrag) {
    int s = blockIdx.x * 256 + threadIdx.x;
    int lane = s & 63;
    int rest = s >> 6;
    int ks = rest & 1;  rest >>= 1;
    int mt = rest & 15; rest >>= 4;
    int cc = rest % 10;
    int k9 = rest / 10;
    int o   = mt * 16 + (lane & 15);
    int ch0 = cc * 64 + ks * 32 + (lane >> 4) * 8;
    short8b v{};
    #pragma unroll
    for (int j = 0; j < 8; ++j)
        v[j] = f2bf(Wot[((size_t)o * 640 + ch0 + j) * 9 + k9]);
    ((short8b*)Wfrag)[s] = v;
}

// ---------------------------------------------------------------------------
// MFMA implicit-GEMM conv3x3, v4: tile 128o x 64px, grid (64row, 2bx, 8n).
// XCD band-swizzle: y = (gx&7)*8 + gx/8 -> each XCD owns an 8-row band, and
// the bx pair for a row shares the same XCD's L2 (ids differ by 64 = 0 mod 8).
// Weight wA/wB double-buffer (R7-validated). LDS-transposed epilogue:
// full 256B-line f32 stores (kills partial-line write amplification).
// ---------------------------------------------------------------------------
#define WLOAD(dst, u, kss) { \
    _Pragma("unroll") for (int mf = 0; mf < 4; ++mf) { \
        int mt_g = bx * 8 + mw * 4 + mf; \
        dst[mf] = wf[(((size_t)(u) * 16 + mt_g) * 2 + (kss)) * 64 + lane]; } }

__global__ __launch_bounds__(256, 4) void k_conv3_mfma(
        const short* __restrict__ amulH, const short* __restrict__ Wfrag,
        const float* __restrict__ bot, float* __restrict__ out_a) {
    __shared__ short lds_x[3 * 66 * 64];   // 25344 B; reused as f32[64][66] in epilogue
    const int tid  = threadIdx.x;
    const int lane = tid & 63;
    const int wid  = tid >> 6;
    const int mw = wid & 1, pw = wid >> 1;
    const int gx = blockIdx.x;             // 0..63
    const int y  = ((gx & 7) << 3) | (gx >> 3);   // band swizzle (bijective 8x8 transpose)
    const int bx = blockIdx.y;             // outch half (0..1)
    const int n  = blockIdx.z;

    f32x4 acc[4][2] = {};
    const short8b* wf = (const short8b*)Wfrag;

    // x staging: 6 slots/thread, idx = it*256+tid; rr=idx>>9, col=(idx>>3)&63, cg=idx&7
    short8b vreg[6];
    #pragma unroll
    for (int it = 0; it < 6; ++it) {
        int idx = it * 256 + tid;
        int rr = idx >> 9, col = (idx >> 3) & 63, cg = idx & 7;
        int gr = y - 1 + rr;
        short8b t{};
        if (gr >= 0 && gr < 64)
            t = *(const short8b*)(amulH + ((size_t)(n * PP + gr * 64 + col)) * 640 + cg * 8);
        vreg[it] = t;
    }
    // zero halo columns once (chc = 0 and 65; never overwritten in main loop)
    if (tid < 48) {
        int rr = tid >> 4, side = (tid >> 3) & 1, cg = tid & 7;
        int chc = side ? 65 : 0;
        int elem = ((rr * 66 + chc) * 64 + cg * 8) ^ ((chc & 7) << 3);
        *(short8b*)&lds_x[elem] = short8b{};
    }

    short8b wA[4], wB[4];
    WLOAD(wA, 0, 0)

    for (int cc = 0; cc < 10; ++cc) {
        __syncthreads();
        #pragma unroll
        for (int it = 0; it < 6; ++it) {
            int idx = it * 256 + tid;
            int rr = idx >> 9, col = (idx >> 3) & 63, cg = idx & 7;
            int chc = col + 1;
            int elem = ((rr * 66 + chc) * 64 + cg * 8) ^ ((chc & 7) << 3);
            *(short8b*)&lds_x[elem] = vreg[it];
        }
        if (cc < 9) {
            #pragma unroll
            for (int it = 0; it < 6; ++it) {
                int idx = it * 256 + tid;
                int rr = idx >> 9, col = (idx >> 3) & 63, cg = idx & 7;
                int gr = y - 1 + rr;
                short8b t{};
                if (gr >= 0 && gr < 64)
                    t = *(const short8b*)(amulH + ((size_t)(n * PP + gr * 64 + col)) * 640
                                          + (cc + 1) * 64 + cg * 8);
                vreg[it] = t;
            }
        }
        __syncthreads();
        #pragma unroll
        for (int k9 = 0; k9 < 9; ++k9) {
            const int ky = k9 / 3, kx = k9 % 3;
            const int u = k9 * 10 + cc;
            WLOAD(wB, u, 1)
            {   // ks = 0
                short8b bfr[2];
                #pragma unroll
                for (int nf = 0; nf < 2; ++nf) {
                    int px = pw * 32 + nf * 16 + (lane & 15);
                    int chc = px + kx;
                    int elem = ((ky * 66 + chc) * 64 + 0 * 32 + (lane >> 4) * 8)
                               ^ ((chc & 7) << 3);
                    bfr[nf] = *(const short8b*)&lds_x[elem];
                }
                #pragma unroll
                for (int mf = 0; mf < 4; ++mf)
                    #pragma unroll
                    for (int nf = 0; nf < 2; ++nf)
                        acc[mf][nf] = __builtin_amdgcn_mfma_f32_16x16x32_bf16(
                            wA[mf], bfr[nf], acc[mf][nf], 0, 0, 0);
            }
            {
                const int unext = (k9 < 8) ? (u + 10) : (cc + 1);
                WLOAD(wA, unext, 0)
            }
            {   // ks = 1
                short8b bfr[2];
                #pragma unroll
                for (int nf = 0; nf < 2; ++nf) {
                    int px = pw * 32 + nf * 16 + (lane & 15);
                    int chc = px + kx;
                    int elem = ((ky * 66 + chc) * 64 + 1 * 32 + (lane >> 4) * 8)
                               ^ ((chc & 7) << 3);
                    bfr[nf] = *(const short8b*)&lds_x[elem];
                }
                #pragma unroll
                for (int mf = 0; mf < 4; ++mf)
                    #pragma unroll
                    for (int nf = 0; nf < 2; ++nf)
                        acc[mf][nf] = __builtin_amdgcn_mfma_f32_16x16x32_bf16(
                            wB[mf], bfr[nf], acc[mf][nf], 0, 0, 0);
            }
        }
    }
    // epilogue: bias+relu into LDS (f32 [64][66]), then full-line NCHW stores
    float* lds_f = (float*)lds_x;
    #pragma unroll
    for (int oh = 0; oh < 2; ++oh) {
        __syncthreads();
        if (mw == oh) {
            #pragma unroll
            for (int mf = 0; mf < 4; ++mf)
                #pragma unroll
                for (int r = 0; r < 4; ++r) {
                    int orow = mf * 16 + (lane >> 4) * 4 + r;   // 0..63
                    float b = bot[bx * 128 + oh * 64 + orow];
                    #pragma unroll
                    for (int nf = 0; nf < 2; ++nf) {
                        int p = pw * 32 + nf * 16 + (lane & 15);
                        float v = acc[mf][nf][r] + b;
                        lds_f[orow * 66 + p] = v > 0.f ? v : 0.f;
                    }
                }
        }
        __syncthreads();
        #pragma unroll
        for (int it = 0; it < 16; ++it) {
            int idx = it * 256 + tid;
            int orow = idx >> 6, col = idx & 63;
            out_a[((size_t)(n * 256 + bx * 128 + oh * 64 + orow)) * PP + y * 64 + col]
                = lds_f[orow * 66 + col];
        }
    }
}

// ---------------------------------------------------------------------------
extern "C" void kernel_launch(void* const* d_in, const int* in_sizes, int n_in,
                              void* d_out, int out_size, void* d_ws, size_t ws_size,
                              hipStream_t stream) {
    static const int want[18] = {
        8388608, 8388608, 8388608, 2097152, 196608, 256, 16384, 16384,
        65536, 256, 32768, 128, 81920, 128, 81920, 640, 1474560, 256
    };
    const void* ptr[18];
    bool used[64];
    for (int i = 0; i < 64; ++i) used[i] = false;
    bool ok = (n_in >= 18 && n_in <= 64);
    for (int k = 0; k < 18 && ok; ++k) {
        ptr[k] = nullptr;
        for (int i = 0; i < n_in; ++i) {
            if (!used[i] && in_sizes[i] == want[k]) { ptr[k] = d_in[i]; used[i] = true; break; }
        }
        if (!ptr[k]) ok = false;
    }
    if (!ok) { for (int k = 0; k < 18; ++k) ptr[k] = d_in[k]; }

    const float* sx1  = (const float*)ptr[0];
    const float* sx2  = (const float*)ptr[1];
    const float* t_hx = (const float*)ptr[2];
    const float* tx   = (const float*)ptr[3];
    const float* Wt1  = (const float*)ptr[4];
    const float* bt1  = (const float*)ptr[5];
    const float* Wt2  = (const float*)ptr[6];
    const float* Wt3  = (const float*)ptr[7];
    const float* WU   = (const float*)ptr[8];
    const float* bU   = (const float*)ptr[9];
    const float* WV   = (const float*)ptr[10];
    const float* bV   = (const float*)ptr[11];
    const float* Wa1  = (const float*)ptr[12];
    const float* ba1  = (const float*)ptr[13];
    const float* Wa2  = (const float*)ptr[14];
    const float* ba2  = (const float*)ptr[15];
    const float* Wot  = (const float*)ptr[16];
    const float* bot  = (const float*)ptr[17];

    // Workspace (peak 96.42 MB; proven available in R4/R5):
    char* base = (char*)d_ws;
    short* txc   = (short*)base;
    short* sxh1  = (short*)(base + (size_t)33554432);
    short* sxh2  = (short*)(base + (size_t)50331648);
    short* bUh   = sxh1;                                   // reuse (sxh1 dead after gap)
    short* amulH = (short*)(base + (size_t)33554432);
    short* txh   = (short*)(base + (size_t)75497472);
    short* bVh   = (short*)(base + (size_t)75497472);
    short* a1h   = (short*)(base + (size_t)83886080);
    float* part  = (float*)(base + (size_t)92274688);
    float* wvec  = (float*)(base + (size_t)92536832);
    short* Wt1p  = (short*)(base + (size_t)92545024);
    short* WUp   = (short*)(base + (size_t)92938240);
    short* WVp   = (short*)(base + (size_t)93069312);
    short* Wa1p  = (short*)(base + (size_t)93134848);
    short* Wa2p  = (short*)(base + (size_t)93298688);
    short* Wotp  = (short*)(base + (size_t)93462528);

    float* out_a = (float*)d_out;
    float* out_w = out_a + (size_t)8 * 256 * PP;

    // weight packs
    k_wpack<<<dim3(96), 256, 0, stream>>>(Wt1, Wt1p, 16, 768);
    k_wpack<<<dim3(32), 256, 0, stream>>>(WU,  WUp,  16, 256);
    k_wpack<<<dim3(16), 256, 0, stream>>>(WV,  WVp,   8, 256);
    k_wpack<<<dim3(40), 256, 0, stream>>>(Wa1, Wa1p,  8, 640);
    k_wpack<<<dim3(40), 256, 0, stream>>>(Wa2, Wa2p, 40, 128);
    k_wprep<<<dim3(720), 256, 0, stream>>>(Wot, Wotp);

    // layout conversion: f32 NCHW -> bf16 NHWC
    k_t2h<<<dim3(64, 4, 8), 256, 0, stream>>>(sx1,  sxh1, 256, 4096, 256, 0);
    k_t2h<<<dim3(64, 4, 8), 256, 0, stream>>>(sx2,  sxh2, 256, 4096, 256, 0);
    k_t2h<<<dim3(64, 4, 8), 256, 0, stream>>>(t_hx, txc,  256, 4096, 512, 0);
    k_t2h<<<dim3(16, 4, 8), 256, 0, stream>>>(tx,   txh,  256, 1024, 256, 0);
    k_up <<<dim3(512, 1, 8), 256, 0, stream>>>(txh, txc);

    // main pipeline
    k_gemm_gap <<<dim3(2, 32, 8), 256, 0, stream>>>(sxh1, txc, Wt1p, bt1, part);
    k_wvec     <<<dim3(8),        256, 0, stream>>>(part, Wt2, Wt3, wvec, out_w);
    k_gemm_bU  <<<dim3(2, 32, 8), 256, 0, stream>>>(sxh2, WUp, bU, wvec, bUh);
    k_gemm_bV  <<<dim3(1, 32, 8), 256, 0, stream>>>(bUh, WVp, bV, bVh);
    k_gemm_a1  <<<dim3(1, 32, 8), 256, 0, stream>>>(bVh, txc, Wa1p, ba1, a1h);
    k_gemm_amul<<<dim3(5, 32, 8), 256, 0, stream>>>(a1h, Wa2p, ba2, bVh, txc, amulH);
    k_conv3_mfma<<<dim3(64, 2, 8), 256, 0, stream>>>(amulH, Wotp, bot, out_a);
}

// Round 9
// 292.047 us; speedup vs baseline: 14.4083x; 1.2577x over previous
//
#include <hip/hip_runtime.h>
#include <hip/hip_bf16.h>

#define PP 4096          // H*W
#define HH 64
#define WW 64

typedef __attribute__((ext_vector_type(8))) short short8b;   // 8 bf16
typedef __attribute__((ext_vector_type(4))) float f32x4;

static __device__ __forceinline__ float bf2f(short s) {
    union { unsigned int u; float f; } cv; cv.u = ((unsigned int)(unsigned short)s) << 16; return cv.f;
}
static __device__ __forceinline__ short f2bf(float f) {
    __hip_bfloat16 h = __float2bfloat16(f);
    return *reinterpret_cast<short*>(&h);
}

// ---------------------------------------------------------------------------
// Pack f32 weight [M][K] into MFMA B-fragment order bf16 (R4/R5-validated).
// ---------------------------------------------------------------------------
__global__ void k_wpack(const float* __restrict__ W, short* __restrict__ dst,
                        int MT, int K) {
    int s = blockIdx.x * 256 + threadIdx.x;
    int total = MT * 2 * (K / 64) * 64;      // short8b slots
    if (s >= total) return;
    int lane = s & 63;
    int rest = s >> 6;
    int ks = rest & 1; rest >>= 1;
    int mt = rest % MT;
    int cc = rest / MT;
    int o   = mt * 16 + (lane & 15);
    int ch0 = cc * 64 + ks * 32 + (lane >> 4) * 8;
    short8b v;
    #pragma unroll
    for (int j = 0; j < 8; ++j) v[j] = f2bf(W[(size_t)o * K + ch0 + j]);
    ((short8b*)dst)[s] = v;
}

// ---------------------------------------------------------------------------
// f32 NCHW -> bf16 NHWC transpose (LDS 64x64 tile, +1 pad).
// ---------------------------------------------------------------------------
__global__ void k_t2h(const float* __restrict__ src, short* __restrict__ dst,
                      int C, int P, int pitch, int colOff) {
    __shared__ short T[64 * 65];
    int tid = threadIdx.x;
    int p0 = blockIdx.x * 64, c0 = blockIdx.y * 64, n = blockIdx.z;
    #pragma unroll
    for (int it = 0; it < 16; ++it) {
        int slot = it * 256 + tid;
        int ch = slot >> 6, px = slot & 63;
        T[ch * 65 + px] = f2bf(src[((size_t)(n * C + c0 + ch)) * P + p0 + px]);
    }
    __syncthreads();
    #pragma unroll
    for (int it = 0; it < 16; ++it) {
        int slot = it * 256 + tid;
        int px = slot >> 6, ch = slot & 63;
        dst[((size_t)n * P + p0 + px) * pitch + colOff + c0 + ch] = T[ch * 65 + px];
    }
}

// ---------------------------------------------------------------------------
// Bilinear 2x upsample (align_corners) txh NHWC [n][1024][256] -> txc cols 256..511.
// ---------------------------------------------------------------------------
__global__ void k_up(const short* __restrict__ txh, short* __restrict__ txc) {
    int tid = threadIdx.x;
    int cg = tid & 31, pxl = tid >> 5;
    int px = blockIdx.x * 8 + pxl;
    int n  = blockIdx.z;
    int y = px >> 6, x = px & 63;
    const float s = 31.0f / 63.0f;
    float fy = y * s, fx = x * s;
    int y0 = (int)fy, x0 = (int)fx;
    int y1 = min(y0 + 1, 31), x1 = min(x0 + 1, 31);
    float wy = fy - (float)y0, wx = fx - (float)x0;
    const short8b* base = (const short8b*)(txh + ((size_t)n * 1024) * 256);
    short8b a = base[((size_t)(y0 * 32 + x0) * 256 + cg * 8) >> 3];
    short8b b = base[((size_t)(y0 * 32 + x1) * 256 + cg * 8) >> 3];
    short8b c = base[((size_t)(y1 * 32 + x0) * 256 + cg * 8) >> 3];
    short8b d = base[((size_t)(y1 * 32 + x1) * 256 + cg * 8) >> 3];
    short8b r;
    #pragma unroll
    for (int j = 0; j < 8; ++j) {
        float v = (bf2f(a[j]) * (1.f - wy) + bf2f(c[j]) * wy) * (1.f - wx)
                + (bf2f(b[j]) * (1.f - wy) + bf2f(d[j]) * wy) * wx;
        r[j] = f2bf(v);
    }
    *(short8b*)(txc + ((size_t)n * PP + px) * 512 + 256 + cg * 8) = r;
}

// ---------------------------------------------------------------------------
// Shared GEMM helpers: LDS tile [128 px][64 ch] bf16, XOR-swizzled.
// ---------------------------------------------------------------------------
static __device__ __forceinline__ void stage64(const short* __restrict__ src, int pitch,
                                               int c0, size_t rowbase, short* lds, int tid) {
    #pragma unroll
    for (int it = 0; it < 4; ++it) {
        int idx = it * 256 + tid;
        int px = idx >> 3, cg = idx & 7;
        short8b v = *(const short8b*)(src + (rowbase + px) * (size_t)pitch + c0 + cg * 8);
        int elem = (px * 64 + cg * 8) ^ ((px & 7) << 3);
        *(short8b*)&lds[elem] = v;
    }
}
static __device__ __forceinline__ short8b afrag(const short* lds, int pw, int mf, int ks, int lane) {
    int px = pw * 64 + mf * 16 + (lane & 15);
    int elem = (px * 64 + ks * 32 + ((lane >> 4) * 8)) ^ ((px & 7) << 3);
    return *(const short8b*)&lds[elem];
}
#define GEMM_PROLOG \
    int tid = threadIdx.x, lane = tid & 63, wid = tid >> 6; \
    int pw = wid & 1, ow = wid >> 1; \
    int bx = blockIdx.x, pt = blockIdx.y, n = blockIdx.z; \
    size_t rowbase = (size_t)n * PP + pt * 128; \
    f32x4 acc[4][4] = {}; (void)bx;
#define GEMM_STEP(MT) { \
    short8b afr[4][2], bfr[4][2]; \
    _Pragma("unroll") for (int mf = 0; mf < 4; ++mf) \
        _Pragma("unroll") for (int ks = 0; ks < 2; ++ks) afr[mf][ks] = afrag(lds, pw, mf, ks, lane); \
    _Pragma("unroll") for (int nf = 0; nf < 4; ++nf) { \
        int mt_g = bx * 8 + ow * 4 + nf; \
        _Pragma("unroll") for (int ks = 0; ks < 2; ++ks) \
            bfr[nf][ks] = wfv[(((size_t)cc * (MT) + mt_g) * 2 + ks) * 64 + lane]; } \
    _Pragma("unroll") for (int ks = 0; ks < 2; ++ks) \
        _Pragma("unroll") for (int mf = 0; mf < 4; ++mf) \
            _Pragma("unroll") for (int nf = 0; nf < 4; ++nf) \
                acc[mf][nf] = __builtin_amdgcn_mfma_f32_16x16x32_bf16(afr[mf][ks], bfr[nf][ks], acc[mf][nf], 0, 0, 0); }

// ---------------------------------------------------------------------------
// GAP GEMM: D[128px][128o] over K=768; epilogue relu(+bias), px-sum -> part.
// ---------------------------------------------------------------------------
__global__ __launch_bounds__(256) void k_gemm_gap(const short* __restrict__ sxh1,
        const short* __restrict__ txc, const short* __restrict__ wf,
        const float* __restrict__ bias, float* __restrict__ part) {
    __shared__ short lds[128 * 64];
    __shared__ float red[128 * 2];
    GEMM_PROLOG
    const short8b* wfv = (const short8b*)wf;
    for (int cc = 0; cc < 12; ++cc) {
        __syncthreads();
        if (cc < 4) stage64(sxh1, 256, cc * 64, rowbase, lds, tid);
        else        stage64(txc, 512, (cc - 4) * 64, rowbase, lds, tid);
        __syncthreads();
        GEMM_STEP(16)
    }
    #pragma unroll
    for (int nf = 0; nf < 4; ++nf) {
        int o = bx * 128 + ow * 64 + nf * 16 + (lane & 15);
        float b = bias[o];
        float s = 0.f;
        #pragma unroll
        for (int mf = 0; mf < 4; ++mf)
            #pragma unroll
            for (int r = 0; r < 4; ++r) {
                float v = acc[mf][nf][r] + b;
                s += v > 0.f ? v : 0.f;
            }
        s += __shfl_xor(s, 16);
        s += __shfl_xor(s, 32);
        if (lane < 16) red[(ow * 64 + nf * 16 + lane) * 2 + pw] = s;
    }
    __syncthreads();
    if (tid < 128)
        part[((size_t)n * 256 + bx * 128 + tid) * 32 + pt] = red[tid * 2] + red[tid * 2 + 1];
}

// ---------------------------------------------------------------------------
// bU GEMM: K=256; relu(+bias)*wvec -> bUh NHWC [n][px][256].
// ---------------------------------------------------------------------------
__global__ __launch_bounds__(256) void k_gemm_bU(const short* __restrict__ sxh2,
        const short* __restrict__ wf, const float* __restrict__ bias,
        const float* __restrict__ wvec, short* __restrict__ bUh) {
    __shared__ short lds[128 * 64];
    GEMM_PROLOG
    const short8b* wfv = (const short8b*)wf;
    for (int cc = 0; cc < 4; ++cc) {
        __syncthreads();
        stage64(sxh2, 256, cc * 64, rowbase, lds, tid);
        __syncthreads();
        GEMM_STEP(16)
    }
    #pragma unroll
    for (int nf = 0; nf < 4; ++nf) {
        int o = bx * 128 + ow * 64 + nf * 16 + (lane & 15);
        float b = bias[o], wv = wvec[n * 256 + o];
        #pragma unroll
        for (int mf = 0; mf < 4; ++mf)
            #pragma unroll
            for (int r = 0; r < 4; ++r) {
                int px = pw * 64 + mf * 16 + (lane >> 4) * 4 + r;
                float v = acc[mf][nf][r] + b;
                v = v > 0.f ? v : 0.f;
                bUh[(rowbase + px) * 256 + o] = f2bf(v * wv);
            }
    }
}

// ---------------------------------------------------------------------------
// bV GEMM: M=128, K=256 (bUh); relu -> bVh [n][px][128].
// ---------------------------------------------------------------------------
__global__ __launch_bounds__(256) void k_gemm_bV(const short* __restrict__ bUh,
        const short* __restrict__ wf, const float* __restrict__ bias,
        short* __restrict__ bVh) {
    __shared__ short lds[128 * 64];
    GEMM_PROLOG
    const short8b* wfv = (const short8b*)wf;
    for (int cc = 0; cc < 4; ++cc) {
        __syncthreads();
        stage64(bUh, 256, cc * 64, rowbase, lds, tid);
        __syncthreads();
        GEMM_STEP(8)
    }
    #pragma unroll
    for (int nf = 0; nf < 4; ++nf) {
        int o = ow * 64 + nf * 16 + (lane & 15);
        float b = bias[o];
        #pragma unroll
        for (int mf = 0; mf < 4; ++mf)
            #pragma unroll
            for (int r = 0; r < 4; ++r) {
                int px = pw * 64 + mf * 16 + (lane >> 4) * 4 + r;
                float v = acc[mf][nf][r] + b;
                bVh[(rowbase + px) * 128 + o] = f2bf(v > 0.f ? v : 0.f);
            }
    }
}

// ---------------------------------------------------------------------------
// a1 GEMM: M=128, K=640 ([bVh;txc]); relu -> a1h [n][px][128].
// ---------------------------------------------------------------------------
__global__ __launch_bounds__(256) void k_gemm_a1(const short* __restrict__ bVh,
        const short* __restrict__ txc, const short* __restrict__ wf,
        const float* __restrict__ bias, short* __restrict__ a1h) {
    __shared__ short lds[128 * 64];
    GEMM_PROLOG
    const short8b* wfv = (const short8b*)wf;
    for (int cc = 0; cc < 10; ++cc) {
        __syncthreads();
        if (cc < 2) stage64(bVh, 128, cc * 64, rowbase, lds, tid);
        else        stage64(txc, 512, (cc - 2) * 64, rowbase, lds, tid);
        __syncthreads();
        GEMM_STEP(8)
    }
    #pragma unroll
    for (int nf = 0; nf < 4; ++nf) {
        int o = ow * 64 + nf * 16 + (lane & 15);
        float b = bias[o];
        #pragma unroll
        for (int mf = 0; mf < 4; ++mf)
            #pragma unroll
            for (int r = 0; r < 4; ++r) {
                int px = pw * 64 + mf * 16 + (lane >> 4) * 4 + r;
                float v = acc[mf][nf][r] + b;
                a1h[(rowbase + px) * 128 + o] = f2bf(v > 0.f ? v : 0.f);
            }
    }
}

// ---------------------------------------------------------------------------
// amul GEMM: M=640, K=128 (a1h); sigmoid * [bVh;txc] -> amulH NHWC [n][px][640].
// ---------------------------------------------------------------------------
__global__ __launch_bounds__(256) void k_gemm_amul(const short* __restrict__ a1h,
        const short* __restrict__ wf, const float* __restrict__ bias,
        const short* __restrict__ bVh, const short* __restrict__ txc,
        short* __restrict__ amulH) {
    __shared__ short lds[128 * 64];
    GEMM_PROLOG
    const short8b* wfv = (const short8b*)wf;
    for (int cc = 0; cc < 2; ++cc) {
        __syncthreads();
        stage64(a1h, 128, cc * 64, rowbase, lds, tid);
        __syncthreads();
        GEMM_STEP(40)
    }
    #pragma unroll
    for (int nf = 0; nf < 4; ++nf) {
        int o = bx * 128 + ow * 64 + nf * 16 + (lane & 15);
        float b = bias[o];
        #pragma unroll
        for (int mf = 0; mf < 4; ++mf)
            #pragma unroll
            for (int r = 0; r < 4; ++r) {
                int px = pw * 64 + mf * 16 + (lane >> 4) * 4 + r;
                float xv = acc[mf][nf][r] + b;
                float sg = 1.0f / (1.0f + expf(-xv));
                float bval = (o < 128) ? bf2f(bVh[(rowbase + px) * 128 + o])
                                       : bf2f(txc[(rowbase + px) * 512 + o - 128]);
                amulH[(rowbase + px) * 640 + o] = f2bf(sg * bval);
            }
    }
}

// ---------------------------------------------------------------------------
// GAP finish + squeeze MLP + L2-normalize.
// ---------------------------------------------------------------------------
__global__ void k_wvec(const float* __restrict__ part, const float* __restrict__ Wt2,
                       const float* __restrict__ Wt3, float* __restrict__ wvec,
                       float* __restrict__ out_w) {
    int n = blockIdx.x, tid = threadIdx.x;
    __shared__ float sm1[256];
    __shared__ float sm2[64];
    __shared__ float smr[4];
    float s = 0.0f;
    #pragma unroll
    for (int t = 0; t < 32; ++t) s += part[(size_t)(n * 256 + tid) * 32 + t];
    sm1[tid] = s * (1.0f / 4096.0f);
    __syncthreads();
    if (tid < 64) {
        float a = 0.0f;
        for (int c = 0; c < 256; ++c) a = fmaf(Wt2[tid * 256 + c], sm1[c], a);
        sm2[tid] = a > 0.0f ? a : 0.0f;
    }
    __syncthreads();
    float w3 = 0.0f;
    for (int e = 0; e < 64; ++e) w3 = fmaf(Wt3[tid * 64 + e], sm2[e], w3);
    float q = w3 * w3;
    int lane = tid & 63, wv = tid >> 6;
    #pragma unroll
    for (int off = 32; off > 0; off >>= 1) q += __shfl_down(q, off);
    if (lane == 0) smr[wv] = q;
    __syncthreads();
    float nrm = sqrtf(smr[0] + smr[1] + smr[2] + smr[3]);
    nrm = fmaxf(nrm, 1e-12f);
    float w = w3 / nrm;
    wvec[n * 256 + tid] = w;
    out_w[n * 256 + tid] = w;
}

// ---------------------------------------------------------------------------
// Conv weight prep (R4-validated): Wot f32 [256][640][3][3] -> A-fragment bf16
// [k9][cc][mt][ks][lane][8]. Chunk u = k9*10+cc has stride 2048 short8b.
// ---------------------------------------------------------------------------
__global__ void k_wprep(const float* __restrict__ Wot, short* __restrict__ Wfrag) {
    int s = blockIdx.x * 256 + threadIdx.x;
    int lane = s & 63;
    int rest = s >> 6;
    int ks = rest & 1;  rest >>= 1;
    int mt = rest & 15; rest >>= 4;
    int cc = rest % 10;
    int k9 = rest / 10;
    int o   = mt * 16 + (lane & 15);
    int ch0 = cc * 64 + ks * 32 + (lane >> 4) * 8;
    short8b v{};
    #pragma unroll
    for (int j = 0; j < 8; ++j)
        v[j] = f2bf(Wot[((size_t)o * 640 + ch0 + j) * 9 + k9]);
    ((short8b*)Wfrag)[s] = v;
}

// ---------------------------------------------------------------------------
// MFMA implicit-GEMM conv3x3, v5: tile 128o x 256px (4 rows), 512 threads
// (8 waves = 2M x 4N; nw = output row in tile), grid (16,2,8) = 1 block/CU.
// The per-(cc,k9) weight working set (16 KB) now fits L1, so the 4 same-mw
// waves' duplicate WLOADs are L1 hits; unique L2 weight traffic drops 4x.
// wA/wB double-buffer + x reg-prefetch (T14) as validated in R6-R8.
// ---------------------------------------------------------------------------
#define WLOAD(dst, u, kss) { \
    _Pragma("unroll") for (int mf = 0; mf < 4; ++mf) { \
        int mt_g = bx * 8 + mw * 4 + mf; \
        dst[mf] = wf[(((size_t)(u) * 16 + mt_g) * 2 + (kss)) * 64 + lane]; } }

__global__ __launch_bounds__(512, 2) void k_conv3_mfma(
        const short* __restrict__ amulH, const short* __restrict__ Wfrag,
        const float* __restrict__ bot, float* __restrict__ out_a) {
    __shared__ short lds_x[6 * 66 * 64];   // 50688 B
    const int tid  = threadIdx.x;          // 0..511
    const int lane = tid & 63;
    const int wid  = tid >> 6;             // 0..7
    const int mw = wid & 1;                // outch-half within 128
    const int nw = wid >> 1;               // output row within 4-row tile
    const int qx = blockIdx.x;             // row-quad (0..15)
    const int bx = blockIdx.y;             // outch half of 256 (0..1)
    const int n  = blockIdx.z;

    f32x4 acc[4][4] = {};
    const short8b* wf = (const short8b*)Wfrag;

    // x staging: 6 slots/thread; slot it covers input row (qx*4 - 1 + it):
    // col = tid>>3 (0..63), cg = tid&7
    const int scol = tid >> 3, scg = tid & 7;
    short8b vreg[6];
    #pragma unroll
    for (int it = 0; it < 6; ++it) {
        int gr = qx * 4 - 1 + it;
        short8b t{};
        if (gr >= 0 && gr < 64)
            t = *(const short8b*)(amulH + ((size_t)(n * PP + gr * 64 + scol)) * 640 + scg * 8);
        vreg[it] = t;
    }
    // zero halo columns once (chc = 0 and 65, 6 rows; never overwritten)
    if (tid < 96) {
        int rr = tid >> 4, side = (tid >> 3) & 1, cg = tid & 7;
        int chc = side ? 65 : 0;
        int elem = ((rr * 66 + chc) * 64 + cg * 8) ^ ((chc & 7) << 3);
        *(short8b*)&lds_x[elem] = short8b{};
    }

    short8b wA[4], wB[4];
    WLOAD(wA, 0, 0)

    for (int cc = 0; cc < 10; ++cc) {
        __syncthreads();
        {
            int chc = scol + 1;
            #pragma unroll
            for (int it = 0; it < 6; ++it) {
                int elem = ((it * 66 + chc) * 64 + scg * 8) ^ ((chc & 7) << 3);
                *(short8b*)&lds_x[elem] = vreg[it];
            }
        }
        if (cc < 9) {
            #pragma unroll
            for (int it = 0; it < 6; ++it) {
                int gr = qx * 4 - 1 + it;
                short8b t{};
                if (gr >= 0 && gr < 64)
                    t = *(const short8b*)(amulH + ((size_t)(n * PP + gr * 64 + scol)) * 640
                                          + (cc + 1) * 64 + scg * 8);
                vreg[it] = t;
            }
        }
        __syncthreads();
        #pragma unroll
        for (int k9 = 0; k9 < 9; ++k9) {
            const int ky = k9 / 3, kx = k9 % 3;
            const int u = k9 * 10 + cc;
            WLOAD(wB, u, 1)
            {   // ks = 0
                short8b bfr[4];
                #pragma unroll
                for (int nf = 0; nf < 4; ++nf) {
                    int col = nf * 16 + (lane & 15);
                    int chc = col + kx;
                    int row_eff = nw + ky;
                    int elem = ((row_eff * 66 + chc) * 64 + 0 * 32 + (lane >> 4) * 8)
                               ^ ((chc & 7) << 3);
                    bfr[nf] = *(const short8b*)&lds_x[elem];
                }
                #pragma unroll
                for (int mf = 0; mf < 4; ++mf)
                    #pragma unroll
                    for (int nf = 0; nf < 4; ++nf)
                        acc[mf][nf] = __builtin_amdgcn_mfma_f32_16x16x32_bf16(
                            wA[mf], bfr[nf], acc[mf][nf], 0, 0, 0);
            }
            {
                const int unext = (k9 < 8) ? (u + 10) : (cc + 1);
                WLOAD(wA, unext, 0)
            }
            {   // ks = 1
                short8b bfr[4];
                #pragma unroll
                for (int nf = 0; nf < 4; ++nf) {
                    int col = nf * 16 + (lane & 15);
                    int chc = col + kx;
                    int row_eff = nw + ky;
                    int elem = ((row_eff * 66 + chc) * 64 + 1 * 32 + (lane >> 4) * 8)
                               ^ ((chc & 7) << 3);
                    bfr[nf] = *(const short8b*)&lds_x[elem];
                }
                #pragma unroll
                for (int mf = 0; mf < 4; ++mf)
                    #pragma unroll
                    for (int nf = 0; nf < 4; ++nf)
                        acc[mf][nf] = __builtin_amdgcn_mfma_f32_16x16x32_bf16(
                            wB[mf], bfr[nf], acc[mf][nf], 0, 0, 0);
            }
        }
    }
    // epilogue: bias + relu, f32 NCHW stores (64B contiguous runs per 16 lanes)
    #pragma unroll
    for (int mf = 0; mf < 4; ++mf) {
        int o = bx * 128 + mw * 64 + mf * 16 + (lane >> 4) * 4;
        #pragma unroll
        for (int r = 0; r < 4; ++r) {
            float bias = bot[o + r];
            #pragma unroll
            for (int nf = 0; nf < 4; ++nf) {
                int p = qx * 256 + nw * 64 + nf * 16 + (lane & 15);
                float v = acc[mf][nf][r] + bias;
                out_a[((size_t)(n * 256 + o + r)) * PP + p] = v > 0.f ? v : 0.f;
            }
        }
    }
}

// ---------------------------------------------------------------------------
extern "C" void kernel_launch(void* const* d_in, const int* in_sizes, int n_in,
                              void* d_out, int out_size, void* d_ws, size_t ws_size,
                              hipStream_t stream) {
    static const int want[18] = {
        8388608, 8388608, 8388608, 2097152, 196608, 256, 16384, 16384,
        65536, 256, 32768, 128, 81920, 128, 81920, 640, 1474560, 256
    };
    const void* ptr[18];
    bool used[64];
    for (int i = 0; i < 64; ++i) used[i] = false;
    bool ok = (n_in >= 18 && n_in <= 64);
    for (int k = 0; k < 18 && ok; ++k) {
        ptr[k] = nullptr;
        for (int i = 0; i < n_in; ++i) {
            if (!used[i] && in_sizes[i] == want[k]) { ptr[k] = d_in[i]; used[i] = true; break; }
        }
        if (!ptr[k]) ok = false;
    }
    if (!ok) { for (int k = 0; k < 18; ++k) ptr[k] = d_in[k]; }

    const float* sx1  = (const float*)ptr[0];
    const float* sx2  = (const float*)ptr[1];
    const float* t_hx = (const float*)ptr[2];
    const float* tx   = (const float*)ptr[3];
    const float* Wt1  = (const float*)ptr[4];
    const float* bt1  = (const float*)ptr[5];
    const float* Wt2  = (const float*)ptr[6];
    const float* Wt3  = (const float*)ptr[7];
    const float* WU   = (const float*)ptr[8];
    const float* bU   = (const float*)ptr[9];
    const float* WV   = (const float*)ptr[10];
    const float* bV   = (const float*)ptr[11];
    const float* Wa1  = (const float*)ptr[12];
    const float* ba1  = (const float*)ptr[13];
    const float* Wa2  = (const float*)ptr[14];
    const float* ba2  = (const float*)ptr[15];
    const float* Wot  = (const float*)ptr[16];
    const float* bot  = (const float*)ptr[17];

    // Workspace (peak 96.42 MB; proven available in R4/R5):
    char* base = (char*)d_ws;
    short* txc   = (short*)base;
    short* sxh1  = (short*)(base + (size_t)33554432);
    short* sxh2  = (short*)(base + (size_t)50331648);
    short* bUh   = sxh1;                                   // reuse (sxh1 dead after gap)
    short* amulH = (short*)(base + (size_t)33554432);
    short* txh   = (short*)(base + (size_t)75497472);
    short* bVh   = (short*)(base + (size_t)75497472);
    short* a1h   = (short*)(base + (size_t)83886080);
    float* part  = (float*)(base + (size_t)92274688);
    float* wvec  = (float*)(base + (size_t)92536832);
    short* Wt1p  = (short*)(base + (size_t)92545024);
    short* WUp   = (short*)(base + (size_t)92938240);
    short* WVp   = (short*)(base + (size_t)93069312);
    short* Wa1p  = (short*)(base + (size_t)93134848);
    short* Wa2p  = (short*)(base + (size_t)93298688);
    short* Wotp  = (short*)(base + (size_t)93462528);

    float* out_a = (float*)d_out;
    float* out_w = out_a + (size_t)8 * 256 * PP;

    // weight packs
    k_wpack<<<dim3(96), 256, 0, stream>>>(Wt1, Wt1p, 16, 768);
    k_wpack<<<dim3(32), 256, 0, stream>>>(WU,  WUp,  16, 256);
    k_wpack<<<dim3(16), 256, 0, stream>>>(WV,  WVp,   8, 256);
    k_wpack<<<dim3(40), 256, 0, stream>>>(Wa1, Wa1p,  8, 640);
    k_wpack<<<dim3(40), 256, 0, stream>>>(Wa2, Wa2p, 40, 128);
    k_wprep<<<dim3(720), 256, 0, stream>>>(Wot, Wotp);

    // layout conversion: f32 NCHW -> bf16 NHWC
    k_t2h<<<dim3(64, 4, 8), 256, 0, stream>>>(sx1,  sxh1, 256, 4096, 256, 0);
    k_t2h<<<dim3(64, 4, 8), 256, 0, stream>>>(sx2,  sxh2, 256, 4096, 256, 0);
    k_t2h<<<dim3(64, 4, 8), 256, 0, stream>>>(t_hx, txc,  256, 4096, 512, 0);
    k_t2h<<<dim3(16, 4, 8), 256, 0, stream>>>(tx,   txh,  256, 1024, 256, 0);
    k_up <<<dim3(512, 1, 8), 256, 0, stream>>>(txh, txc);

    // main pipeline
    k_gemm_gap <<<dim3(2, 32, 8), 256, 0, stream>>>(sxh1, txc, Wt1p, bt1, part);
    k_wvec     <<<dim3(8),        256, 0, stream>>>(part, Wt2, Wt3, wvec, out_w);
    k_gemm_bU  <<<dim3(2, 32, 8), 256, 0, stream>>>(sxh2, WUp, bU, wvec, bUh);
    k_gemm_bV  <<<dim3(1, 32, 8), 256, 0, stream>>>(bUh, WVp, bV, bVh);
    k_gemm_a1  <<<dim3(1, 32, 8), 256, 0, stream>>>(bVh, txc, Wa1p, ba1, a1h);
    k_gemm_amul<<<dim3(5, 32, 8), 256, 0, stream>>>(a1h, Wa2p, ba2, bVh, txc, amulH);
    k_conv3_mfma<<<dim3(16, 2, 8), 512, 0, stream>>>(amulH, Wotp, bot, out_a);
}

// Round 10
// 290.193 us; speedup vs baseline: 14.5003x; 1.0064x over previous
//
#include <hip/hip_runtime.h>
#include <hip/hip_bf16.h>

#define PP 4096          // H*W
#define HH 64
#define WW 64

typedef __attribute__((ext_vector_type(8))) short short8b;   // 8 bf16
typedef __attribute__((ext_vector_type(4))) float f32x4;

static __device__ __forceinline__ float bf2f(short s) {
    union { unsigned int u; float f; } cv; cv.u = ((unsigned int)(unsigned short)s) << 16; return cv.f;
}
static __device__ __forceinline__ short f2bf(float f) {
    __hip_bfloat16 h = __float2bfloat16(f);
    return *reinterpret_cast<short*>(&h);
}

// ---------------------------------------------------------------------------
// Pack f32 weight [M][K] into MFMA B-fragment order bf16 (R4/R5-validated).
// ---------------------------------------------------------------------------
__global__ void k_wpack(const float* __restrict__ W, short* __restrict__ dst,
                        int MT, int K) {
    int s = blockIdx.x * 256 + threadIdx.x;
    int total = MT * 2 * (K / 64) * 64;      // short8b slots
    if (s >= total) return;
    int lane = s & 63;
    int rest = s >> 6;
    int ks = rest & 1; rest >>= 1;
    int mt = rest % MT;
    int cc = rest / MT;
    int o   = mt * 16 + (lane & 15);
    int ch0 = cc * 64 + ks * 32 + (lane >> 4) * 8;
    short8b v;
    #pragma unroll
    for (int j = 0; j < 8; ++j) v[j] = f2bf(W[(size_t)o * K + ch0 + j]);
    ((short8b*)dst)[s] = v;
}

// ---------------------------------------------------------------------------
// f32 NCHW -> bf16 NHWC transpose (LDS 64x64 tile, +1 pad).
// ---------------------------------------------------------------------------
__global__ void k_t2h(const float* __restrict__ src, short* __restrict__ dst,
                      int C, int P, int pitch, int colOff) {
    __shared__ short T[64 * 65];
    int tid = threadIdx.x;
    int p0 = blockIdx.x * 64, c0 = blockIdx.y * 64, n = blockIdx.z;
    #pragma unroll
    for (int it = 0; it < 16; ++it) {
        int slot = it * 256 + tid;
        int ch = slot >> 6, px = slot & 63;
        T[ch * 65 + px] = f2bf(src[((size_t)(n * C + c0 + ch)) * P + p0 + px]);
    }
    __syncthreads();
    #pragma unroll
    for (int it = 0; it < 16; ++it) {
        int slot = it * 256 + tid;
        int px = slot >> 6, ch = slot & 63;
        dst[((size_t)n * P + p0 + px) * pitch + colOff + c0 + ch] = T[ch * 65 + px];
    }
}

// ---------------------------------------------------------------------------
// Bilinear 2x upsample (align_corners) txh NHWC [n][1024][256] -> txc cols 256..511.
// ---------------------------------------------------------------------------
__global__ void k_up(const short* __restrict__ txh, short* __restrict__ txc) {
    int tid = threadIdx.x;
    int cg = tid & 31, pxl = tid >> 5;
    int px = blockIdx.x * 8 + pxl;
    int n  = blockIdx.z;
    int y = px >> 6, x = px & 63;
    const float s = 31.0f / 63.0f;
    float fy = y * s, fx = x * s;
    int y0 = (int)fy, x0 = (int)fx;
    int y1 = min(y0 + 1, 31), x1 = min(x0 + 1, 31);
    float wy = fy - (float)y0, wx = fx - (float)x0;
    const short8b* base = (const short8b*)(txh + ((size_t)n * 1024) * 256);
    short8b a = base[((size_t)(y0 * 32 + x0) * 256 + cg * 8) >> 3];
    short8b b = base[((size_t)(y0 * 32 + x1) * 256 + cg * 8) >> 3];
    short8b c = base[((size_t)(y1 * 32 + x0) * 256 + cg * 8) >> 3];
    short8b d = base[((size_t)(y1 * 32 + x1) * 256 + cg * 8) >> 3];
    short8b r;
    #pragma unroll
    for (int j = 0; j < 8; ++j) {
        float v = (bf2f(a[j]) * (1.f - wy) + bf2f(c[j]) * wy) * (1.f - wx)
                + (bf2f(b[j]) * (1.f - wy) + bf2f(d[j]) * wy) * wx;
        r[j] = f2bf(v);
    }
    *(short8b*)(txc + ((size_t)n * PP + px) * 512 + 256 + cg * 8) = r;
}

// ---------------------------------------------------------------------------
// Shared GEMM helpers: LDS tile [128 px][64 ch] bf16, XOR-swizzled.
// ---------------------------------------------------------------------------
static __device__ __forceinline__ void stage64(const short* __restrict__ src, int pitch,
                                               int c0, size_t rowbase, short* lds, int tid) {
    #pragma unroll
    for (int it = 0; it < 4; ++it) {
        int idx = it * 256 + tid;
        int px = idx >> 3, cg = idx & 7;
        short8b v = *(const short8b*)(src + (rowbase + px) * (size_t)pitch + c0 + cg * 8);
        int elem = (px * 64 + cg * 8) ^ ((px & 7) << 3);
        *(short8b*)&lds[elem] = v;
    }
}
static __device__ __forceinline__ short8b afrag(const short* lds, int pw, int mf, int ks, int lane) {
    int px = pw * 64 + mf * 16 + (lane & 15);
    int elem = (px * 64 + ks * 32 + ((lane >> 4) * 8)) ^ ((px & 7) << 3);
    return *(const short8b*)&lds[elem];
}
#define GEMM_PROLOG \
    int tid = threadIdx.x, lane = tid & 63, wid = tid >> 6; \
    int pw = wid & 1, ow = wid >> 1; \
    int bx = blockIdx.x, pt = blockIdx.y, n = blockIdx.z; \
    size_t rowbase = (size_t)n * PP + pt * 128; \
    f32x4 acc[4][4] = {}; (void)bx;
#define GEMM_STEP(MT) { \
    short8b afr[4][2], bfr[4][2]; \
    _Pragma("unroll") for (int mf = 0; mf < 4; ++mf) \
        _Pragma("unroll") for (int ks = 0; ks < 2; ++ks) afr[mf][ks] = afrag(lds, pw, mf, ks, lane); \
    _Pragma("unroll") for (int nf = 0; nf < 4; ++nf) { \
        int mt_g = bx * 8 + ow * 4 + nf; \
        _Pragma("unroll") for (int ks = 0; ks < 2; ++ks) \
            bfr[nf][ks] = wfv[(((size_t)cc * (MT) + mt_g) * 2 + ks) * 64 + lane]; } \
    _Pragma("unroll") for (int ks = 0; ks < 2; ++ks) \
        _Pragma("unroll") for (int mf = 0; mf < 4; ++mf) \
            _Pragma("unroll") for (int nf = 0; nf < 4; ++nf) \
                acc[mf][nf] = __builtin_amdgcn_mfma_f32_16x16x32_bf16(afr[mf][ks], bfr[nf][ks], acc[mf][nf], 0, 0, 0); }

// ---------------------------------------------------------------------------
// GAP GEMM: D[128px][128o] over K=768; epilogue relu(+bias), px-sum -> part.
// ---------------------------------------------------------------------------
__global__ __launch_bounds__(256) void k_gemm_gap(const short* __restrict__ sxh1,
        const short* __restrict__ txc, const short* __restrict__ wf,
        const float* __restrict__ bias, float* __restrict__ part) {
    __shared__ short lds[128 * 64];
    __shared__ float red[128 * 2];
    GEMM_PROLOG
    const short8b* wfv = (const short8b*)wf;
    for (int cc = 0; cc < 12; ++cc) {
        __syncthreads();
        if (cc < 4) stage64(sxh1, 256, cc * 64, rowbase, lds, tid);
        else        stage64(txc, 512, (cc - 4) * 64, rowbase, lds, tid);
        __syncthreads();
        GEMM_STEP(16)
    }
    #pragma unroll
    for (int nf = 0; nf < 4; ++nf) {
        int o = bx * 128 + ow * 64 + nf * 16 + (lane & 15);
        float b = bias[o];
        float s = 0.f;
        #pragma unroll
        for (int mf = 0; mf < 4; ++mf)
            #pragma unroll
            for (int r = 0; r < 4; ++r) {
                float v = acc[mf][nf][r] + b;
                s += v > 0.f ? v : 0.f;
            }
        s += __shfl_xor(s, 16);
        s += __shfl_xor(s, 32);
        if (lane < 16) red[(ow * 64 + nf * 16 + lane) * 2 + pw] = s;
    }
    __syncthreads();
    if (tid < 128)
        part[((size_t)n * 256 + bx * 128 + tid) * 32 + pt] = red[tid * 2] + red[tid * 2 + 1];
}

// ---------------------------------------------------------------------------
// bU GEMM: K=256; relu(+bias)*wvec -> bUh NHWC [n][px][256].
// ---------------------------------------------------------------------------
__global__ __launch_bounds__(256) void k_gemm_bU(const short* __restrict__ sxh2,
        const short* __restrict__ wf, const float* __restrict__ bias,
        const float* __restrict__ wvec, short* __restrict__ bUh) {
    __shared__ short lds[128 * 64];
    GEMM_PROLOG
    const short8b* wfv = (const short8b*)wf;
    for (int cc = 0; cc < 4; ++cc) {
        __syncthreads();
        stage64(sxh2, 256, cc * 64, rowbase, lds, tid);
        __syncthreads();
        GEMM_STEP(16)
    }
    #pragma unroll
    for (int nf = 0; nf < 4; ++nf) {
        int o = bx * 128 + ow * 64 + nf * 16 + (lane & 15);
        float b = bias[o], wv = wvec[n * 256 + o];
        #pragma unroll
        for (int mf = 0; mf < 4; ++mf)
            #pragma unroll
            for (int r = 0; r < 4; ++r) {
                int px = pw * 64 + mf * 16 + (lane >> 4) * 4 + r;
                float v = acc[mf][nf][r] + b;
                v = v > 0.f ? v : 0.f;
                bUh[(rowbase + px) * 256 + o] = f2bf(v * wv);
            }
    }
}

// ---------------------------------------------------------------------------
// bV GEMM: M=128, K=256 (bUh); relu -> bVh [n][px][128].
// ---------------------------------------------------------------------------
__global__ __launch_bounds__(256) void k_gemm_bV(const short* __restrict__ bUh,
        const short* __restrict__ wf, const float* __restrict__ bias,
        short* __restrict__ bVh) {
    __shared__ short lds[128 * 64];
    GEMM_PROLOG
    const short8b* wfv = (const short8b*)wf;
    for (int cc = 0; cc < 4; ++cc) {
        __syncthreads();
        stage64(bUh, 256, cc * 64, rowbase, lds, tid);
        __syncthreads();
        GEMM_STEP(8)
    }
    #pragma unroll
    for (int nf = 0; nf < 4; ++nf) {
        int o = ow * 64 + nf * 16 + (lane & 15);
        float b = bias[o];
        #pragma unroll
        for (int mf = 0; mf < 4; ++mf)
            #pragma unroll
            for (int r = 0; r < 4; ++r) {
                int px = pw * 64 + mf * 16 + (lane >> 4) * 4 + r;
                float v = acc[mf][nf][r] + b;
                bVh[(rowbase + px) * 128 + o] = f2bf(v > 0.f ? v : 0.f);
            }
    }
}

// ---------------------------------------------------------------------------
// a1 GEMM: M=128, K=640 ([bVh;txc]); relu -> a1h [n][px][128].
// ---------------------------------------------------------------------------
__global__ __launch_bounds__(256) void k_gemm_a1(const short* __restrict__ bVh,
        const short* __restrict__ txc, const short* __restrict__ wf,
        const float* __restrict__ bias, short* __restrict__ a1h) {
    __shared__ short lds[128 * 64];
    GEMM_PROLOG
    const short8b* wfv = (const short8b*)wf;
    for (int cc = 0; cc < 10; ++cc) {
        __syncthreads();
        if (cc < 2) stage64(bVh, 128, cc * 64, rowbase, lds, tid);
        else        stage64(txc, 512, (cc - 2) * 64, rowbase, lds, tid);
        __syncthreads();
        GEMM_STEP(8)
    }
    #pragma unroll
    for (int nf = 0; nf < 4; ++nf) {
        int o = ow * 64 + nf * 16 + (lane & 15);
        float b = bias[o];
        #pragma unroll
        for (int mf = 0; mf < 4; ++mf)
            #pragma unroll
            for (int r = 0; r < 4; ++r) {
                int px = pw * 64 + mf * 16 + (lane >> 4) * 4 + r;
                float v = acc[mf][nf][r] + b;
                a1h[(rowbase + px) * 128 + o] = f2bf(v > 0.f ? v : 0.f);
            }
    }
}

// ---------------------------------------------------------------------------
// amul GEMM: M=640, K=128 (a1h); sigmoid * [bVh;txc] -> amulH NHWC [n][px][640].
// ---------------------------------------------------------------------------
__global__ __launch_bounds__(256) void k_gemm_amul(const short* __restrict__ a1h,
        const short* __restrict__ wf, const float* __restrict__ bias,
        const short* __restrict__ bVh, const short* __restrict__ txc,
        short* __restrict__ amulH) {
    __shared__ short lds[128 * 64];
    GEMM_PROLOG
    const short8b* wfv = (const short8b*)wf;
    for (int cc = 0; cc < 2; ++cc) {
        __syncthreads();
        stage64(a1h, 128, cc * 64, rowbase, lds, tid);
        __syncthreads();
        GEMM_STEP(40)
    }
    #pragma unroll
    for (int nf = 0; nf < 4; ++nf) {
        int o = bx * 128 + ow * 64 + nf * 16 + (lane & 15);
        float b = bias[o];
        #pragma unroll
        for (int mf = 0; mf < 4; ++mf)
            #pragma unroll
            for (int r = 0; r < 4; ++r) {
                int px = pw * 64 + mf * 16 + (lane >> 4) * 4 + r;
                float xv = acc[mf][nf][r] + b;
                float sg = 1.0f / (1.0f + expf(-xv));
                float bval = (o < 128) ? bf2f(bVh[(rowbase + px) * 128 + o])
                                       : bf2f(txc[(rowbase + px) * 512 + o - 128]);
                amulH[(rowbase + px) * 640 + o] = f2bf(sg * bval);
            }
    }
}

// ---------------------------------------------------------------------------
// GAP finish + squeeze MLP + L2-normalize.
// ---------------------------------------------------------------------------
__global__ void k_wvec(const float* __restrict__ part, const float* __restrict__ Wt2,
                       const float* __restrict__ Wt3, float* __restrict__ wvec,
                       float* __restrict__ out_w) {
    int n = blockIdx.x, tid = threadIdx.x;
    __shared__ float sm1[256];
    __shared__ float sm2[64];
    __shared__ float smr[4];
    float s = 0.0f;
    #pragma unroll
    for (int t = 0; t < 32; ++t) s += part[(size_t)(n * 256 + tid) * 32 + t];
    sm1[tid] = s * (1.0f / 4096.0f);
    __syncthreads();
    if (tid < 64) {
        float a = 0.0f;
        for (int c = 0; c < 256; ++c) a = fmaf(Wt2[tid * 256 + c], sm1[c], a);
        sm2[tid] = a > 0.0f ? a : 0.0f;
    }
    __syncthreads();
    float w3 = 0.0f;
    for (int e = 0; e < 64; ++e) w3 = fmaf(Wt3[tid * 64 + e], sm2[e], w3);
    float q = w3 * w3;
    int lane = tid & 63, wv = tid >> 6;
    #pragma unroll
    for (int off = 32; off > 0; off >>= 1) q += __shfl_down(q, off);
    if (lane == 0) smr[wv] = q;
    __syncthreads();
    float nrm = sqrtf(smr[0] + smr[1] + smr[2] + smr[3]);
    nrm = fmaxf(nrm, 1e-12f);
    float w = w3 / nrm;
    wvec[n * 256 + tid] = w;
    out_w[n * 256 + tid] = w;
}

// ---------------------------------------------------------------------------
// Conv weight prep (R4-validated): Wot f32 [256][640][3][3] -> A-fragment bf16
// [k9][cc][mt][ks][lane][8]. Chunk u = k9*10+cc has stride 2048 short8b.
// ---------------------------------------------------------------------------
__global__ void k_wprep(const float* __restrict__ Wot, short* __restrict__ Wfrag) {
    int s = blockIdx.x * 256 + threadIdx.x;
    int lane = s & 63;
    int rest = s >> 6;
    int ks = rest & 1;  rest >>= 1;
    int mt = rest & 15; rest >>= 4;
    int cc = rest % 10;
    int k9 = rest / 10;
    int o   = mt * 16 + (lane & 15);
    int ch0 = cc * 64 + ks * 32 + (lane >> 4) * 8;
    short8b v{};
    #pragma unroll
    for (int j = 0; j < 8; ++j)
        v[j] = f2bf(Wot[((size_t)o * 640 + ch0 + j) * 9 + k9]);
    ((short8b*)Wfrag)[s] = v;
}

// ---------------------------------------------------------------------------
// MFMA implicit-GEMM conv3x3, v6: R9 geometry (128o x 256px, 512 thr, 8 waves
// 2M x 4N, grid (16,2,8) = 1 block/CU) + one-half-step-deep software pipeline:
// each half-step h issues h+1's 4 ds_reads (bfr ping-pong) and 4 weight loads
// (wA/wB ping-pong) BEFORE its 16 MFMAs. Fully unrolled -> compile-time regs.
// Pipeline drains only at the cc-boundary barrier (1 of 18 half-steps).
// ---------------------------------------------------------------------------
#define WLOAD(dst, u, kss) { \
    _Pragma("unroll") for (int mf = 0; mf < 4; ++mf) { \
        int mt_g = bx * 8 + mw * 4 + mf; \
        dst[mf] = wf[(((size_t)(u) * 16 + mt_g) * 2 + (kss)) * 64 + lane]; } }

#define BLOAD(dst, kyv, kxv, ksv) { \
    _Pragma("unroll") for (int nf = 0; nf < 4; ++nf) { \
        int col = nf * 16 + (lane & 15); \
        int chc = col + (kxv); \
        int row_eff = nw + (kyv); \
        int elem = ((row_eff * 66 + chc) * 64 + (ksv) * 32 + (lane >> 4) * 8) \
                   ^ ((chc & 7) << 3); \
        dst[nf] = *(const short8b*)&lds_x[elem]; } }

#define MFMA16(W, B) { \
    _Pragma("unroll") for (int mf = 0; mf < 4; ++mf) \
        _Pragma("unroll") for (int nf = 0; nf < 4; ++nf) \
            acc[mf][nf] = __builtin_amdgcn_mfma_f32_16x16x32_bf16( \
                W[mf], B[nf], acc[mf][nf], 0, 0, 0); }

__global__ __launch_bounds__(512, 2) void k_conv3_mfma(
        const short* __restrict__ amulH, const short* __restrict__ Wfrag,
        const float* __restrict__ bot, float* __restrict__ out_a) {
    __shared__ short lds_x[6 * 66 * 64];   // 50688 B
    const int tid  = threadIdx.x;          // 0..511
    const int lane = tid & 63;
    const int wid  = tid >> 6;             // 0..7
    const int mw = wid & 1;                // outch-half within 128
    const int nw = wid >> 1;               // output row within 4-row tile
    const int qx = blockIdx.x;             // row-quad (0..15)
    const int bx = blockIdx.y;             // outch half of 256 (0..1)
    const int n  = blockIdx.z;

    f32x4 acc[4][4] = {};
    const short8b* wf = (const short8b*)Wfrag;

    // x staging: 6 slots/thread; slot it covers input row (qx*4 - 1 + it):
    const int scol = tid >> 3, scg = tid & 7;
    short8b vreg[6];
    #pragma unroll
    for (int it = 0; it < 6; ++it) {
        int gr = qx * 4 - 1 + it;
        short8b t{};
        if (gr >= 0 && gr < 64)
            t = *(const short8b*)(amulH + ((size_t)(n * PP + gr * 64 + scol)) * 640 + scg * 8);
        vreg[it] = t;
    }
    // zero halo columns once (chc = 0 and 65, 6 rows; never overwritten)
    if (tid < 96) {
        int rr = tid >> 4, side = (tid >> 3) & 1, cg = tid & 7;
        int chc = side ? 65 : 0;
        int elem = ((rr * 66 + chc) * 64 + cg * 8) ^ ((chc & 7) << 3);
        *(short8b*)&lds_x[elem] = short8b{};
    }

    short8b wA[4], wB[4], bfrA[4], bfrB[4];
    WLOAD(wA, 0, 0)     // (cc=0, k9=0, ks=0)

    for (int cc = 0; cc < 10; ++cc) {
        __syncthreads();
        {
            int chc = scol + 1;
            #pragma unroll
            for (int it = 0; it < 6; ++it) {
                int elem = ((it * 66 + chc) * 64 + scg * 8) ^ ((chc & 7) << 3);
                *(short8b*)&lds_x[elem] = vreg[it];
            }
        }
        if (cc < 9) {
            #pragma unroll
            for (int it = 0; it < 6; ++it) {
                int gr = qx * 4 - 1 + it;
                short8b t{};
                if (gr >= 0 && gr < 64)
                    t = *(const short8b*)(amulH + ((size_t)(n * PP + gr * 64 + scol)) * 640
                                          + (cc + 1) * 64 + scg * 8);
                vreg[it] = t;
            }
        }
        __syncthreads();
        // software-pipelined 18 half-steps: h = (k9<<1)|ks
        BLOAD(bfrA, 0, 0, 0)                 // prefetch h=0 fragments
        #pragma unroll
        for (int h = 0; h < 18; ++h) {
            const bool even = ((h & 1) == 0);
            if (h < 17) {
                const int hn = h + 1;
                const int k9n = hn >> 1, ksn = hn & 1;
                const int kyn = k9n / 3, kxn = k9n % 3;
                const int un = k9n * 10 + cc;
                if (even) { BLOAD(bfrB, kyn, kxn, ksn) WLOAD(wB, un, ksn) }
                else      { BLOAD(bfrA, kyn, kxn, ksn) WLOAD(wA, un, ksn) }
            } else {
                // prefetch next cc's (k9=0, ks=0) weights; cc=9 load is
                // in-bounds (chunk 10) and unused.
                WLOAD(wA, cc + 1, 0)
            }
            if (even) { MFMA16(wA, bfrA) } else { MFMA16(wB, bfrB) }
        }
    }
    // epilogue: bias + relu, f32 NCHW stores (64B contiguous runs per 16 lanes)
    #pragma unroll
    for (int mf = 0; mf < 4; ++mf) {
        int o = bx * 128 + mw * 64 + mf * 16 + (lane >> 4) * 4;
        #pragma unroll
        for (int r = 0; r < 4; ++r) {
            float bias = bot[o + r];
            #pragma unroll
            for (int nf = 0; nf < 4; ++nf) {
                int p = qx * 256 + nw * 64 + nf * 16 + (lane & 15);
                float v = acc[mf][nf][r] + bias;
                out_a[((size_t)(n * 256 + o + r)) * PP + p] = v > 0.f ? v : 0.f;
            }
        }
    }
}

// ---------------------------------------------------------------------------
extern "C" void kernel_launch(void* const* d_in, const int* in_sizes, int n_in,
                              void* d_out, int out_size, void* d_ws, size_t ws_size,
                              hipStream_t stream) {
    static const int want[18] = {
        8388608, 8388608, 8388608, 2097152, 196608, 256, 16384, 16384,
        65536, 256, 32768, 128, 81920, 128, 81920, 640, 1474560, 256
    };
    const void* ptr[18];
    bool used[64];
    for (int i = 0; i < 64; ++i) used[i] = false;
    bool ok = (n_in >= 18 && n_in <= 64);
    for (int k = 0; k < 18 && ok; ++k) {
        ptr[k] = nullptr;
        for (int i = 0; i < n_in; ++i) {
            if (!used[i] && in_sizes[i] == want[k]) { ptr[k] = d_in[i]; used[i] = true; break; }
        }
        if (!ptr[k]) ok = false;
    }
    if (!ok) { for (int k = 0; k < 18; ++k) ptr[k] = d_in[k]; }

    const float* sx1  = (const float*)ptr[0];
    const float* sx2  = (const float*)ptr[1];
    const float* t_hx = (const float*)ptr[2];
    const float* tx   = (const float*)ptr[3];
    const float* Wt1  = (const float*)ptr[4];
    const float* bt1  = (const float*)ptr[5];
    const float* Wt2  = (const float*)ptr[6];
    const float* Wt3  = (const float*)ptr[7];
    const float* WU   = (const float*)ptr[8];
    const float* bU   = (const float*)ptr[9];
    const float* WV   = (const float*)ptr[10];
    const float* bV   = (const float*)ptr[11];
    const float* Wa1  = (const float*)ptr[12];
    const float* ba1  = (const float*)ptr[13];
    const float* Wa2  = (const float*)ptr[14];
    const float* ba2  = (const float*)ptr[15];
    const float* Wot  = (const float*)ptr[16];
    const float* bot  = (const float*)ptr[17];

    // Workspace (peak 96.42 MB; proven available in R4/R5):
    char* base = (char*)d_ws;
    short* txc   = (short*)base;
    short* sxh1  = (short*)(base + (size_t)33554432);
    short* sxh2  = (short*)(base + (size_t)50331648);
    short* bUh   = sxh1;                                   // reuse (sxh1 dead after gap)
    short* amulH = (short*)(base + (size_t)33554432);
    short* txh   = (short*)(base + (size_t)75497472);
    short* bVh   = (short*)(base + (size_t)75497472);
    short* a1h   = (short*)(base + (size_t)83886080);
    float* part  = (float*)(base + (size_t)92274688);
    float* wvec  = (float*)(base + (size_t)92536832);
    short* Wt1p  = (short*)(base + (size_t)92545024);
    short* WUp   = (short*)(base + (size_t)92938240);
    short* WVp   = (short*)(base + (size_t)93069312);
    short* Wa1p  = (short*)(base + (size_t)93134848);
    short* Wa2p  = (short*)(base + (size_t)93298688);
    short* Wotp  = (short*)(base + (size_t)93462528);

    float* out_a = (float*)d_out;
    float* out_w = out_a + (size_t)8 * 256 * PP;

    // weight packs
    k_wpack<<<dim3(96), 256, 0, stream>>>(Wt1, Wt1p, 16, 768);
    k_wpack<<<dim3(32), 256, 0, stream>>>(WU,  WUp,  16, 256);
    k_wpack<<<dim3(16), 256, 0, stream>>>(WV,  WVp,   8, 256);
    k_wpack<<<dim3(40), 256, 0, stream>>>(Wa1, Wa1p,  8, 640);
    k_wpack<<<dim3(40), 256, 0, stream>>>(Wa2, Wa2p, 40, 128);
    k_wprep<<<dim3(720), 256, 0, stream>>>(Wot, Wotp);

    // layout conversion: f32 NCHW -> bf16 NHWC
    k_t2h<<<dim3(64, 4, 8), 256, 0, stream>>>(sx1,  sxh1, 256, 4096, 256, 0);
    k_t2h<<<dim3(64, 4, 8), 256, 0, stream>>>(sx2,  sxh2, 256, 4096, 256, 0);
    k_t2h<<<dim3(64, 4, 8), 256, 0, stream>>>(t_hx, txc,  256, 4096, 512, 0);
    k_t2h<<<dim3(16, 4, 8), 256, 0, stream>>>(tx,   txh,  256, 1024, 256, 0);
    k_up <<<dim3(512, 1, 8), 256, 0, stream>>>(txh, txc);

    // main pipeline
    k_gemm_gap <<<dim3(2, 32, 8), 256, 0, stream>>>(sxh1, txc, Wt1p, bt1, part);
    k_wvec     <<<dim3(8),        256, 0, stream>>>(part, Wt2, Wt3, wvec, out_w);
    k_gemm_bU  <<<dim3(2, 32, 8), 256, 0, stream>>>(sxh2, WUp, bU, wvec, bUh);
    k_gemm_bV  <<<dim3(1, 32, 8), 256, 0, stream>>>(bUh, WVp, bV, bVh);
    k_gemm_a1  <<<dim3(1, 32, 8), 256, 0, stream>>>(bVh, txc, Wa1p, ba1, a1h);
    k_gemm_amul<<<dim3(5, 32, 8), 256, 0, stream>>>(a1h, Wa2p, ba2, bVh, txc, amulH);
    k_conv3_mfma<<<dim3(16, 2, 8), 512, 0, stream>>>(amulH, Wotp, bot, out_a);
}